// Round 1
// baseline (2466.066 us; speedup 1.0000x reference)
//
#include <hip/hip_runtime.h>
#include <cstdint>
#include <cstddef>

// ---------------------------------------------------------------------------
// SDHGNN: 4-layer dual-stream attention GNN, fp32 baseline.
// B=2, D=128 (H=4 heads x dh=32), N=2048, layers self/cross/self/cross,
// pooling halves the source index set each layer (2048->1024->512->256->128).
//
// Head mapping (from reshape [B,D,N]->[B,dh,H,N]): channel d = i*H + h.
// Top-k selection must be EXACT (ties -> lower index), so everything feeding
// the importance vector p stays in fp32.
// ---------------------------------------------------------------------------

#define NB 2
#define ND 128
#define NH 4
#define NDH 32
#define NN 2048
#define ND2 256
#define BDN (NB*ND*NN)          // 524288
#define QK_SCALE 0.17677669529663687f   // 1/sqrt(32)
#define IN_EPS 1e-3f

// ---------------------------------------------------------------------------
// init: copy inputs into d_out (x0|x1) and set idx = arange per batch
// ---------------------------------------------------------------------------
__global__ __launch_bounds__(256) void init_kernel(
    const float* __restrict__ x0in, const float* __restrict__ x1in,
    float* __restrict__ out, int* __restrict__ idx0, int* __restrict__ idx1)
{
    int tid = blockIdx.x * 256 + threadIdx.x;          // BDN/4 threads, float4
    const float4* a = (const float4*)x0in;
    const float4* b = (const float4*)x1in;
    float4* o = (float4*)out;
    o[tid] = a[tid];
    o[BDN/4 + tid] = b[tid];
    if (tid < NB*NN) {
        int v = tid & (NN-1);
        idx0[tid] = v;
        idx1[tid] = v;
    }
}

__global__ __launch_bounds__(256) void zerop_kernel(float* __restrict__ p0,
                                                    float* __restrict__ p1)
{
    int t = blockIdx.x * 256 + threadIdx.x;
    if (t < NB*NN) { p0[t] = 0.f; p1[t] = 0.f; }
}

// ---------------------------------------------------------------------------
// gather: s[b,d,j] = x[b,d,idx[b,j]]
// ---------------------------------------------------------------------------
__global__ __launch_bounds__(256) void gather_kernel(
    const float* __restrict__ x, const int* __restrict__ idx,
    float* __restrict__ s, int M)
{
    int tid = blockIdx.x * 256 + threadIdx.x;
    int total = NB * ND * M;
    if (tid >= total) return;
    int j  = tid % M;
    int bd = tid / M;
    int b  = bd / ND;
    s[tid] = x[(size_t)bd * NN + idx[b * NN + j]];
}

// ---------------------------------------------------------------------------
// Pointwise conv GEMM: out[b,o,n] (+)= sum_i W[o, wcol0+i] * f(in[b,i,n]) + bias[o]
// f = identity or instnorm+relu (nmean/ninv per [b, cin]).
// Tile 64x64, 4x4 micro, K-chunk 16. All dims here are multiples of 64/16.
// ---------------------------------------------------------------------------
__global__ __launch_bounds__(256) void pw_gemm_kernel(
    const float* __restrict__ W, int ldw, int wcol0,
    const float* __restrict__ bias,
    const float* __restrict__ in, int in_bs,
    const float* __restrict__ nmean, const float* __restrict__ ninv,
    float* __restrict__ out, int out_bs,
    int Cout, int Cin, int nCols, int acc_flag)
{
    __shared__ float As[16][68];
    __shared__ float Bs[16][68];
    int b  = blockIdx.z;
    int o0 = blockIdx.y * 64;
    int n0 = blockIdx.x * 64;
    int t  = threadIdx.x;
    int tx = t & 15, ty = t >> 4;
    float acc[4][4] = {};

    for (int kc0 = 0; kc0 < Cin; kc0 += 16) {
        // W tile: 64 rows x 16 k, one float4 per thread
        {
            int row = t >> 2, kk4 = (t & 3) * 4;
            const float* wp = &W[(size_t)(o0 + row) * ldw + wcol0 + kc0 + kk4];
            float4 wv = *(const float4*)wp;
            As[kk4+0][row] = wv.x; As[kk4+1][row] = wv.y;
            As[kk4+2][row] = wv.z; As[kk4+3][row] = wv.w;
        }
        // in tile: 16 k x 64 n, one float4 per thread
        {
            int kk = t >> 4, nl4 = (t & 15) * 4;
            int c = kc0 + kk;
            float4 v = *(const float4*)&in[(size_t)b*in_bs + (size_t)c*nCols + n0 + nl4];
            if (nmean) {
                float m = nmean[b*Cin + c], iv = ninv[b*Cin + c];
                v.x = (v.x - m)*iv; v.y = (v.y - m)*iv;
                v.z = (v.z - m)*iv; v.w = (v.w - m)*iv;
                v.x = v.x > 0.f ? v.x : 0.f; v.y = v.y > 0.f ? v.y : 0.f;
                v.z = v.z > 0.f ? v.z : 0.f; v.w = v.w > 0.f ? v.w : 0.f;
            }
            *(float4*)&Bs[kk][nl4] = v;
        }
        __syncthreads();
        #pragma unroll
        for (int kk = 0; kk < 16; ++kk) {
            float a[4], bb[4];
            #pragma unroll
            for (int u = 0; u < 4; ++u) a[u] = As[kk][ty + 16*u];
            #pragma unroll
            for (int w = 0; w < 4; ++w) bb[w] = Bs[kk][tx + 16*w];
            #pragma unroll
            for (int u = 0; u < 4; ++u)
                #pragma unroll
                for (int w = 0; w < 4; ++w)
                    acc[u][w] = fmaf(a[u], bb[w], acc[u][w]);
        }
        __syncthreads();
    }

    #pragma unroll
    for (int u = 0; u < 4; ++u) {
        int o = o0 + ty + 16*u;
        float bv = bias ? bias[o] : 0.f;
        #pragma unroll
        for (int w = 0; w < 4; ++w) {
            int n = n0 + tx + 16*w;
            size_t oi = (size_t)b*out_bs + (size_t)o*nCols + n;
            float v = acc[u][w] + bv;
            if (acc_flag) out[oi] += v; else out[oi] = v;
        }
    }
}

// ---------------------------------------------------------------------------
// Fused attention: per block = one (b, h, 32-query tile).
// Pass 1: stream K, online (max, sumexp) per query.
// Pass 2: stream K,V, recompute scores, prob = exp(s-m)/l; accumulate
//         msg = prob @ V and p[b,m] += sum_{n,h} prob / H (atomic).
// ---------------------------------------------------------------------------
__global__ __launch_bounds__(256) void attn_kernel(
    const float* __restrict__ qg, const float* __restrict__ kg,
    const float* __restrict__ vg, int M,
    float* __restrict__ msg, float* __restrict__ p)
{
    __shared__ float qs[32][36];
    __shared__ float ks[32][68];
    __shared__ float vs[32][68];
    __shared__ float ps[32][68];
    __shared__ float pm[32][9];
    __shared__ float pl[32][9];
    __shared__ float rowm[32], rowinv[32];

    int b = blockIdx.z, h = blockIdx.y;
    int n0 = blockIdx.x * 32;
    int t = threadIdx.x;

    // load q tile: 32 i x 32 n (channel d = i*H + h)
    {
        int row = t >> 3, c4 = (t & 7) * 4;
        *(float4*)&qs[row][c4] =
            *(const float4*)&qg[((size_t)b*ND + row*NH + h)*NN + n0 + c4];
    }
    __syncthreads();

    int nl1 = t >> 3;            // query row this thread scores (0..31)
    int mlo = (t & 7) * 8;       // contiguous 8 source columns
    float qreg[32];
    #pragma unroll
    for (int i = 0; i < 32; ++i) qreg[i] = qs[i][nl1];

    float tmax = -1e30f, tsum = 0.f;

    // ---- pass 1 ----
    for (int m0 = 0; m0 < M; m0 += 64) {
        #pragma unroll
        for (int r = 0; r < 2; ++r) {
            int e = t + 256*r;
            int row = e >> 4, c4 = (e & 15) * 4;
            *(float4*)&ks[row][c4] =
                *(const float4*)&kg[((size_t)b*ND + row*NH + h)*M + m0 + c4];
        }
        __syncthreads();
        float sarr[8] = {};
        #pragma unroll
        for (int i = 0; i < 32; ++i) {
            float4 k0 = *(const float4*)&ks[i][mlo];
            float4 k1 = *(const float4*)&ks[i][mlo+4];
            float qv = qreg[i];
            sarr[0] = fmaf(qv, k0.x, sarr[0]); sarr[1] = fmaf(qv, k0.y, sarr[1]);
            sarr[2] = fmaf(qv, k0.z, sarr[2]); sarr[3] = fmaf(qv, k0.w, sarr[3]);
            sarr[4] = fmaf(qv, k1.x, sarr[4]); sarr[5] = fmaf(qv, k1.y, sarr[5]);
            sarr[6] = fmaf(qv, k1.z, sarr[6]); sarr[7] = fmaf(qv, k1.w, sarr[7]);
        }
        #pragma unroll
        for (int c = 0; c < 8; ++c) {
            float s = sarr[c] * QK_SCALE;
            if (s > tmax) { tsum = tsum * __expf(tmax - s) + 1.f; tmax = s; }
            else tsum += __expf(s - tmax);
        }
        __syncthreads();
    }
    pm[nl1][t & 7] = tmax;
    pl[nl1][t & 7] = tsum;
    __syncthreads();
    if (t < 32) {
        float m = -1e30f;
        #pragma unroll
        for (int c = 0; c < 8; ++c) m = fmaxf(m, pm[t][c]);
        float l = 0.f;
        #pragma unroll
        for (int c = 0; c < 8; ++c) l += pl[t][c] * __expf(pm[t][c] - m);
        rowm[t] = m;
        rowinv[t] = 1.f / l;
    }
    __syncthreads();

    float rm = rowm[nl1], rinv = rowinv[nl1];

    // ---- pass 2 ----
    int nl2 = t & 31, iq = t >> 5;     // PV mapping: 4 i-rows = iq + 8u
    float acc[4] = {0.f, 0.f, 0.f, 0.f};

    for (int m0 = 0; m0 < M; m0 += 64) {
        #pragma unroll
        for (int r = 0; r < 2; ++r) {
            int e = t + 256*r;
            int row = e >> 4, c4 = (e & 15) * 4;
            size_t base = ((size_t)b*ND + row*NH + h)*M + m0 + c4;
            *(float4*)&ks[row][c4] = *(const float4*)&kg[base];
            *(float4*)&vs[row][c4] = *(const float4*)&vg[base];
        }
        __syncthreads();
        {
            float sarr[8] = {};
            #pragma unroll
            for (int i = 0; i < 32; ++i) {
                float4 k0 = *(const float4*)&ks[i][mlo];
                float4 k1 = *(const float4*)&ks[i][mlo+4];
                float qv = qreg[i];
                sarr[0] = fmaf(qv, k0.x, sarr[0]); sarr[1] = fmaf(qv, k0.y, sarr[1]);
                sarr[2] = fmaf(qv, k0.z, sarr[2]); sarr[3] = fmaf(qv, k0.w, sarr[3]);
                sarr[4] = fmaf(qv, k1.x, sarr[4]); sarr[5] = fmaf(qv, k1.y, sarr[5]);
                sarr[6] = fmaf(qv, k1.z, sarr[6]); sarr[7] = fmaf(qv, k1.w, sarr[7]);
            }
            float4 o0, o1;
            o0.x = __expf(sarr[0]*QK_SCALE - rm) * rinv;
            o0.y = __expf(sarr[1]*QK_SCALE - rm) * rinv;
            o0.z = __expf(sarr[2]*QK_SCALE - rm) * rinv;
            o0.w = __expf(sarr[3]*QK_SCALE - rm) * rinv;
            o1.x = __expf(sarr[4]*QK_SCALE - rm) * rinv;
            o1.y = __expf(sarr[5]*QK_SCALE - rm) * rinv;
            o1.z = __expf(sarr[6]*QK_SCALE - rm) * rinv;
            o1.w = __expf(sarr[7]*QK_SCALE - rm) * rinv;
            *(float4*)&ps[nl1][mlo]   = o0;
            *(float4*)&ps[nl1][mlo+4] = o1;
        }
        __syncthreads();
        // importance accumulation: sum probs over the 32 queries, /H
        if (t < 64) {
            float sum = 0.f;
            #pragma unroll
            for (int j = 0; j < 32; ++j) sum += ps[j][t];
            atomicAdd(&p[(size_t)b*NN + m0 + t], sum * 0.25f);
        }
        // PV
        #pragma unroll
        for (int m4 = 0; m4 < 16; ++m4) {
            float4 pr = *(const float4*)&ps[nl2][m4*4];
            #pragma unroll
            for (int u = 0; u < 4; ++u) {
                float4 vv = *(const float4*)&vs[iq + 8*u][m4*4];
                acc[u] += pr.x*vv.x + pr.y*vv.y + pr.z*vv.z + pr.w*vv.w;
            }
        }
        __syncthreads();
    }
    #pragma unroll
    for (int u = 0; u < 4; ++u) {
        int i = iq + 8*u;
        msg[((size_t)b*ND + i*NH + h)*NN + n0 + nl2] = acc[u];
    }
}

// ---------------------------------------------------------------------------
// InstanceNorm stats over N per (b, c): exact two-pass mean / var.
// ---------------------------------------------------------------------------
__global__ __launch_bounds__(256) void stats_kernel(
    const float* __restrict__ z, float* __restrict__ mean, float* __restrict__ inv)
{
    int bc = blockIdx.x;
    const float* row = z + (size_t)bc * NN;
    __shared__ float red[256];
    __shared__ float m_s;
    int t = threadIdx.x;
    float s = 0.f;
    for (int i = t; i < NN; i += 256) s += row[i];
    red[t] = s; __syncthreads();
    for (int o = 128; o > 0; o >>= 1) {
        if (t < o) red[t] += red[t + o];
        __syncthreads();
    }
    if (t == 0) { m_s = red[0] * (1.f / NN); mean[bc] = m_s; }
    __syncthreads();
    float m = m_s;
    float ss = 0.f;
    for (int i = t; i < NN; i += 256) { float d = row[i] - m; ss = fmaf(d, d, ss); }
    red[t] = ss; __syncthreads();
    for (int o = 128; o > 0; o >>= 1) {
        if (t < o) red[t] += red[t + o];
        __syncthreads();
    }
    if (t == 0) inv[bc] = 1.f / sqrtf(red[0] * (1.f / NN) + IN_EPS);
}

// ---------------------------------------------------------------------------
// Exact top-k rank: rank[i] = #{j : p[j] > p[i]  or  (p[j]==p[i] and j<i)}
// (matches jax.lax.top_k tie-break: lower index first). Selected iff rank < k.
// ---------------------------------------------------------------------------
__global__ __launch_bounds__(256) void rank_kernel(
    const float* __restrict__ p, int* __restrict__ rank, int M)
{
    int b = blockIdx.y;
    __shared__ float pv[2048];
    for (int i = threadIdx.x; i < M; i += 256) pv[i] = p[(size_t)b*NN + i];
    __syncthreads();
    int i = blockIdx.x * 256 + threadIdx.x;
    if (i < M) {
        float pi = pv[i];
        int r = 0;
        for (int j = 0; j < M; ++j) {
            float pj = pv[j];
            r += (pj > pi) ? 1 : ((pj == pi && j < i) ? 1 : 0);
        }
        rank[b*NN + i] = r;
    }
}

// select + compact (ascending original index) + gather through old idx, in-place
__global__ __launch_bounds__(256) void select_kernel(
    const int* __restrict__ rank, int* __restrict__ idx, int M, int k)
{
    int b = blockIdx.x;
    __shared__ int sel[2048], idv[2048], sa[2048], sb[2048];
    int t = threadIdx.x;
    for (int i = t; i < M; i += 256) {
        int s = rank[b*NN + i] < k ? 1 : 0;
        sel[i] = s;
        sa[i] = s;
        idv[i] = idx[b*NN + i];
    }
    __syncthreads();
    int* src = sa; int* dst = sb;
    for (int off = 1; off < M; off <<= 1) {
        for (int i = t; i < M; i += 256)
            dst[i] = src[i] + (i >= off ? src[i - off] : 0);
        __syncthreads();
        int* tmp = src; src = dst; dst = tmp;
    }
    for (int i = t; i < M; i += 256)
        if (sel[i]) idx[b*NN + src[i] - 1] = idv[i];
}

// ---------------------------------------------------------------------------
extern "C" void kernel_launch(void* const* d_in, const int* in_sizes, int n_in,
                              void* d_out, int out_size, void* d_ws, size_t ws_size,
                              hipStream_t stream)
{
    const float* x0in = (const float*)d_in[0];
    const float* x1in = (const float*)d_in[1];
    const float* Wq = (const float*)d_in[2];
    const float* bq = (const float*)d_in[3];
    const float* Wk = (const float*)d_in[4];
    const float* bk = (const float*)d_in[5];
    const float* Wv = (const float*)d_in[6];
    const float* bv = (const float*)d_in[7];
    const float* Wm = (const float*)d_in[8];
    const float* bm = (const float*)d_in[9];
    const float* W1 = (const float*)d_in[10];
    const float* b1 = (const float*)d_in[11];
    const float* W2 = (const float*)d_in[12];
    const float* b2 = (const float*)d_in[13];

    float* out = (float*)d_out;
    float* ws  = (float*)d_ws;

    // workspace layout (floats)
    float* s0   = ws;
    float* s1   = ws + (size_t)BDN;
    float* qb   = ws + (size_t)2*BDN;
    float* kb   = ws + (size_t)3*BDN;
    float* vb   = ws + (size_t)4*BDN;
    float* mb   = ws + (size_t)5*BDN;
    float* zb   = ws + (size_t)6*BDN;            // [B, 2D, N] -> 2*BDN floats
    float* meanb= ws + (size_t)8*BDN;
    float* invb = meanb + NB*ND2;
    float* p0   = invb + NB*ND2;
    float* p1   = p0 + NB*NN;
    int* idx0   = (int*)(p1 + NB*NN);
    int* idx1   = idx0 + NB*NN;
    int* rankb  = idx1 + NB*NN;

    float* x0 = out;
    float* x1 = out + BDN;

    init_kernel<<<BDN/4/256, 256, 0, stream>>>(x0in, x1in, out, idx0, idx1);

    const int Ms[4] = {2048, 1024, 512, 256};
    for (int l = 0; l < 4; ++l) {
        int M = Ms[l];
        int k_new = (M/2 < 128) ? 128 : M/2;
        int cross = l & 1;
        const float* srcA = cross ? x1 : x0; const int* idxA = cross ? idx1 : idx0;
        const float* srcB = cross ? x0 : x1; const int* idxB = cross ? idx0 : idx1;

        int tot = NB * ND * M;
        gather_kernel<<<(tot+255)/256, 256, 0, stream>>>(srcA, idxA, s0, M);
        gather_kernel<<<(tot+255)/256, 256, 0, stream>>>(srcB, idxB, s1, M);
        zerop_kernel<<<(NB*NN+255)/256, 256, 0, stream>>>(p0, p1);

        for (int st = 0; st < 2; ++st) {
            float* xs = st ? x1 : x0;
            const float* sb = st ? s1 : s0;
            float* pb = st ? p1 : p0;

            dim3 gN(NN/64, ND/64, NB);
            dim3 gM(M/64, ND/64, NB);
            dim3 gZ(NN/64, ND2/64, NB);

            // q = Wq x + bq  (N cols);  k,v from gathered source (M cols)
            pw_gemm_kernel<<<gN, 256, 0, stream>>>(Wq + (size_t)l*ND*ND, ND, 0, bq + l*ND,
                xs, ND*NN, nullptr, nullptr, qb, ND*NN, ND, ND, NN, 0);
            pw_gemm_kernel<<<gM, 256, 0, stream>>>(Wk + (size_t)l*ND*ND, ND, 0, bk + l*ND,
                sb, ND*M, nullptr, nullptr, kb, ND*M, ND, ND, M, 0);
            pw_gemm_kernel<<<gM, 256, 0, stream>>>(Wv + (size_t)l*ND*ND, ND, 0, bv + l*ND,
                sb, ND*M, nullptr, nullptr, vb, ND*M, ND, ND, M, 0);

            dim3 ga(NN/32, NH, NB);
            attn_kernel<<<ga, 256, 0, stream>>>(qb, kb, vb, M, mb, pb);

            // msg2 = Wm msg + bm  (reuse qb)
            pw_gemm_kernel<<<gN, 256, 0, stream>>>(Wm + (size_t)l*ND*ND, ND, 0, bm + l*ND,
                mb, ND*NN, nullptr, nullptr, qb, ND*NN, ND, ND, NN, 0);

            // z = W1[:, :D] x + b1 ;  z += W1[:, D:] msg2
            pw_gemm_kernel<<<gZ, 256, 0, stream>>>(W1 + (size_t)l*ND2*ND2, ND2, 0, b1 + l*ND2,
                xs, ND*NN, nullptr, nullptr, zb, ND2*NN, ND2, ND, NN, 0);
            pw_gemm_kernel<<<gZ, 256, 0, stream>>>(W1 + (size_t)l*ND2*ND2, ND2, ND, nullptr,
                qb, ND*NN, nullptr, nullptr, zb, ND2*NN, ND2, ND, NN, 1);

            stats_kernel<<<NB*ND2, 256, 0, stream>>>(zb, meanb, invb);

            // x += W2 relu(instnorm(z)) + b2
            pw_gemm_kernel<<<gN, 256, 0, stream>>>(W2 + (size_t)l*ND*ND2, ND2, 0, b2 + l*ND,
                zb, ND2*NN, meanb, invb, xs, ND*NN, ND, ND2, NN, 1);
        }

        dim3 gr((M+255)/256, NB);
        if (!cross) {
            rank_kernel<<<gr, 256, 0, stream>>>(p0, rankb, M);
            select_kernel<<<NB, 256, 0, stream>>>(rankb, idx0, M, k_new);
            rank_kernel<<<gr, 256, 0, stream>>>(p1, rankb, M);
            select_kernel<<<NB, 256, 0, stream>>>(rankb, idx1, M, k_new);
        } else {
            rank_kernel<<<gr, 256, 0, stream>>>(p0, rankb, M);
            select_kernel<<<NB, 256, 0, stream>>>(rankb, idx1, M, k_new);
            rank_kernel<<<gr, 256, 0, stream>>>(p1, rankb, M);
            select_kernel<<<NB, 256, 0, stream>>>(rankb, idx0, M, k_new);
        }
    }
}

// Round 2
// 1568.173 us; speedup vs baseline: 1.5726x; 1.5726x over previous
//
#include <hip/hip_runtime.h>
#include <cstdint>
#include <cstddef>

// ---------------------------------------------------------------------------
// SDHGNN fp32, round 2: stream-fused grids (z = stream*2 + batch, Z=4),
// float4 micro-tiled GEMM, restructured attention (4q x 4c per thread).
// ---------------------------------------------------------------------------

#define NB 2
#define ND 128
#define NH 4
#define NN 2048
#define ND2 256
#define DN (ND*NN)              // 262144, z-stride of x/q/msg
#define BDN (NB*DN)             // 524288
#define QK_SCALE 0.17677669529663687f
#define IN_EPS 1e-3f

// ---------------------------------------------------------------------------
__global__ __launch_bounds__(256) void init_kernel(
    const float* __restrict__ x0in, const float* __restrict__ x1in,
    float* __restrict__ out, int* __restrict__ idx0, int* __restrict__ idx1)
{
    int tid = blockIdx.x * 256 + threadIdx.x;
    const float4* a = (const float4*)x0in;
    const float4* b = (const float4*)x1in;
    float4* o = (float4*)out;
    o[tid] = a[tid];
    o[BDN/4 + tid] = b[tid];
    if (tid < NB*NN) {
        int v = tid & (NN-1);
        idx0[tid] = v;
        idx1[tid] = v;
    }
}

__global__ __launch_bounds__(256) void zerop_kernel(float* __restrict__ p)
{
    p[blockIdx.x * 256 + threadIdx.x] = 0.f;
}

// ---------------------------------------------------------------------------
// gather: s[z][d][m] = x[srcz][d][idx[m]]
// ---------------------------------------------------------------------------
__global__ __launch_bounds__(256) void gather_kernel(
    const float* __restrict__ x, const int* __restrict__ idx0,
    const int* __restrict__ idx1, float* __restrict__ s, int mbits, int cross)
{
    int tid = blockIdx.x * 256 + threadIdx.x;
    int M = 1 << mbits;
    int m = tid & (M - 1);
    int zd = tid >> mbits;
    int d = zd & (ND - 1), z = zd >> 7;
    int st = z >> 1, b = z & 1;
    int ss = cross ? 1 - st : st;
    const int* idx = (ss ? idx1 : idx0) + b * NN;
    s[tid] = x[((size_t)(ss*2 + b) * ND + d) * NN + idx[m]];
}

// ---------------------------------------------------------------------------
// GEMM: out[z][o][n] (+)= sum_c W[o][c] * f(in(c)[z][..][n]) + bias[o]
//   in(c) = in1 row c for c<split else in2 row c-split (both z-stride in_zs)
//   f = identity, or instnorm+relu via nmean/ninv [z][Cin]
// tile 64x64, 4x4 micro via float4 LDS reads; K-chunk 16.
// ---------------------------------------------------------------------------
__global__ __launch_bounds__(256) void gemm64_kernel(
    const float* __restrict__ W, int ldw, const float* __restrict__ bias,
    const float* __restrict__ in1, const float* __restrict__ in2, int split,
    int in_zs, const float* __restrict__ nmean, const float* __restrict__ ninv,
    float* __restrict__ out, int out_zs, int Cin, int nCols, int acc_flag)
{
    __shared__ float As[16][68];
    __shared__ float Bs[16][68];
    const int z  = blockIdx.z;
    const int r0 = blockIdx.y * 64;
    const int n0 = blockIdx.x * 64;
    const int t  = threadIdx.x;
    const int tx4 = (t & 15) * 4, ty4 = (t >> 4) * 4;
    const int arow = t >> 2, ak4 = (t & 3) * 4;
    const int bk = t >> 4, bn4 = (t & 15) * 4;
    float acc[4][4] = {};

    for (int kc = 0; kc < Cin; kc += 16) {
        {   // stage W tile transposed: As[k][row]
            float4 wv = *(const float4*)&W[(size_t)(r0 + arow) * ldw + kc + ak4];
            As[ak4+0][arow] = wv.x; As[ak4+1][arow] = wv.y;
            As[ak4+2][arow] = wv.z; As[ak4+3][arow] = wv.w;
        }
        {   // stage input tile: Bs[k][n]
            int c = kc + bk;
            const float* src = in1; int cc = c;
            if (in2 && c >= split) { src = in2; cc = c - split; }
            float4 v = *(const float4*)&src[(size_t)z*in_zs + (size_t)cc*nCols + n0 + bn4];
            if (nmean) {
                float m = nmean[z*Cin + c], iv = ninv[z*Cin + c];
                v.x = (v.x - m)*iv; v.y = (v.y - m)*iv;
                v.z = (v.z - m)*iv; v.w = (v.w - m)*iv;
                v.x = v.x > 0.f ? v.x : 0.f; v.y = v.y > 0.f ? v.y : 0.f;
                v.z = v.z > 0.f ? v.z : 0.f; v.w = v.w > 0.f ? v.w : 0.f;
            }
            *(float4*)&Bs[bk][bn4] = v;
        }
        __syncthreads();
        #pragma unroll
        for (int kk = 0; kk < 16; ++kk) {
            float4 av = *(const float4*)&As[kk][ty4];
            float4 bv = *(const float4*)&Bs[kk][tx4];
            const float* aa = (const float*)&av;
            const float* bb = (const float*)&bv;
            #pragma unroll
            for (int j = 0; j < 4; ++j)
                #pragma unroll
                for (int w = 0; w < 4; ++w)
                    acc[j][w] = fmaf(aa[j], bb[w], acc[j][w]);
        }
        __syncthreads();
    }

    #pragma unroll
    for (int j = 0; j < 4; ++j) {
        int row = r0 + ty4 + j;
        float bv = bias ? bias[row] : 0.f;
        size_t oi = (size_t)z*out_zs + (size_t)row*nCols + n0 + tx4;
        float4 res;
        res.x = acc[j][0] + bv; res.y = acc[j][1] + bv;
        res.z = acc[j][2] + bv; res.w = acc[j][3] + bv;
        if (acc_flag) {
            float4 o = *(const float4*)&out[oi];
            res.x += o.x; res.y += o.y; res.z += o.z; res.w += o.w;
        }
        *(float4*)&out[oi] = res;
    }
}

// ---------------------------------------------------------------------------
// Fused attention: block = (32-query tile, h, z). Chunk = 128 source cols.
// Pass 1: online (max, sumexp); pass 2: recompute scores, probs -> LDS,
// column-sum into p (atomic), PV accumulate.
// Thread maps: scores 4q x 4c (qgp=t>>5, cg=t&31); PV 4dh x 1q (dhg=t>>5, qv=t&31).
// ---------------------------------------------------------------------------
__global__ __launch_bounds__(256) void attn_kernel(
    const float* __restrict__ qg, const float* __restrict__ kg,
    const float* __restrict__ vg, int M,
    float* __restrict__ msg, float* __restrict__ p)
{
    __shared__ float qs[32][36];
    __shared__ float kb[32][132];
    __shared__ float vb[32][132];
    __shared__ float rowm[32], rowiv[32];

    const int z = blockIdx.z, h = blockIdx.y;
    const int n0 = blockIdx.x * 32;
    const int t = threadIdx.x;

    {   // stage q tile (transposed, pre-scaled): qs[i][local n]
        int i = t >> 3, c4 = (t & 7) * 4;
        float4 qv = *(const float4*)&qg[((size_t)z*ND + i*NH + h)*NN + n0 + c4];
        qv.x *= QK_SCALE; qv.y *= QK_SCALE; qv.z *= QK_SCALE; qv.w *= QK_SCALE;
        *(float4*)&qs[i][c4] = qv;
    }

    const int q0 = (t >> 5) * 4;
    const int cA = (t & 31) * 4;
    const int nch = M >> 7;

    float tmax[4], tsum[4];
    #pragma unroll
    for (int j = 0; j < 4; ++j) { tmax[j] = -1e30f; tsum[j] = 0.f; }

    // ---- pass 1 ----
    for (int ch = 0; ch < nch; ++ch) {
        const int m0 = ch << 7;
        #pragma unroll
        for (int r = 0; r < 4; ++r) {
            int e = t + 256*r;
            int row = e >> 5, c4 = (e & 31) * 4;
            *(float4*)&kb[row][c4] =
                *(const float4*)&kg[((size_t)z*ND + row*NH + h)*M + m0 + c4];
        }
        __syncthreads();
        float s[4][4] = {};
        #pragma unroll
        for (int i = 0; i < 32; ++i) {
            float4 qv = *(const float4*)&qs[i][q0];
            float4 kv = *(const float4*)&kb[i][cA];
            const float* qa = (const float*)&qv;
            #pragma unroll
            for (int j = 0; j < 4; ++j) {
                s[j][0] = fmaf(qa[j], kv.x, s[j][0]);
                s[j][1] = fmaf(qa[j], kv.y, s[j][1]);
                s[j][2] = fmaf(qa[j], kv.z, s[j][2]);
                s[j][3] = fmaf(qa[j], kv.w, s[j][3]);
            }
        }
        #pragma unroll
        for (int j = 0; j < 4; ++j)
            #pragma unroll
            for (int c = 0; c < 4; ++c) {
                float sv = s[j][c];
                if (sv > tmax[j]) { tsum[j] = tsum[j]*__expf(tmax[j]-sv) + 1.f; tmax[j] = sv; }
                else tsum[j] += __expf(sv - tmax[j]);
            }
        __syncthreads();
    }

    // reduce (m,l) across the 32 col-groups (scratch aliases vb)
    {
        float (*redm)[33] = (float(*)[33])&vb[0][0];
        float (*redl)[33] = (float(*)[33])(&vb[0][0] + 1056);
        #pragma unroll
        for (int j = 0; j < 4; ++j) {
            redm[q0+j][t & 31] = tmax[j];
            redl[q0+j][t & 31] = tsum[j];
        }
        __syncthreads();
        if (t < 32) {
            float m = -1e30f;
            for (int c = 0; c < 32; ++c) m = fmaxf(m, redm[t][c]);
            float l = 0.f;
            for (int c = 0; c < 32; ++c) l += redl[t][c] * __expf(redm[t][c] - m);
            rowm[t] = m; rowiv[t] = 1.f / l;
        }
        __syncthreads();
    }
    float rm[4], ri[4];
    #pragma unroll
    for (int j = 0; j < 4; ++j) { rm[j] = rowm[q0+j]; ri[j] = rowiv[q0+j]; }

    const int dhg = (t >> 5) * 4;
    const int qv_ = t & 31;
    float apv[4] = {0.f, 0.f, 0.f, 0.f};

    // ---- pass 2 ----
    for (int ch = 0; ch < nch; ++ch) {
        const int m0 = ch << 7;
        #pragma unroll
        for (int r = 0; r < 4; ++r) {
            int e = t + 256*r;
            int row = e >> 5, c4 = (e & 31) * 4;
            size_t gb = ((size_t)z*ND + row*NH + h)*M + m0 + c4;
            *(float4*)&kb[row][c4] = *(const float4*)&kg[gb];
            *(float4*)&vb[row][c4] = *(const float4*)&vg[gb];
        }
        __syncthreads();
        float s[4][4] = {};
        #pragma unroll
        for (int i = 0; i < 32; ++i) {
            float4 qv = *(const float4*)&qs[i][q0];
            float4 kv = *(const float4*)&kb[i][cA];
            const float* qa = (const float*)&qv;
            #pragma unroll
            for (int j = 0; j < 4; ++j) {
                s[j][0] = fmaf(qa[j], kv.x, s[j][0]);
                s[j][1] = fmaf(qa[j], kv.y, s[j][1]);
                s[j][2] = fmaf(qa[j], kv.z, s[j][2]);
                s[j][3] = fmaf(qa[j], kv.w, s[j][3]);
            }
        }
        __syncthreads();                       // all kb score reads done
        #pragma unroll
        for (int j = 0; j < 4; ++j) {          // probs overwrite kb as ps[q][c]
            float4 pr;
            pr.x = __expf(s[j][0]-rm[j])*ri[j];
            pr.y = __expf(s[j][1]-rm[j])*ri[j];
            pr.z = __expf(s[j][2]-rm[j])*ri[j];
            pr.w = __expf(s[j][3]-rm[j])*ri[j];
            *(float4*)&kb[q0+j][cA] = pr;
        }
        __syncthreads();
        if (t < 128) {                         // importance column sums
            float su = 0.f;
            #pragma unroll
            for (int r = 0; r < 32; ++r) su += kb[r][t];
            atomicAdd(&p[(size_t)z*NN + m0 + t], su * 0.25f);
        }
        #pragma unroll
        for (int m4 = 0; m4 < 32; ++m4) {      // PV
            float4 pr = *(const float4*)&kb[qv_][m4*4];
            #pragma unroll
            for (int u = 0; u < 4; ++u) {
                float4 vv = *(const float4*)&vb[dhg+u][m4*4];
                apv[u] = fmaf(pr.x, vv.x, apv[u]);
                apv[u] = fmaf(pr.y, vv.y, apv[u]);
                apv[u] = fmaf(pr.z, vv.z, apv[u]);
                apv[u] = fmaf(pr.w, vv.w, apv[u]);
            }
        }
        __syncthreads();
    }
    #pragma unroll
    for (int u = 0; u < 4; ++u)
        msg[((size_t)z*ND + (dhg+u)*NH + h)*NN + n0 + qv_] = apv[u];
}

// ---------------------------------------------------------------------------
// InstanceNorm stats over N per (z, c)
// ---------------------------------------------------------------------------
__global__ __launch_bounds__(256) void stats_kernel(
    const float* __restrict__ zbuf, float* __restrict__ mean, float* __restrict__ inv)
{
    int bc = blockIdx.x;
    const float* row = zbuf + (size_t)bc * NN;
    __shared__ float red[256];
    __shared__ float m_s;
    int t = threadIdx.x;
    float s = 0.f;
    for (int i = t; i < NN; i += 256) s += row[i];
    red[t] = s; __syncthreads();
    for (int o = 128; o > 0; o >>= 1) {
        if (t < o) red[t] += red[t + o];
        __syncthreads();
    }
    if (t == 0) { m_s = red[0] * (1.f / NN); mean[bc] = m_s; }
    __syncthreads();
    float m = m_s;
    float ss = 0.f;
    for (int i = t; i < NN; i += 256) { float d = row[i] - m; ss = fmaf(d, d, ss); }
    red[t] = ss; __syncthreads();
    for (int o = 128; o > 0; o >>= 1) {
        if (t < o) red[t] += red[t + o];
        __syncthreads();
    }
    if (t == 0) inv[bc] = 1.f / sqrtf(red[0] * (1.f / NN) + IN_EPS);
}

// ---------------------------------------------------------------------------
// Exact top-k rank (ties -> lower index), then compaction
// ---------------------------------------------------------------------------
__global__ __launch_bounds__(256) void rank_kernel(
    const float* __restrict__ p, int* __restrict__ rank, int M)
{
    int zz = blockIdx.y;
    __shared__ float pv[2048];
    for (int i = threadIdx.x; i < M; i += 256) pv[i] = p[(size_t)zz*NN + i];
    __syncthreads();
    int i = blockIdx.x * 256 + threadIdx.x;
    if (i < M) {
        float pi = pv[i];
        int r = 0;
        for (int j = 0; j < M; ++j) {
            float pj = pv[j];
            r += (pj > pi) ? 1 : ((pj == pi && j < i) ? 1 : 0);
        }
        rank[zz*NN + i] = r;
    }
}

__global__ __launch_bounds__(256) void select_kernel(
    const int* __restrict__ rank, int* __restrict__ idx0, int* __restrict__ idx1,
    int M, int k, int cross)
{
    int z = blockIdx.x;
    int st = z >> 1, b = z & 1;
    int ts = cross ? 1 - st : st;
    int* idx = (ts ? idx1 : idx0) + b * NN;
    const int* rk = rank + z * NN;
    __shared__ int sel[2048], idv[2048], sa[2048], sb[2048];
    int t = threadIdx.x;
    for (int i = t; i < M; i += 256) {
        int s = rk[i] < k ? 1 : 0;
        sel[i] = s;
        sa[i] = s;
        idv[i] = idx[i];
    }
    __syncthreads();
    int* src = sa; int* dst = sb;
    for (int off = 1; off < M; off <<= 1) {
        for (int i = t; i < M; i += 256)
            dst[i] = src[i] + (i >= off ? src[i - off] : 0);
        __syncthreads();
        int* tmp = src; src = dst; dst = tmp;
    }
    for (int i = t; i < M; i += 256)
        if (sel[i]) idx[src[i] - 1] = idv[i];
}

// ---------------------------------------------------------------------------
extern "C" void kernel_launch(void* const* d_in, const int* in_sizes, int n_in,
                              void* d_out, int out_size, void* d_ws, size_t ws_size,
                              hipStream_t stream)
{
    const float* x0in = (const float*)d_in[0];
    const float* x1in = (const float*)d_in[1];
    const float* Wq = (const float*)d_in[2];
    const float* bq = (const float*)d_in[3];
    const float* Wk = (const float*)d_in[4];
    const float* bk = (const float*)d_in[5];
    const float* Wv = (const float*)d_in[6];
    const float* bv = (const float*)d_in[7];
    const float* Wm = (const float*)d_in[8];
    const float* bm = (const float*)d_in[9];
    const float* W1 = (const float*)d_in[10];
    const float* b1 = (const float*)d_in[11];
    const float* W2 = (const float*)d_in[12];
    const float* b2 = (const float*)d_in[13];

    float* out = (float*)d_out;
    float* ws  = (float*)d_ws;

    // ws layout (floats). 1M = Z*ND*NN. Aliasing (per layer, in order):
    //   buf0: s (gathered)  -> msg (attn out)
    //   buf1: k             -> zb (2M, spans buf1+buf2)
    //   buf2: v
    //   buf3: q             -> m2 (Wm out)
    const size_t MB1 = 1048576;
    float* buf0 = ws;
    float* buf1 = ws + MB1;
    float* buf2 = ws + 2*MB1;
    float* buf3 = ws + 3*MB1;
    float* meanb = ws + 4*MB1;          // Z*256
    float* invb  = meanb + 1024;
    float* p     = invb + 1024;         // Z*NN
    int* idx0 = (int*)(p + 4*NN);       // B*NN
    int* idx1 = idx0 + NB*NN;
    int* rankb = idx1 + NB*NN;          // Z*NN

    init_kernel<<<BDN/4/256, 256, 0, stream>>>(x0in, x1in, out, idx0, idx1);

    const int Ms[4] = {2048, 1024, 512, 256};
    const int Mb[4] = {11, 10, 9, 8};
    for (int l = 0; l < 4; ++l) {
        int M = Ms[l];
        int k_new = (M/2 < 128) ? 128 : M/2;
        int cross = l & 1;

        gather_kernel<<<(4*ND*M)/256, 256, 0, stream>>>(out, idx0, idx1, buf0, Mb[l], cross);
        zerop_kernel<<<4*NN/256, 256, 0, stream>>>(p);

        // q = Wq x + bq       [z][128][N]
        gemm64_kernel<<<dim3(NN/64, 2, 4), 256, 0, stream>>>(
            Wq + (size_t)l*ND*ND, ND, bq + l*ND,
            out, nullptr, 0, DN, nullptr, nullptr, buf3, DN, ND, NN, 0);
        // k, v from gathered s  [z][128][M]
        gemm64_kernel<<<dim3(M/64, 2, 4), 256, 0, stream>>>(
            Wk + (size_t)l*ND*ND, ND, bk + l*ND,
            buf0, nullptr, 0, ND*M, nullptr, nullptr, buf1, ND*M, ND, M, 0);
        gemm64_kernel<<<dim3(M/64, 2, 4), 256, 0, stream>>>(
            Wv + (size_t)l*ND*ND, ND, bv + l*ND,
            buf0, nullptr, 0, ND*M, nullptr, nullptr, buf2, ND*M, ND, M, 0);

        attn_kernel<<<dim3(NN/32, NH, 4), 256, 0, stream>>>(buf3, buf1, buf2, M, buf0, p);

        // m2 = Wm msg + bm    (msg in buf0 -> buf3)
        gemm64_kernel<<<dim3(NN/64, 2, 4), 256, 0, stream>>>(
            Wm + (size_t)l*ND*ND, ND, bm + l*ND,
            buf0, nullptr, 0, DN, nullptr, nullptr, buf3, DN, ND, NN, 0);

        // z = W1 [x ; m2] + b1   [z][256][N] into buf1..buf2
        gemm64_kernel<<<dim3(NN/64, 4, 4), 256, 0, stream>>>(
            W1 + (size_t)l*ND2*ND2, ND2, b1 + l*ND2,
            out, buf3, ND, DN, nullptr, nullptr, buf1, 2*DN, ND2, NN, 0);

        stats_kernel<<<4*ND2, 256, 0, stream>>>(buf1, meanb, invb);

        // x += W2 relu(instnorm(z)) + b2
        gemm64_kernel<<<dim3(NN/64, 2, 4), 256, 0, stream>>>(
            W2 + (size_t)l*ND*ND2, ND2, b2 + l*ND,
            buf1, nullptr, 0, 2*DN, meanb, invb, out, DN, ND2, NN, 1);

        rank_kernel<<<dim3((M+255)/256, 4), 256, 0, stream>>>(p, rankb, M);
        select_kernel<<<4, 256, 0, stream>>>(rankb, idx0, idx1, M, k_new, cross);
    }
}

// Round 3
// 862.632 us; speedup vs baseline: 2.8588x; 1.8179x over previous
//
#include <hip/hip_runtime.h>
#include <cstdint>
#include <cstddef>

// ---------------------------------------------------------------------------
// SDHGNN round 3: attention via MFMA with split-bf16 (hi/lo) 3-pass products
// for fp32-grade precision (top-k ordering must not flip).
// z = stream*2 + batch (Z=4). Head channel d = i*NH + h.
// ---------------------------------------------------------------------------

#define NB 2
#define ND 128
#define NH 4
#define NN 2048
#define ND2 256
#define DN (ND*NN)
#define BDN (NB*DN)
#define QK_SCALE 0.17677669529663687f
#define IN_EPS 1e-3f

typedef __attribute__((ext_vector_type(8))) short short8;
typedef __attribute__((ext_vector_type(4))) float f32x4;

__device__ __forceinline__ unsigned short f2bf(float f) {
    unsigned u = __float_as_uint(f);
    return (unsigned short)((u + 0x7fffu + ((u >> 16) & 1u)) >> 16);
}
__device__ __forceinline__ float bf2f(unsigned short h) {
    return __uint_as_float(((unsigned)h) << 16);
}

// ---------------------------------------------------------------------------
__global__ __launch_bounds__(256) void init_kernel(
    const float* __restrict__ x0in, const float* __restrict__ x1in,
    float* __restrict__ out, int* __restrict__ idx0, int* __restrict__ idx1)
{
    int tid = blockIdx.x * 256 + threadIdx.x;
    const float4* a = (const float4*)x0in;
    const float4* b = (const float4*)x1in;
    float4* o = (float4*)out;
    o[tid] = a[tid];
    o[BDN/4 + tid] = b[tid];
    if (tid < NB*NN) {
        int v = tid & (NN-1);
        idx0[tid] = v;
        idx1[tid] = v;
    }
}

__global__ __launch_bounds__(256) void zerop_kernel(float* __restrict__ p)
{
    p[blockIdx.x * 256 + threadIdx.x] = 0.f;
}

// ---------------------------------------------------------------------------
__global__ __launch_bounds__(256) void gather_kernel(
    const float* __restrict__ x, const int* __restrict__ idx0,
    const int* __restrict__ idx1, float* __restrict__ s, int mbits, int cross)
{
    int tid = blockIdx.x * 256 + threadIdx.x;
    int M = 1 << mbits;
    int m = tid & (M - 1);
    int zd = tid >> mbits;
    int d = zd & (ND - 1), z = zd >> 7;
    int st = z >> 1, b = z & 1;
    int ss = cross ? 1 - st : st;
    const int* idx = (ss ? idx1 : idx0) + b * NN;
    s[tid] = x[((size_t)(ss*2 + b) * ND + d) * NN + idx[m]];
}

// ---------------------------------------------------------------------------
// fp32 GEMM (unchanged from round 2): out[z][o][n] (+)= W*f(in) + bias
// ---------------------------------------------------------------------------
__global__ __launch_bounds__(256) void gemm64_kernel(
    const float* __restrict__ W, int ldw, const float* __restrict__ bias,
    const float* __restrict__ in1, const float* __restrict__ in2, int split,
    int in_zs, const float* __restrict__ nmean, const float* __restrict__ ninv,
    float* __restrict__ out, int out_zs, int Cin, int nCols, int acc_flag)
{
    __shared__ float As[16][68];
    __shared__ float Bs[16][68];
    const int z  = blockIdx.z;
    const int r0 = blockIdx.y * 64;
    const int n0 = blockIdx.x * 64;
    const int t  = threadIdx.x;
    const int tx4 = (t & 15) * 4, ty4 = (t >> 4) * 4;
    const int arow = t >> 2, ak4 = (t & 3) * 4;
    const int bk = t >> 4, bn4 = (t & 15) * 4;
    float acc[4][4] = {};

    for (int kc = 0; kc < Cin; kc += 16) {
        {
            float4 wv = *(const float4*)&W[(size_t)(r0 + arow) * ldw + kc + ak4];
            As[ak4+0][arow] = wv.x; As[ak4+1][arow] = wv.y;
            As[ak4+2][arow] = wv.z; As[ak4+3][arow] = wv.w;
        }
        {
            int c = kc + bk;
            const float* src = in1; int cc = c;
            if (in2 && c >= split) { src = in2; cc = c - split; }
            float4 v = *(const float4*)&src[(size_t)z*in_zs + (size_t)cc*nCols + n0 + bn4];
            if (nmean) {
                float m = nmean[z*Cin + c], iv = ninv[z*Cin + c];
                v.x = (v.x - m)*iv; v.y = (v.y - m)*iv;
                v.z = (v.z - m)*iv; v.w = (v.w - m)*iv;
                v.x = v.x > 0.f ? v.x : 0.f; v.y = v.y > 0.f ? v.y : 0.f;
                v.z = v.z > 0.f ? v.z : 0.f; v.w = v.w > 0.f ? v.w : 0.f;
            }
            *(float4*)&Bs[bk][bn4] = v;
        }
        __syncthreads();
        #pragma unroll
        for (int kk = 0; kk < 16; ++kk) {
            float4 av = *(const float4*)&As[kk][ty4];
            float4 bv = *(const float4*)&Bs[kk][tx4];
            const float* aa = (const float*)&av;
            const float* bb = (const float*)&bv;
            #pragma unroll
            for (int j = 0; j < 4; ++j)
                #pragma unroll
                for (int w = 0; w < 4; ++w)
                    acc[j][w] = fmaf(aa[j], bb[w], acc[j][w]);
        }
        __syncthreads();
    }

    #pragma unroll
    for (int j = 0; j < 4; ++j) {
        int row = r0 + ty4 + j;
        float bv = bias ? bias[row] : 0.f;
        size_t oi = (size_t)z*out_zs + (size_t)row*nCols + n0 + tx4;
        float4 res;
        res.x = acc[j][0] + bv; res.y = acc[j][1] + bv;
        res.z = acc[j][2] + bv; res.w = acc[j][3] + bv;
        if (acc_flag) {
            float4 o = *(const float4*)&out[oi];
            res.x += o.x; res.y += o.y; res.z += o.z; res.w += o.w;
        }
        *(float4*)&out[oi] = res;
    }
}

// ---------------------------------------------------------------------------
// repack with transpose: in [z][128][C] fp32 -> out hi/lo [zh][C][32] bf16
// (row = column index n/m, 32 dh contiguous), optional scale (QK fold).
// ---------------------------------------------------------------------------
__global__ __launch_bounds__(256) void repack_t_kernel(
    const float* __restrict__ in, unsigned short* __restrict__ ohi,
    unsigned short* __restrict__ olo, int C, float scale)
{
    __shared__ float tile[32][68];
    int zh = blockIdx.y;
    int h = zh & 3, z = zh >> 2;
    int n0 = blockIdx.x * 64;
    int t = threadIdx.x;
    {
        int i = t >> 3, nc = (t & 7) * 8;
        const float* src = &in[((size_t)z*ND + i*NH + h)*C + n0 + nc];
        float4 a = *(const float4*)src;
        float4 b = *(const float4*)(src + 4);
        tile[i][nc+0]=a.x*scale; tile[i][nc+1]=a.y*scale;
        tile[i][nc+2]=a.z*scale; tile[i][nc+3]=a.w*scale;
        tile[i][nc+4]=b.x*scale; tile[i][nc+5]=b.y*scale;
        tile[i][nc+6]=b.z*scale; tile[i][nc+7]=b.w*scale;
    }
    __syncthreads();
    int n = t >> 2, i8 = (t & 3) * 8;
    short8 hi, lo;
    #pragma unroll
    for (int j = 0; j < 8; ++j) {
        float v = tile[i8 + j][n];
        unsigned short hb = f2bf(v);
        hi[j] = (short)hb;
        lo[j] = (short)f2bf(v - bf2f(hb));
    }
    size_t ob = ((size_t)zh * C + n0 + n) * 32 + i8;
    *(short8*)&ohi[ob] = hi;
    *(short8*)&olo[ob] = lo;
}

// ---------------------------------------------------------------------------
// repack V (no transpose): in [z][128][M] fp32 -> out hi/lo [zh][32][M] bf16
// ---------------------------------------------------------------------------
__global__ __launch_bounds__(256) void repack_v_kernel(
    const float* __restrict__ in, unsigned short* __restrict__ ohi,
    unsigned short* __restrict__ olo, int M)
{
    int tid = blockIdx.x * 256 + threadIdx.x;
    int per = M >> 3;
    int m8 = (tid % per) * 8;
    int zd = tid / per;
    int d = zd & (ND-1), z = zd >> 7;
    int i = d >> 2, h = d & 3;
    const float* src = &in[(size_t)zd * M + m8];
    float4 a = *(const float4*)src;
    float4 b = *(const float4*)(src + 4);
    float vals[8] = {a.x,a.y,a.z,a.w,b.x,b.y,b.z,b.w};
    short8 hi, lo;
    #pragma unroll
    for (int j = 0; j < 8; ++j) {
        unsigned short hb = f2bf(vals[j]);
        hi[j] = (short)hb;
        lo[j] = (short)f2bf(vals[j] - bf2f(hb));
    }
    size_t ob = (((size_t)(z*4 + h))*32 + i) * M + m8;
    *(short8*)&ohi[ob] = hi;
    *(short8*)&olo[ob] = lo;
}

// ---------------------------------------------------------------------------
// MFMA attention. Block = (32-query tile, h, z); 4 waves.
// Wave roles: scores: (qt = w&1 16-query subtile) x (chalf = w>>1 32-col half)
//             PV:     (qt q-subtile) x (chalf dh-half), K-dim = chunk cols.
// Chunk = 64 source cols. Two-pass online softmax (exact m,l then probs).
// Split-bf16: X*Y ~= Xh*Yh + Xh*Yl + Xl*Yh  (fp32-grade).
// ---------------------------------------------------------------------------
__global__ __launch_bounds__(256) void attn_mfma_kernel(
    const unsigned short* __restrict__ qhi, const unsigned short* __restrict__ qlo,
    const unsigned short* __restrict__ khi, const unsigned short* __restrict__ klo,
    const unsigned short* __restrict__ vhi, const unsigned short* __restrict__ vlo,
    int M, float* __restrict__ msg, float* __restrict__ p)
{
    __shared__ unsigned short ks[2][64][40];   // [plane][m][dh], pad 40
    __shared__ unsigned short vs[2][32][72];   // [plane][dh][m], pad 72
    __shared__ float Sb[32][68];               // scores then fp32 probs
    __shared__ unsigned short Pb[2][32][72];   // probs hi/lo [q][m]
    __shared__ float rowM[32], rowIV[32];

    const int t = threadIdx.x;
    const int lane = t & 63, wave = t >> 6;
    const int qt = wave & 1, chalf = wave >> 1;
    const int l15 = lane & 15, quad = lane >> 4;
    const int zh = blockIdx.z * 4 + blockIdx.y;
    const int n0 = blockIdx.x * 32;
    const int q_own = t >> 3, seg = t & 7;

    // persistent Q A-fragments (row = query, k = dh)
    size_t qbase = ((size_t)zh * NN + n0 + qt*16 + l15) * 32 + quad*8;
    const short8 qAh = *(const short8*)&qhi[qbase];
    const short8 qAl = *(const short8*)&qlo[qbase];

    const int nch = M >> 6;
    float rm_run = -1e30f, rl_run = 0.f;

    // ---------------- pass 1: exact (m, l) per query row ----------------
    for (int ch = 0; ch < nch; ++ch) {
        const int m0 = ch << 6;
        {   // stage K chunk (both planes)
            int mr = t >> 2, sg = (t & 3) * 8;
            size_t gb = ((size_t)zh * M + m0 + mr) * 32 + sg;
            *(short8*)&ks[0][mr][sg] = *(const short8*)&khi[gb];
            *(short8*)&ks[1][mr][sg] = *(const short8*)&klo[gb];
        }
        __syncthreads();
        #pragma unroll
        for (int ct = 0; ct < 2; ++ct) {
            int mt = chalf*32 + ct*16;
            short8 kh = *(const short8*)&ks[0][mt + l15][quad*8];
            short8 kl = *(const short8*)&ks[1][mt + l15][quad*8];
            f32x4 acc = {0.f, 0.f, 0.f, 0.f};
            acc = __builtin_amdgcn_mfma_f32_16x16x32_bf16(qAh, kl, acc, 0, 0, 0);
            acc = __builtin_amdgcn_mfma_f32_16x16x32_bf16(qAl, kh, acc, 0, 0, 0);
            acc = __builtin_amdgcn_mfma_f32_16x16x32_bf16(qAh, kh, acc, 0, 0, 0);
            #pragma unroll
            for (int r = 0; r < 4; ++r)
                Sb[qt*16 + quad*4 + r][mt + l15] = acc[r];
        }
        __syncthreads();
        {   // online (m,l) over this thread's 8 cols, reduce across 8 lanes
            float4 s0 = *(const float4*)&Sb[q_own][seg*8];
            float4 s1 = *(const float4*)&Sb[q_own][seg*8 + 4];
            float mx = fmaxf(fmaxf(fmaxf(s0.x,s0.y), fmaxf(s0.z,s0.w)),
                             fmaxf(fmaxf(s1.x,s1.y), fmaxf(s1.z,s1.w)));
            float sm = __expf(s0.x-mx) + __expf(s0.y-mx) + __expf(s0.z-mx) + __expf(s0.w-mx)
                     + __expf(s1.x-mx) + __expf(s1.y-mx) + __expf(s1.z-mx) + __expf(s1.w-mx);
            float cm = mx, cl = sm;
            #pragma unroll
            for (int o = 1; o < 8; o <<= 1) {
                float om = __shfl_xor(cm, o, 64);
                float ol = __shfl_xor(cl, o, 64);
                float nm = fmaxf(cm, om);
                cl = cl * __expf(cm - nm) + ol * __expf(om - nm);
                cm = nm;
            }
            float nm = fmaxf(rm_run, cm);
            rl_run = rl_run * __expf(rm_run - nm) + cl * __expf(cm - nm);
            rm_run = nm;
        }
    }
    if (seg == 0) { rowM[q_own] = rm_run; rowIV[q_own] = 1.f / rl_run; }
    __syncthreads();
    const float myRM = rowM[q_own], myRIV = rowIV[q_own];

    // ---------------- pass 2: probs, p column-sums, PV ----------------
    f32x4 oacc = {0.f, 0.f, 0.f, 0.f};
    for (int ch = 0; ch < nch; ++ch) {
        const int m0 = ch << 6;
        {   // stage K + V chunks
            int mr = t >> 2, sg = (t & 3) * 8;
            size_t gb = ((size_t)zh * M + m0 + mr) * 32 + sg;
            *(short8*)&ks[0][mr][sg] = *(const short8*)&khi[gb];
            *(short8*)&ks[1][mr][sg] = *(const short8*)&klo[gb];
            int dh = t >> 3, sg2 = (t & 7) * 8;
            size_t vb_ = ((size_t)zh * 32 + dh) * M + m0 + sg2;
            *(short8*)&vs[0][dh][sg2] = *(const short8*)&vhi[vb_];
            *(short8*)&vs[1][dh][sg2] = *(const short8*)&vlo[vb_];
        }
        __syncthreads();
        #pragma unroll
        for (int ct = 0; ct < 2; ++ct) {   // scores -> Sb
            int mt = chalf*32 + ct*16;
            short8 kh = *(const short8*)&ks[0][mt + l15][quad*8];
            short8 kl = *(const short8*)&ks[1][mt + l15][quad*8];
            f32x4 acc = {0.f, 0.f, 0.f, 0.f};
            acc = __builtin_amdgcn_mfma_f32_16x16x32_bf16(qAh, kl, acc, 0, 0, 0);
            acc = __builtin_amdgcn_mfma_f32_16x16x32_bf16(qAl, kh, acc, 0, 0, 0);
            acc = __builtin_amdgcn_mfma_f32_16x16x32_bf16(qAh, kh, acc, 0, 0, 0);
            #pragma unroll
            for (int r = 0; r < 4; ++r)
                Sb[qt*16 + quad*4 + r][mt + l15] = acc[r];
        }
        __syncthreads();
        {   // probs: fp32 back into Sb (for p sums) + bf16 hi/lo into Pb
            float4 s0 = *(const float4*)&Sb[q_own][seg*8];
            float4 s1 = *(const float4*)&Sb[q_own][seg*8 + 4];
            float pr[8];
            pr[0] = __expf(s0.x - myRM) * myRIV; pr[1] = __expf(s0.y - myRM) * myRIV;
            pr[2] = __expf(s0.z - myRM) * myRIV; pr[3] = __expf(s0.w - myRM) * myRIV;
            pr[4] = __expf(s1.x - myRM) * myRIV; pr[5] = __expf(s1.y - myRM) * myRIV;
            pr[6] = __expf(s1.z - myRM) * myRIV; pr[7] = __expf(s1.w - myRM) * myRIV;
            float4 w0 = {pr[0], pr[1], pr[2], pr[3]};
            float4 w1 = {pr[4], pr[5], pr[6], pr[7]};
            *(float4*)&Sb[q_own][seg*8]     = w0;
            *(float4*)&Sb[q_own][seg*8 + 4] = w1;
            short8 ph, pl_;
            #pragma unroll
            for (int j = 0; j < 8; ++j) {
                unsigned short hb = f2bf(pr[j]);
                ph[j] = (short)hb;
                pl_[j] = (short)f2bf(pr[j] - bf2f(hb));
            }
            *(short8*)&Pb[0][q_own][seg*8] = ph;
            *(short8*)&Pb[1][q_own][seg*8] = pl_;
        }
        __syncthreads();
        if (t < 64) {   // p column sums (fp32)
            float su = 0.f;
            #pragma unroll
            for (int qq = 0; qq < 32; ++qq) su += Sb[qq][t];
            atomicAdd(&p[(size_t)blockIdx.z * NN + m0 + t], su * 0.25f);
        }
        #pragma unroll
        for (int ksb = 0; ksb < 2; ++ksb) {   // PV
            int ml = ksb * 32;
            short8 vAh = *(const short8*)&vs[0][chalf*16 + l15][ml + quad*8];
            short8 vAl = *(const short8*)&vs[1][chalf*16 + l15][ml + quad*8];
            short8 pBh = *(const short8*)&Pb[0][qt*16 + l15][ml + quad*8];
            short8 pBl = *(const short8*)&Pb[1][qt*16 + l15][ml + quad*8];
            oacc = __builtin_amdgcn_mfma_f32_16x16x32_bf16(vAh, pBl, oacc, 0, 0, 0);
            oacc = __builtin_amdgcn_mfma_f32_16x16x32_bf16(vAl, pBh, oacc, 0, 0, 0);
            oacc = __builtin_amdgcn_mfma_f32_16x16x32_bf16(vAh, pBh, oacc, 0, 0, 0);
        }
        __syncthreads();
    }
    #pragma unroll
    for (int r = 0; r < 4; ++r) {   // msg: d = dh*NH + h
        int dh = chalf*16 + quad*4 + r;
        msg[((size_t)blockIdx.z * ND + dh*NH + blockIdx.y) * NN + n0 + qt*16 + l15] = oacc[r];
    }
}

// ---------------------------------------------------------------------------
__global__ __launch_bounds__(256) void stats_kernel(
    const float* __restrict__ zbuf, float* __restrict__ mean, float* __restrict__ inv)
{
    int bc = blockIdx.x;
    const float* row = zbuf + (size_t)bc * NN;
    __shared__ float red[256];
    __shared__ float m_s;
    int t = threadIdx.x;
    float s = 0.f;
    for (int i = t; i < NN; i += 256) s += row[i];
    red[t] = s; __syncthreads();
    for (int o = 128; o > 0; o >>= 1) {
        if (t < o) red[t] += red[t + o];
        __syncthreads();
    }
    if (t == 0) { m_s = red[0] * (1.f / NN); mean[bc] = m_s; }
    __syncthreads();
    float m = m_s;
    float ss = 0.f;
    for (int i = t; i < NN; i += 256) { float d = row[i] - m; ss = fmaf(d, d, ss); }
    red[t] = ss; __syncthreads();
    for (int o = 128; o > 0; o >>= 1) {
        if (t < o) red[t] += red[t + o];
        __syncthreads();
    }
    if (t == 0) inv[bc] = 1.f / sqrtf(red[0] * (1.f / NN) + IN_EPS);
}

// ---------------------------------------------------------------------------
__global__ __launch_bounds__(256) void rank_kernel(
    const float* __restrict__ p, int* __restrict__ rank, int M)
{
    int zz = blockIdx.y;
    __shared__ float pv[2048];
    for (int i = threadIdx.x; i < M; i += 256) pv[i] = p[(size_t)zz*NN + i];
    __syncthreads();
    int i = blockIdx.x * 256 + threadIdx.x;
    if (i < M) {
        float pi = pv[i];
        int r = 0;
        for (int j = 0; j < M; ++j) {
            float pj = pv[j];
            r += (pj > pi) ? 1 : ((pj == pi && j < i) ? 1 : 0);
        }
        rank[zz*NN + i] = r;
    }
}

__global__ __launch_bounds__(256) void select_kernel(
    const int* __restrict__ rank, int* __restrict__ idx0, int* __restrict__ idx1,
    int M, int k, int cross)
{
    int z = blockIdx.x;
    int st = z >> 1, b = z & 1;
    int ts = cross ? 1 - st : st;
    int* idx = (ts ? idx1 : idx0) + b * NN;
    const int* rk = rank + z * NN;
    __shared__ int sel[2048], idv[2048], sa[2048], sb[2048];
    int t = threadIdx.x;
    for (int i = t; i < M; i += 256) {
        int s = rk[i] < k ? 1 : 0;
        sel[i] = s;
        sa[i] = s;
        idv[i] = idx[i];
    }
    __syncthreads();
    int* src = sa; int* dst = sb;
    for (int off = 1; off < M; off <<= 1) {
        for (int i = t; i < M; i += 256)
            dst[i] = src[i] + (i >= off ? src[i - off] : 0);
        __syncthreads();
        int* tmp = src; src = dst; dst = tmp;
    }
    for (int i = t; i < M; i += 256)
        if (sel[i]) idx[src[i] - 1] = idv[i];
}

// ---------------------------------------------------------------------------
extern "C" void kernel_launch(void* const* d_in, const int* in_sizes, int n_in,
                              void* d_out, int out_size, void* d_ws, size_t ws_size,
                              hipStream_t stream)
{
    const float* x0in = (const float*)d_in[0];
    const float* x1in = (const float*)d_in[1];
    const float* Wq = (const float*)d_in[2];
    const float* bq = (const float*)d_in[3];
    const float* Wk = (const float*)d_in[4];
    const float* bk = (const float*)d_in[5];
    const float* Wv = (const float*)d_in[6];
    const float* bv = (const float*)d_in[7];
    const float* Wm = (const float*)d_in[8];
    const float* bm = (const float*)d_in[9];
    const float* W1 = (const float*)d_in[10];
    const float* b1 = (const float*)d_in[11];
    const float* W2 = (const float*)d_in[12];
    const float* b2 = (const float*)d_in[13];

    float* out = (float*)d_out;
    float* ws  = (float*)d_ws;

    // ws layout: 5 x 1M-float buffers + tail.
    //  buf0: gather s -> k_t planes -> zb(lo half)
    //  buf1: k fp32   -> v_t planes -> zb(hi half)
    //  buf2: v fp32   -> msg
    //  buf3: q fp32   -> m2
    //  buf4: q_t planes
    const size_t MB1 = 1048576;
    float* buf0 = ws;
    float* buf1 = ws + MB1;
    float* buf2 = ws + 2*MB1;
    float* buf3 = ws + 3*MB1;
    float* buf4 = ws + 4*MB1;
    float* meanb = ws + 5*MB1;          // Z*256
    float* invb  = meanb + 1024;
    float* p     = invb + 1024;         // Z*NN
    int* idx0 = (int*)(p + 4*NN);
    int* idx1 = idx0 + NB*NN;
    int* rankb = idx1 + NB*NN;

    init_kernel<<<BDN/4/256, 256, 0, stream>>>(x0in, x1in, out, idx0, idx1);

    const int Ms[4] = {2048, 1024, 512, 256};
    const int Mb[4] = {11, 10, 9, 8};
    for (int l = 0; l < 4; ++l) {
        int M = Ms[l];
        int k_new = (M/2 < 128) ? 128 : M/2;
        int cross = l & 1;

        gather_kernel<<<(4*ND*M)/256, 256, 0, stream>>>(out, idx0, idx1, buf0, Mb[l], cross);
        zerop_kernel<<<4*NN/256, 256, 0, stream>>>(p);

        // q,k,v projections (fp32)
        gemm64_kernel<<<dim3(NN/64, 2, 4), 256, 0, stream>>>(
            Wq + (size_t)l*ND*ND, ND, bq + l*ND,
            out, nullptr, 0, DN, nullptr, nullptr, buf3, DN, ND, NN, 0);
        gemm64_kernel<<<dim3(M/64, 2, 4), 256, 0, stream>>>(
            Wk + (size_t)l*ND*ND, ND, bk + l*ND,
            buf0, nullptr, 0, ND*M, nullptr, nullptr, buf1, ND*M, ND, M, 0);
        gemm64_kernel<<<dim3(M/64, 2, 4), 256, 0, stream>>>(
            Wv + (size_t)l*ND*ND, ND, bv + l*ND,
            buf0, nullptr, 0, ND*M, nullptr, nullptr, buf2, ND*M, ND, M, 0);

        // repack to bf16 hi/lo frag-ready planes
        unsigned short* qthi = (unsigned short*)buf4;
        unsigned short* qtlo = qthi + MB1;
        unsigned short* kthi = (unsigned short*)buf0;   // gather s is dead
        unsigned short* ktlo = kthi + (size_t)512*M;    // plane = 4*4*M*32 = 512*M
        unsigned short* vthi = (unsigned short*)buf1;   // k fp32 dead after repack_t
        unsigned short* vtlo = vthi + (size_t)512*M;
        repack_t_kernel<<<dim3(NN/64, 16), 256, 0, stream>>>(buf3, qthi, qtlo, NN, QK_SCALE);
        repack_t_kernel<<<dim3(M/64, 16), 256, 0, stream>>>(buf1, kthi, ktlo, M, 1.0f);
        repack_v_kernel<<<dim3((4*ND*M)/(8*256)), 256, 0, stream>>>(buf2, vthi, vtlo, M);

        // attention (msg -> buf2; v fp32 dead)
        attn_mfma_kernel<<<dim3(NN/32, NH, 4), 256, 0, stream>>>(
            qthi, qtlo, kthi, ktlo, vthi, vtlo, M, buf2, p);

        // m2 = Wm msg + bm   (buf2 -> buf3)
        gemm64_kernel<<<dim3(NN/64, 2, 4), 256, 0, stream>>>(
            Wm + (size_t)l*ND*ND, ND, bm + l*ND,
            buf2, nullptr, 0, DN, nullptr, nullptr, buf3, DN, ND, NN, 0);

        // z = W1 [x ; m2] + b1  -> buf0..buf1 (8 MB contiguous)
        gemm64_kernel<<<dim3(NN/64, 4, 4), 256, 0, stream>>>(
            W1 + (size_t)l*ND2*ND2, ND2, b1 + l*ND2,
            out, buf3, ND, DN, nullptr, nullptr, buf0, 2*DN, ND2, NN, 0);

        stats_kernel<<<4*ND2, 256, 0, stream>>>(buf0, meanb, invb);

        // x += W2 relu(instnorm(z)) + b2
        gemm64_kernel<<<dim3(NN/64, 2, 4), 256, 0, stream>>>(
            W2 + (size_t)l*ND*ND2, ND2, b2 + l*ND,
            buf0, nullptr, 0, 2*DN, meanb, invb, out, DN, ND2, NN, 1);

        rank_kernel<<<dim3((M+255)/256, 4), 256, 0, stream>>>(p, rankb, M);
        select_kernel<<<4, 256, 0, stream>>>(rankb, idx0, idx1, M, k_new, cross);
    }
}

// Round 4
// 824.079 us; speedup vs baseline: 2.9925x; 1.0468x over previous
//
#include <hip/hip_runtime.h>
#include <cstdint>
#include <cstddef>

// ---------------------------------------------------------------------------
// SDHGNN round 4: all GEMMs via MFMA split-bf16 (hi/lo 3-term, fp32-grade).
// Activations as channel-minor bf16 planes [z][n][C]; weights pre-split.
// Attention kernel identical to round 3. z = stream*2 + batch (Z=4).
// ---------------------------------------------------------------------------

#define NB 2
#define ND 128
#define NH 4
#define NN 2048
#define ND2 256
#define DN (ND*NN)
#define BDN (NB*DN)
#define QK_SCALE 0.17677669529663687f
#define IN_EPS 1e-3f

typedef unsigned short u16;
typedef __attribute__((ext_vector_type(8))) short short8;
typedef __attribute__((ext_vector_type(4))) float f32x4;

__device__ __forceinline__ u16 f2bf(float f) {
    unsigned u = __float_as_uint(f);
    return (u16)((u + 0x7fffu + ((u >> 16) & 1u)) >> 16);
}
__device__ __forceinline__ float bf2f(u16 h) {
    return __uint_as_float(((unsigned)h) << 16);
}

// ---------------------------------------------------------------------------
__global__ __launch_bounds__(256) void init_kernel(
    const float* __restrict__ x0in, const float* __restrict__ x1in,
    float* __restrict__ out, int* __restrict__ idx0, int* __restrict__ idx1)
{
    int tid = blockIdx.x * 256 + threadIdx.x;
    const float4* a = (const float4*)x0in;
    const float4* b = (const float4*)x1in;
    float4* o = (float4*)out;
    o[tid] = a[tid];
    o[BDN/4 + tid] = b[tid];
    if (tid < NB*NN) {
        int v = tid & (NN-1);
        idx0[tid] = v;
        idx1[tid] = v;
    }
}

__global__ __launch_bounds__(256) void zerop_kernel(float* __restrict__ p)
{
    p[blockIdx.x * 256 + threadIdx.x] = 0.f;
}

// ---------------------------------------------------------------------------
// weights -> bf16 hi/lo planes, all 4 layers in one dispatch.
// per-layer flat: Wq(16384) Wk Wv Wm | W1(65536) | W2(32768) = 163840.
// ---------------------------------------------------------------------------
__global__ __launch_bounds__(256) void wrepack_kernel(
    const float* __restrict__ Wq, const float* __restrict__ Wk,
    const float* __restrict__ Wv, const float* __restrict__ Wm,
    const float* __restrict__ W1, const float* __restrict__ W2,
    u16* __restrict__ whi, u16* __restrict__ wlo)
{
    int e = blockIdx.x * 256 + threadIdx.x;      // 655360 total
    int l = e / 163840;
    int r = e - l * 163840;
    float v;
    if      (r <  16384) v = Wq[l*16384 + r];
    else if (r <  32768) v = Wk[l*16384 + r - 16384];
    else if (r <  49152) v = Wv[l*16384 + r - 32768];
    else if (r <  65536) v = Wm[l*16384 + r - 49152];
    else if (r < 131072) v = W1[l*65536 + r - 65536];
    else                 v = W2[l*32768 + r - 131072];
    u16 h = f2bf(v);
    whi[e] = h;
    wlo[e] = f2bf(v - bf2f(h));
}

// ---------------------------------------------------------------------------
// fp32 [z][C][NN] -> bf16 hi/lo planes [z][n][C], optional instnorm+relu.
// block: 32 channels x 64 n. grid (NN/64, 4*(C/32)).
// ---------------------------------------------------------------------------
__global__ __launch_bounds__(256) void repack_xh_kernel(
    const float* __restrict__ in, u16* __restrict__ ohi, u16* __restrict__ olo,
    int C, const float* __restrict__ nmean, const float* __restrict__ ninv)
{
    __shared__ float tile[32][68];
    int ncg = C >> 5;
    int z = blockIdx.y / ncg, cg = blockIdx.y % ncg;
    int n0 = blockIdx.x * 64;
    int t = threadIdx.x;
    {
        int i = t >> 3, nc = (t & 7) * 8;
        int c = cg*32 + i;
        const float* src = &in[((size_t)z*C + c)*NN + n0 + nc];
        float4 a = *(const float4*)src;
        float4 b = *(const float4*)(src + 4);
        if (nmean) {
            float m = nmean[z*C + c], iv = ninv[z*C + c];
            a.x=(a.x-m)*iv; a.y=(a.y-m)*iv; a.z=(a.z-m)*iv; a.w=(a.w-m)*iv;
            b.x=(b.x-m)*iv; b.y=(b.y-m)*iv; b.z=(b.z-m)*iv; b.w=(b.w-m)*iv;
            a.x=a.x>0.f?a.x:0.f; a.y=a.y>0.f?a.y:0.f; a.z=a.z>0.f?a.z:0.f; a.w=a.w>0.f?a.w:0.f;
            b.x=b.x>0.f?b.x:0.f; b.y=b.y>0.f?b.y:0.f; b.z=b.z>0.f?b.z:0.f; b.w=b.w>0.f?b.w:0.f;
        }
        tile[i][nc+0]=a.x; tile[i][nc+1]=a.y; tile[i][nc+2]=a.z; tile[i][nc+3]=a.w;
        tile[i][nc+4]=b.x; tile[i][nc+5]=b.y; tile[i][nc+6]=b.z; tile[i][nc+7]=b.w;
    }
    __syncthreads();
    int n = t >> 2, c8 = (t & 3) * 8;
    short8 hi, lo;
    #pragma unroll
    for (int j = 0; j < 8; ++j) {
        float v = tile[c8 + j][n];
        u16 h = f2bf(v);
        hi[j] = (short)h;
        lo[j] = (short)f2bf(v - bf2f(h));
    }
    size_t ob = ((size_t)z*NN + n0 + n)*C + cg*32 + c8;
    *(short8*)&ohi[ob] = hi;
    *(short8*)&olo[ob] = lo;
}

// ---------------------------------------------------------------------------
// gather: s planes [z][m][128] = x planes row idx[m] (coalesced row copies)
// ---------------------------------------------------------------------------
__global__ __launch_bounds__(256) void gather_rows_kernel(
    const u16* __restrict__ xphi, const u16* __restrict__ xplo,
    const int* __restrict__ idx0, const int* __restrict__ idx1,
    u16* __restrict__ sphi, u16* __restrict__ splo, int mbits, int cross)
{
    int tid = blockIdx.x * 256 + threadIdx.x;
    int c8 = (tid & 15) * 8;
    int plane = (tid >> 4) & 1;
    int M = 1 << mbits;
    int m = (tid >> 5) & (M - 1);
    int z = tid >> (5 + mbits);
    int st = z >> 1, b = z & 1;
    int ss = cross ? 1 - st : st;
    const int* idx = (ss ? idx1 : idx0) + b * NN;
    int n = idx[m];
    const u16* xp = plane ? xplo : xphi;
    u16* sp = plane ? splo : sphi;
    short8 v = *(const short8*)&xp[((size_t)(ss*2 + b)*NN + n)*128 + c8];
    *(short8*)&sp[((size_t)z*M + m)*128 + c8] = v;
}

// ---------------------------------------------------------------------------
// MFMA GEMM, split-bf16 3-term. Tile 64 rows(Cout) x 128 cols(n), K-chunk 32.
// A: weight planes [Cout][Cin]; B: activation planes [z][n][s] (split sides).
// Wave w: rows (w&1)*32, cols (w>>1)*64; 2x4 16x16 subtiles, 24 MFMA/chunk.
// ---------------------------------------------------------------------------
__global__ __launch_bounds__(256) void gemm_mfma_kernel(
    const u16* __restrict__ Whi, const u16* __restrict__ Wlo, int ldw,
    const float* __restrict__ bias,
    const u16* __restrict__ B1hi, const u16* __restrict__ B1lo, int s1,
    const u16* __restrict__ B2hi, const u16* __restrict__ B2lo, int s2, int split,
    int Cin, int nCols, float* __restrict__ out, int out_zs, int acc_flag)
{
    __shared__ u16 As[2][64][40];
    __shared__ u16 Bs[2][128][40];
    const int z  = blockIdx.z;
    const int o0 = blockIdx.y * 64;
    const int n0 = blockIdx.x * 128;
    const int t  = threadIdx.x;
    const int lane = t & 63, w = t >> 6;
    const int l15 = lane & 15, quad = lane >> 4;
    const int wr = (w & 1) * 32, wc = (w >> 1) * 64;

    f32x4 acc[2][4];
    #pragma unroll
    for (int a = 0; a < 2; ++a)
        #pragma unroll
        for (int c = 0; c < 4; ++c) acc[a][c] = (f32x4){0.f,0.f,0.f,0.f};

    const int ao = t >> 2, ak = (t & 3) * 8;

    for (int kc = 0; kc < Cin; kc += 32) {
        {   // A tile 64x32, both planes
            size_t wa = (size_t)(o0 + ao) * ldw + kc + ak;
            *(short8*)&As[0][ao][ak] = *(const short8*)&Whi[wa];
            *(short8*)&As[1][ao][ak] = *(const short8*)&Wlo[wa];
        }
        #pragma unroll
        for (int r = 0; r < 2; ++r) {   // B tile 128x32
            int nl = (t >> 2) + r*64;
            int c = kc + ak;
            size_t off;
            const u16 *ph, *pl_;
            if (c < split) { off = ((size_t)z*nCols + n0 + nl)*s1 + c; ph = B1hi; pl_ = B1lo; }
            else { off = ((size_t)z*nCols + n0 + nl)*s2 + (c - split); ph = B2hi; pl_ = B2lo; }
            *(short8*)&Bs[0][nl][ak] = *(const short8*)&ph[off];
            *(short8*)&Bs[1][nl][ak] = *(const short8*)&pl_[off];
        }
        __syncthreads();
        short8 Ah[2], Al[2], Bh[4], Bl[4];
        #pragma unroll
        for (int a = 0; a < 2; ++a) {
            Ah[a] = *(const short8*)&As[0][wr + a*16 + l15][quad*8];
            Al[a] = *(const short8*)&As[1][wr + a*16 + l15][quad*8];
        }
        #pragma unroll
        for (int c = 0; c < 4; ++c) {
            Bh[c] = *(const short8*)&Bs[0][wc + c*16 + l15][quad*8];
            Bl[c] = *(const short8*)&Bs[1][wc + c*16 + l15][quad*8];
        }
        #pragma unroll
        for (int a = 0; a < 2; ++a)
            #pragma unroll
            for (int c = 0; c < 4; ++c) {
                acc[a][c] = __builtin_amdgcn_mfma_f32_16x16x32_bf16(Ah[a], Bl[c], acc[a][c], 0, 0, 0);
                acc[a][c] = __builtin_amdgcn_mfma_f32_16x16x32_bf16(Al[a], Bh[c], acc[a][c], 0, 0, 0);
                acc[a][c] = __builtin_amdgcn_mfma_f32_16x16x32_bf16(Ah[a], Bh[c], acc[a][c], 0, 0, 0);
            }
        __syncthreads();
    }

    #pragma unroll
    for (int a = 0; a < 2; ++a) {
        int ob = o0 + wr + a*16 + quad*4;
        #pragma unroll
        for (int c = 0; c < 4; ++c) {
            int n = n0 + wc + c*16 + l15;
            #pragma unroll
            for (int r = 0; r < 4; ++r) {
                int o = ob + r;
                size_t oi = (size_t)z*out_zs + (size_t)o*nCols + n;
                float v = acc[a][c][r] + bias[o];
                if (acc_flag) v += out[oi];
                out[oi] = v;
            }
        }
    }
}

// ---------------------------------------------------------------------------
// repack with transpose: q/k fp32 [z][128][C] -> hi/lo [zh][C][32]
// ---------------------------------------------------------------------------
__global__ __launch_bounds__(256) void repack_t_kernel(
    const float* __restrict__ in, u16* __restrict__ ohi,
    u16* __restrict__ olo, int C, float scale)
{
    __shared__ float tile[32][68];
    int zh = blockIdx.y;
    int h = zh & 3, z = zh >> 2;
    int n0 = blockIdx.x * 64;
    int t = threadIdx.x;
    {
        int i = t >> 3, nc = (t & 7) * 8;
        const float* src = &in[((size_t)z*ND + i*NH + h)*C + n0 + nc];
        float4 a = *(const float4*)src;
        float4 b = *(const float4*)(src + 4);
        tile[i][nc+0]=a.x*scale; tile[i][nc+1]=a.y*scale;
        tile[i][nc+2]=a.z*scale; tile[i][nc+3]=a.w*scale;
        tile[i][nc+4]=b.x*scale; tile[i][nc+5]=b.y*scale;
        tile[i][nc+6]=b.z*scale; tile[i][nc+7]=b.w*scale;
    }
    __syncthreads();
    int n = t >> 2, i8 = (t & 3) * 8;
    short8 hi, lo;
    #pragma unroll
    for (int j = 0; j < 8; ++j) {
        float v = tile[i8 + j][n];
        u16 hb = f2bf(v);
        hi[j] = (short)hb;
        lo[j] = (short)f2bf(v - bf2f(hb));
    }
    size_t ob = ((size_t)zh * C + n0 + n) * 32 + i8;
    *(short8*)&ohi[ob] = hi;
    *(short8*)&olo[ob] = lo;
}

// ---------------------------------------------------------------------------
// repack V: [z][128][M] fp32 -> hi/lo [zh][32][M]
// ---------------------------------------------------------------------------
__global__ __launch_bounds__(256) void repack_v_kernel(
    const float* __restrict__ in, u16* __restrict__ ohi,
    u16* __restrict__ olo, int M)
{
    int tid = blockIdx.x * 256 + threadIdx.x;
    int per = M >> 3;
    int m8 = (tid % per) * 8;
    int zd = tid / per;
    int d = zd & (ND-1), z = zd >> 7;
    int i = d >> 2, h = d & 3;
    const float* src = &in[(size_t)zd * M + m8];
    float4 a = *(const float4*)src;
    float4 b = *(const float4*)(src + 4);
    float vals[8] = {a.x,a.y,a.z,a.w,b.x,b.y,b.z,b.w};
    short8 hi, lo;
    #pragma unroll
    for (int j = 0; j < 8; ++j) {
        u16 hb = f2bf(vals[j]);
        hi[j] = (short)hb;
        lo[j] = (short)f2bf(vals[j] - bf2f(hb));
    }
    size_t ob = (((size_t)(z*4 + h))*32 + i) * M + m8;
    *(short8*)&ohi[ob] = hi;
    *(short8*)&olo[ob] = lo;
}

// ---------------------------------------------------------------------------
// MFMA attention (identical to round 3)
// ---------------------------------------------------------------------------
__global__ __launch_bounds__(256) void attn_mfma_kernel(
    const u16* __restrict__ qhi, const u16* __restrict__ qlo,
    const u16* __restrict__ khi, const u16* __restrict__ klo,
    const u16* __restrict__ vhi, const u16* __restrict__ vlo,
    int M, float* __restrict__ msg, float* __restrict__ p)
{
    __shared__ u16 ks[2][64][40];
    __shared__ u16 vs[2][32][72];
    __shared__ float Sb[32][68];
    __shared__ u16 Pb[2][32][72];
    __shared__ float rowM[32], rowIV[32];

    const int t = threadIdx.x;
    const int lane = t & 63, wave = t >> 6;
    const int qt = wave & 1, chalf = wave >> 1;
    const int l15 = lane & 15, quad = lane >> 4;
    const int zh = blockIdx.z * 4 + blockIdx.y;
    const int n0 = blockIdx.x * 32;
    const int q_own = t >> 3, seg = t & 7;

    size_t qbase = ((size_t)zh * NN + n0 + qt*16 + l15) * 32 + quad*8;
    const short8 qAh = *(const short8*)&qhi[qbase];
    const short8 qAl = *(const short8*)&qlo[qbase];

    const int nch = M >> 6;
    float rm_run = -1e30f, rl_run = 0.f;

    for (int ch = 0; ch < nch; ++ch) {
        const int m0 = ch << 6;
        {
            int mr = t >> 2, sg = (t & 3) * 8;
            size_t gb = ((size_t)zh * M + m0 + mr) * 32 + sg;
            *(short8*)&ks[0][mr][sg] = *(const short8*)&khi[gb];
            *(short8*)&ks[1][mr][sg] = *(const short8*)&klo[gb];
        }
        __syncthreads();
        #pragma unroll
        for (int ct = 0; ct < 2; ++ct) {
            int mt = chalf*32 + ct*16;
            short8 kh = *(const short8*)&ks[0][mt + l15][quad*8];
            short8 kl = *(const short8*)&ks[1][mt + l15][quad*8];
            f32x4 acc = {0.f, 0.f, 0.f, 0.f};
            acc = __builtin_amdgcn_mfma_f32_16x16x32_bf16(qAh, kl, acc, 0, 0, 0);
            acc = __builtin_amdgcn_mfma_f32_16x16x32_bf16(qAl, kh, acc, 0, 0, 0);
            acc = __builtin_amdgcn_mfma_f32_16x16x32_bf16(qAh, kh, acc, 0, 0, 0);
            #pragma unroll
            for (int r = 0; r < 4; ++r)
                Sb[qt*16 + quad*4 + r][mt + l15] = acc[r];
        }
        __syncthreads();
        {
            float4 s0 = *(const float4*)&Sb[q_own][seg*8];
            float4 s1 = *(const float4*)&Sb[q_own][seg*8 + 4];
            float mx = fmaxf(fmaxf(fmaxf(s0.x,s0.y), fmaxf(s0.z,s0.w)),
                             fmaxf(fmaxf(s1.x,s1.y), fmaxf(s1.z,s1.w)));
            float sm = __expf(s0.x-mx) + __expf(s0.y-mx) + __expf(s0.z-mx) + __expf(s0.w-mx)
                     + __expf(s1.x-mx) + __expf(s1.y-mx) + __expf(s1.z-mx) + __expf(s1.w-mx);
            float cm = mx, cl = sm;
            #pragma unroll
            for (int o = 1; o < 8; o <<= 1) {
                float om = __shfl_xor(cm, o, 64);
                float ol = __shfl_xor(cl, o, 64);
                float nm = fmaxf(cm, om);
                cl = cl * __expf(cm - nm) + ol * __expf(om - nm);
                cm = nm;
            }
            float nm = fmaxf(rm_run, cm);
            rl_run = rl_run * __expf(rm_run - nm) + cl * __expf(cm - nm);
            rm_run = nm;
        }
    }
    if (seg == 0) { rowM[q_own] = rm_run; rowIV[q_own] = 1.f / rl_run; }
    __syncthreads();
    const float myRM = rowM[q_own], myRIV = rowIV[q_own];

    f32x4 oacc = {0.f, 0.f, 0.f, 0.f};
    for (int ch = 0; ch < nch; ++ch) {
        const int m0 = ch << 6;
        {
            int mr = t >> 2, sg = (t & 3) * 8;
            size_t gb = ((size_t)zh * M + m0 + mr) * 32 + sg;
            *(short8*)&ks[0][mr][sg] = *(const short8*)&khi[gb];
            *(short8*)&ks[1][mr][sg] = *(const short8*)&klo[gb];
            int dh = t >> 3, sg2 = (t & 7) * 8;
            size_t vb_ = ((size_t)zh * 32 + dh) * M + m0 + sg2;
            *(short8*)&vs[0][dh][sg2] = *(const short8*)&vhi[vb_];
            *(short8*)&vs[1][dh][sg2] = *(const short8*)&vlo[vb_];
        }
        __syncthreads();
        #pragma unroll
        for (int ct = 0; ct < 2; ++ct) {
            int mt = chalf*32 + ct*16;
            short8 kh = *(const short8*)&ks[0][mt + l15][quad*8];
            short8 kl = *(const short8*)&ks[1][mt + l15][quad*8];
            f32x4 acc = {0.f, 0.f, 0.f, 0.f};
            acc = __builtin_amdgcn_mfma_f32_16x16x32_bf16(qAh, kl, acc, 0, 0, 0);
            acc = __builtin_amdgcn_mfma_f32_16x16x32_bf16(qAl, kh, acc, 0, 0, 0);
            acc = __builtin_amdgcn_mfma_f32_16x16x32_bf16(qAh, kh, acc, 0, 0, 0);
            #pragma unroll
            for (int r = 0; r < 4; ++r)
                Sb[qt*16 + quad*4 + r][mt + l15] = acc[r];
        }
        __syncthreads();
        {
            float4 s0 = *(const float4*)&Sb[q_own][seg*8];
            float4 s1 = *(const float4*)&Sb[q_own][seg*8 + 4];
            float pr[8];
            pr[0] = __expf(s0.x - myRM) * myRIV; pr[1] = __expf(s0.y - myRM) * myRIV;
            pr[2] = __expf(s0.z - myRM) * myRIV; pr[3] = __expf(s0.w - myRM) * myRIV;
            pr[4] = __expf(s1.x - myRM) * myRIV; pr[5] = __expf(s1.y - myRM) * myRIV;
            pr[6] = __expf(s1.z - myRM) * myRIV; pr[7] = __expf(s1.w - myRM) * myRIV;
            float4 w0 = {pr[0], pr[1], pr[2], pr[3]};
            float4 w1 = {pr[4], pr[5], pr[6], pr[7]};
            *(float4*)&Sb[q_own][seg*8]     = w0;
            *(float4*)&Sb[q_own][seg*8 + 4] = w1;
            short8 ph, pl_;
            #pragma unroll
            for (int j = 0; j < 8; ++j) {
                u16 hb = f2bf(pr[j]);
                ph[j] = (short)hb;
                pl_[j] = (short)f2bf(pr[j] - bf2f(hb));
            }
            *(short8*)&Pb[0][q_own][seg*8] = ph;
            *(short8*)&Pb[1][q_own][seg*8] = pl_;
        }
        __syncthreads();
        if (t < 64) {
            float su = 0.f;
            #pragma unroll
            for (int qq = 0; qq < 32; ++qq) su += Sb[qq][t];
            atomicAdd(&p[(size_t)blockIdx.z * NN + m0 + t], su * 0.25f);
        }
        #pragma unroll
        for (int ksb = 0; ksb < 2; ++ksb) {
            int ml = ksb * 32;
            short8 vAh = *(const short8*)&vs[0][chalf*16 + l15][ml + quad*8];
            short8 vAl = *(const short8*)&vs[1][chalf*16 + l15][ml + quad*8];
            short8 pBh = *(const short8*)&Pb[0][qt*16 + l15][ml + quad*8];
            short8 pBl = *(const short8*)&Pb[1][qt*16 + l15][ml + quad*8];
            oacc = __builtin_amdgcn_mfma_f32_16x16x32_bf16(vAh, pBl, oacc, 0, 0, 0);
            oacc = __builtin_amdgcn_mfma_f32_16x16x32_bf16(vAl, pBh, oacc, 0, 0, 0);
            oacc = __builtin_amdgcn_mfma_f32_16x16x32_bf16(vAh, pBh, oacc, 0, 0, 0);
        }
        __syncthreads();
    }
    #pragma unroll
    for (int r = 0; r < 4; ++r) {
        int dh = chalf*16 + quad*4 + r;
        msg[((size_t)blockIdx.z * ND + dh*NH + blockIdx.y) * NN + n0 + qt*16 + l15] = oacc[r];
    }
}

// ---------------------------------------------------------------------------
__global__ __launch_bounds__(256) void stats_kernel(
    const float* __restrict__ zbuf, float* __restrict__ mean, float* __restrict__ inv)
{
    int bc = blockIdx.x;
    const float* row = zbuf + (size_t)bc * NN;
    __shared__ float red[256];
    __shared__ float m_s;
    int t = threadIdx.x;
    float s = 0.f;
    for (int i = t; i < NN; i += 256) s += row[i];
    red[t] = s; __syncthreads();
    for (int o = 128; o > 0; o >>= 1) {
        if (t < o) red[t] += red[t + o];
        __syncthreads();
    }
    if (t == 0) { m_s = red[0] * (1.f / NN); mean[bc] = m_s; }
    __syncthreads();
    float m = m_s;
    float ss = 0.f;
    for (int i = t; i < NN; i += 256) { float d = row[i] - m; ss = fmaf(d, d, ss); }
    red[t] = ss; __syncthreads();
    for (int o = 128; o > 0; o >>= 1) {
        if (t < o) red[t] += red[t + o];
        __syncthreads();
    }
    if (t == 0) inv[bc] = 1.f / sqrtf(red[0] * (1.f / NN) + IN_EPS);
}

// ---------------------------------------------------------------------------
__global__ __launch_bounds__(256) void rank_kernel(
    const float* __restrict__ p, int* __restrict__ rank, int M)
{
    int zz = blockIdx.y;
    __shared__ float pv[2048];
    for (int i = threadIdx.x; i < M; i += 256) pv[i] = p[(size_t)zz*NN + i];
    __syncthreads();
    int i = blockIdx.x * 256 + threadIdx.x;
    if (i < M) {
        float pi = pv[i];
        int r = 0;
        for (int j = 0; j < M; ++j) {
            float pj = pv[j];
            r += (pj > pi) ? 1 : ((pj == pi && j < i) ? 1 : 0);
        }
        rank[zz*NN + i] = r;
    }
}

__global__ __launch_bounds__(256) void select_kernel(
    const int* __restrict__ rank, int* __restrict__ idx0, int* __restrict__ idx1,
    int M, int k, int cross)
{
    int z = blockIdx.x;
    int st = z >> 1, b = z & 1;
    int ts = cross ? 1 - st : st;
    int* idx = (ts ? idx1 : idx0) + b * NN;
    const int* rk = rank + z * NN;
    __shared__ int sel[2048], idv[2048], sa[2048], sb[2048];
    int t = threadIdx.x;
    for (int i = t; i < M; i += 256) {
        int s = rk[i] < k ? 1 : 0;
        sel[i] = s;
        sa[i] = s;
        idv[i] = idx[i];
    }
    __syncthreads();
    int* src = sa; int* dst = sb;
    for (int off = 1; off < M; off <<= 1) {
        for (int i = t; i < M; i += 256)
            dst[i] = src[i] + (i >= off ? src[i - off] : 0);
        __syncthreads();
        int* tmp = src; src = dst; dst = tmp;
    }
    for (int i = t; i < M; i += 256)
        if (sel[i]) idx[src[i] - 1] = idv[i];
}

// ---------------------------------------------------------------------------
extern "C" void kernel_launch(void* const* d_in, const int* in_sizes, int n_in,
                              void* d_out, int out_size, void* d_ws, size_t ws_size,
                              hipStream_t stream)
{
    const float* x0in = (const float*)d_in[0];
    const float* x1in = (const float*)d_in[1];
    const float* Wq = (const float*)d_in[2];
    const float* bq = (const float*)d_in[3];
    const float* Wk = (const float*)d_in[4];
    const float* bk = (const float*)d_in[5];
    const float* Wv = (const float*)d_in[6];
    const float* bv = (const float*)d_in[7];
    const float* Wm = (const float*)d_in[8];
    const float* bm = (const float*)d_in[9];
    const float* W1 = (const float*)d_in[10];
    const float* b1 = (const float*)d_in[11];
    const float* W2 = (const float*)d_in[12];
    const float* b2 = (const float*)d_in[13];

    float* out = (float*)d_out;
    float* ws  = (float*)d_ws;

    // 4MB slots (1Mi floats each):
    //  S0 x planes | S1 s planes -> m2 planes | S2 q -> msg -> h.hi
    //  S3 k -> msg planes -> h.lo | S4 v -> m2 fp32 | S5 qt (later z lo)
    //  S6 kt (later z hi) | S7 vt | S8 weight planes | tail
    const size_t MB1 = 1048576;
    u16* xphi = (u16*)ws;                 u16* xplo = xphi + MB1;
    float* S1 = ws + 1*MB1;
    float* S2 = ws + 2*MB1;
    float* S3 = ws + 3*MB1;
    float* S4 = ws + 4*MB1;
    float* S5 = ws + 5*MB1;
    float* S6 = ws + 6*MB1;
    float* S7 = ws + 7*MB1;
    u16* whi = (u16*)(ws + 8*MB1);        u16* wlo = whi + 655360;
    float* meanb = ws + 9*MB1;            // Z*256
    float* invb  = meanb + 1024;
    float* p     = invb + 1024;           // Z*NN
    int* idx0 = (int*)(p + 4*NN);
    int* idx1 = idx0 + NB*NN;
    int* rankb = idx1 + NB*NN;

    u16* hphi = (u16*)S2;  u16* hplo = hphi + 2*MB1;   // 256-ch planes (S2+S3)
    u16* mphi = (u16*)S3;  u16* mplo = mphi + MB1;     // msg planes
    u16* m2phi = (u16*)S1; u16* m2plo = m2phi + MB1;   // m2 planes
    float* zf = S5;                                    // z fp32 [z][256][NN]

    init_kernel<<<BDN/4/256, 256, 0, stream>>>(x0in, x1in, out, idx0, idx1);
    wrepack_kernel<<<2560, 256, 0, stream>>>(Wq, Wk, Wv, Wm, W1, W2, whi, wlo);
    repack_xh_kernel<<<dim3(32, 16), 256, 0, stream>>>(out, xphi, xplo, 128, nullptr, nullptr);

    const int Ms[4] = {2048, 1024, 512, 256};
    const int Mb[4] = {11, 10, 9, 8};
    for (int l = 0; l < 4; ++l) {
        int M = Ms[l];
        int k_new = (M/2 < 128) ? 128 : M/2;
        int cross = l & 1;
        size_t lw = (size_t)l * 163840;
        const u16* Wqh = whi + lw;           const u16* Wql = wlo + lw;
        const u16* Wkh = Wqh + 16384;        const u16* Wkl = Wql + 16384;
        const u16* Wvh = Wqh + 32768;        const u16* Wvl = Wql + 32768;
        const u16* Wmh = Wqh + 49152;        const u16* Wml = Wql + 49152;
        const u16* W1h = Wqh + 65536;        const u16* W1l = Wql + 65536;
        const u16* W2h = Wqh + 131072;       const u16* W2l = Wql + 131072;

        u16* sphi = (u16*)S1;  u16* splo = sphi + (size_t)512*M;
        u16* qthi = (u16*)S5;  u16* qtlo = qthi + MB1;
        u16* kthi = (u16*)S6;  u16* ktlo = kthi + (size_t)512*M;
        u16* vthi = (u16*)S7;  u16* vtlo = vthi + (size_t)512*M;

        gather_rows_kernel<<<M/2, 256, 0, stream>>>(xphi, xplo, idx0, idx1,
                                                    sphi, splo, Mb[l], cross);
        zerop_kernel<<<4*NN/256, 256, 0, stream>>>(p);

        // q = Wq x + bq -> S2 fp32
        gemm_mfma_kernel<<<dim3(16, 2, 4), 256, 0, stream>>>(
            Wqh, Wql, 128, bq + l*ND, xphi, xplo, 128, xphi, xplo, 128, 128,
            128, NN, S2, DN, 0);
        // k = Wk s -> S3 ; v = Wv s -> S4
        gemm_mfma_kernel<<<dim3(M/128, 2, 4), 256, 0, stream>>>(
            Wkh, Wkl, 128, bk + l*ND, sphi, splo, 128, sphi, splo, 128, 128,
            128, M, S3, 128*M, 0);
        gemm_mfma_kernel<<<dim3(M/128, 2, 4), 256, 0, stream>>>(
            Wvh, Wvl, 128, bv + l*ND, sphi, splo, 128, sphi, splo, 128, 128,
            128, M, S4, 128*M, 0);

        // attention-ready planes
        repack_t_kernel<<<dim3(NN/64, 16), 256, 0, stream>>>(S2, qthi, qtlo, NN, QK_SCALE);
        repack_t_kernel<<<dim3(M/64, 16), 256, 0, stream>>>(S3, kthi, ktlo, M, 1.0f);
        repack_v_kernel<<<dim3((4*ND*M)/(8*256)), 256, 0, stream>>>(S4, vthi, vtlo, M);

        attn_mfma_kernel<<<dim3(NN/32, NH, 4), 256, 0, stream>>>(
            qthi, qtlo, kthi, ktlo, vthi, vtlo, M, S2, p);   // msg -> S2

        // msg planes; m2 = Wm msg + bm -> S4 fp32; m2 planes -> S1
        repack_xh_kernel<<<dim3(32, 16), 256, 0, stream>>>(S2, mphi, mplo, 128, nullptr, nullptr);
        gemm_mfma_kernel<<<dim3(16, 2, 4), 256, 0, stream>>>(
            Wmh, Wml, 128, bm + l*ND, mphi, mplo, 128, mphi, mplo, 128, 128,
            128, NN, S4, DN, 0);
        repack_xh_kernel<<<dim3(32, 16), 256, 0, stream>>>(S4, m2phi, m2plo, 128, nullptr, nullptr);

        // z = W1 [x ; m2] + b1 -> zf (S5+S6)
        gemm_mfma_kernel<<<dim3(16, 4, 4), 256, 0, stream>>>(
            W1h, W1l, 256, b1 + l*ND2, xphi, xplo, 128, m2phi, m2plo, 128, 128,
            256, NN, zf, 2*DN, 0);

        stats_kernel<<<4*ND2, 256, 0, stream>>>(zf, meanb, invb);
        // h = relu(instnorm(z)) planes -> S2+S3
        repack_xh_kernel<<<dim3(32, 32), 256, 0, stream>>>(zf, hphi, hplo, 256, meanb, invb);

        // x += W2 h + b2
        gemm_mfma_kernel<<<dim3(16, 2, 4), 256, 0, stream>>>(
            W2h, W2l, 256, b2 + l*ND, hphi, hplo, 256, hphi, hplo, 256, 256,
            256, NN, out, DN, 1);

        if (l < 3)
            repack_xh_kernel<<<dim3(32, 16), 256, 0, stream>>>(out, xphi, xplo, 128, nullptr, nullptr);

        rank_kernel<<<dim3((M+255)/256, 4), 256, 0, stream>>>(p, rankb, M);
        select_kernel<<<4, 256, 0, stream>>>(rankb, idx0, idx1, M, k_new, cross);
    }
}

// Round 5
// 786.919 us; speedup vs baseline: 3.1338x; 1.0472x over previous
//
#include <hip/hip_runtime.h>
#include <cstdint>
#include <cstddef>

// ---------------------------------------------------------------------------
// SDHGNN round 5: attention v2 — 64-query blocks, in-register online softmax
// (C = K·Q^T so row stats live per-lane), wave-private P staging, LDS pcol.
// GEMMs: k+v stacked into one dispatch. Split-bf16 3-term everywhere.
// ---------------------------------------------------------------------------

#define NB 2
#define ND 128
#define NH 4
#define NN 2048
#define ND2 256
#define DN (ND*NN)
#define BDN (NB*DN)
#define QK_SCALE 0.17677669529663687f
#define IN_EPS 1e-3f

typedef unsigned short u16;
typedef __attribute__((ext_vector_type(8))) short short8;
typedef __attribute__((ext_vector_type(4))) float f32x4;

__device__ __forceinline__ u16 f2bf(float f) {
    unsigned u = __float_as_uint(f);
    return (u16)((u + 0x7fffu + ((u >> 16) & 1u)) >> 16);
}
__device__ __forceinline__ float bf2f(u16 h) {
    return __uint_as_float(((unsigned)h) << 16);
}

// ---------------------------------------------------------------------------
__global__ __launch_bounds__(256) void init_kernel(
    const float* __restrict__ x0in, const float* __restrict__ x1in,
    float* __restrict__ out, int* __restrict__ idx0, int* __restrict__ idx1)
{
    int tid = blockIdx.x * 256 + threadIdx.x;
    const float4* a = (const float4*)x0in;
    const float4* b = (const float4*)x1in;
    float4* o = (float4*)out;
    o[tid] = a[tid];
    o[BDN/4 + tid] = b[tid];
    if (tid < NB*NN) {
        int v = tid & (NN-1);
        idx0[tid] = v;
        idx1[tid] = v;
    }
}

// ---------------------------------------------------------------------------
// weights -> bf16 hi/lo planes (all layers, one dispatch).
// layer flat: Wq(16384) Wk Wv Wm | W1(65536) | W2(32768) = 163840.
// ---------------------------------------------------------------------------
__global__ __launch_bounds__(256) void wrepack_kernel(
    const float* __restrict__ Wq, const float* __restrict__ Wk,
    const float* __restrict__ Wv, const float* __restrict__ Wm,
    const float* __restrict__ W1, const float* __restrict__ W2,
    u16* __restrict__ whi, u16* __restrict__ wlo)
{
    int e = blockIdx.x * 256 + threadIdx.x;
    int l = e / 163840;
    int r = e - l * 163840;
    float v;
    if      (r <  16384) v = Wq[l*16384 + r];
    else if (r <  32768) v = Wk[l*16384 + r - 16384];
    else if (r <  49152) v = Wv[l*16384 + r - 32768];
    else if (r <  65536) v = Wm[l*16384 + r - 49152];
    else if (r < 131072) v = W1[l*65536 + r - 65536];
    else                 v = W2[l*32768 + r - 131072];
    u16 h = f2bf(v);
    whi[e] = h;
    wlo[e] = f2bf(v - bf2f(h));
}

// ---------------------------------------------------------------------------
// fp32 [z][C][NN] -> bf16 hi/lo planes [z][n][C], optional instnorm+relu.
// ---------------------------------------------------------------------------
__global__ __launch_bounds__(256) void repack_xh_kernel(
    const float* __restrict__ in, u16* __restrict__ ohi, u16* __restrict__ olo,
    int C, const float* __restrict__ nmean, const float* __restrict__ ninv)
{
    __shared__ float tile[32][68];
    int ncg = C >> 5;
    int z = blockIdx.y / ncg, cg = blockIdx.y % ncg;
    int n0 = blockIdx.x * 64;
    int t = threadIdx.x;
    {
        int i = t >> 3, nc = (t & 7) * 8;
        int c = cg*32 + i;
        const float* src = &in[((size_t)z*C + c)*NN + n0 + nc];
        float4 a = *(const float4*)src;
        float4 b = *(const float4*)(src + 4);
        if (nmean) {
            float m = nmean[z*C + c], iv = ninv[z*C + c];
            a.x=(a.x-m)*iv; a.y=(a.y-m)*iv; a.z=(a.z-m)*iv; a.w=(a.w-m)*iv;
            b.x=(b.x-m)*iv; b.y=(b.y-m)*iv; b.z=(b.z-m)*iv; b.w=(b.w-m)*iv;
            a.x=a.x>0.f?a.x:0.f; a.y=a.y>0.f?a.y:0.f; a.z=a.z>0.f?a.z:0.f; a.w=a.w>0.f?a.w:0.f;
            b.x=b.x>0.f?b.x:0.f; b.y=b.y>0.f?b.y:0.f; b.z=b.z>0.f?b.z:0.f; b.w=b.w>0.f?b.w:0.f;
        }
        tile[i][nc+0]=a.x; tile[i][nc+1]=a.y; tile[i][nc+2]=a.z; tile[i][nc+3]=a.w;
        tile[i][nc+4]=b.x; tile[i][nc+5]=b.y; tile[i][nc+6]=b.z; tile[i][nc+7]=b.w;
    }
    __syncthreads();
    int n = t >> 2, c8 = (t & 3) * 8;
    short8 hi, lo;
    #pragma unroll
    for (int j = 0; j < 8; ++j) {
        float v = tile[c8 + j][n];
        u16 h = f2bf(v);
        hi[j] = (short)h;
        lo[j] = (short)f2bf(v - bf2f(h));
    }
    size_t ob = ((size_t)z*NN + n0 + n)*C + cg*32 + c8;
    *(short8*)&ohi[ob] = hi;
    *(short8*)&olo[ob] = lo;
}

// ---------------------------------------------------------------------------
// gather (+ p zero-init): s planes [z][m][128] = x planes row idx[m]
// ---------------------------------------------------------------------------
__global__ __launch_bounds__(256) void gather_rows_kernel(
    const u16* __restrict__ xphi, const u16* __restrict__ xplo,
    const int* __restrict__ idx0, const int* __restrict__ idx1,
    u16* __restrict__ sphi, u16* __restrict__ splo, int mbits, int cross,
    float* __restrict__ p)
{
    int tid = blockIdx.x * 256 + threadIdx.x;
    if (tid < 4*NN) p[tid] = 0.f;
    int c8 = (tid & 15) * 8;
    int plane = (tid >> 4) & 1;
    int M = 1 << mbits;
    int m = (tid >> 5) & (M - 1);
    int z = tid >> (5 + mbits);
    int st = z >> 1, b = z & 1;
    int ss = cross ? 1 - st : st;
    const int* idx = (ss ? idx1 : idx0) + b * NN;
    int n = idx[m];
    const u16* xp = plane ? xplo : xphi;
    u16* sp = plane ? splo : sphi;
    short8 v = *(const short8*)&xp[((size_t)(ss*2 + b)*NN + n)*128 + c8];
    *(short8*)&sp[((size_t)z*M + m)*128 + c8] = v;
}

// ---------------------------------------------------------------------------
// MFMA GEMM, split-bf16 3-term. Tile 64x128, K-chunk 32. Row-stacked outputs:
// blocks with o0 >= osplit write out2/bias2 (rows rebased). B from planes.
// ---------------------------------------------------------------------------
__global__ __launch_bounds__(256) void gemm_mfma_kernel(
    const u16* __restrict__ Whi, const u16* __restrict__ Wlo, int ldw,
    const float* __restrict__ bias1, const float* __restrict__ bias2, int osplit,
    const u16* __restrict__ B1hi, const u16* __restrict__ B1lo, int s1,
    const u16* __restrict__ B2hi, const u16* __restrict__ B2lo, int s2, int split,
    int Cin, int nCols,
    float* __restrict__ out1, int out_zs1,
    float* __restrict__ out2, int out_zs2, int acc_flag)
{
    __shared__ u16 As[2][64][40];
    __shared__ u16 Bs[2][128][40];
    const int z  = blockIdx.z;
    const int o0 = blockIdx.y * 64;
    const int n0 = blockIdx.x * 128;
    const int t  = threadIdx.x;
    const int lane = t & 63, w = t >> 6;
    const int l15 = lane & 15, quad = lane >> 4;
    const int wr = (w & 1) * 32, wc = (w >> 1) * 64;

    f32x4 acc[2][4];
    #pragma unroll
    for (int a = 0; a < 2; ++a)
        #pragma unroll
        for (int c = 0; c < 4; ++c) acc[a][c] = (f32x4){0.f,0.f,0.f,0.f};

    const int ao = t >> 2, ak = (t & 3) * 8;

    for (int kc = 0; kc < Cin; kc += 32) {
        {
            size_t wa = (size_t)(o0 + ao) * ldw + kc + ak;
            *(short8*)&As[0][ao][ak] = *(const short8*)&Whi[wa];
            *(short8*)&As[1][ao][ak] = *(const short8*)&Wlo[wa];
        }
        #pragma unroll
        for (int r = 0; r < 2; ++r) {
            int nl = (t >> 2) + r*64;
            int c = kc + ak;
            size_t off;
            const u16 *ph, *pl_;
            if (c < split) { off = ((size_t)z*nCols + n0 + nl)*s1 + c; ph = B1hi; pl_ = B1lo; }
            else { off = ((size_t)z*nCols + n0 + nl)*s2 + (c - split); ph = B2hi; pl_ = B2lo; }
            *(short8*)&Bs[0][nl][ak] = *(const short8*)&ph[off];
            *(short8*)&Bs[1][nl][ak] = *(const short8*)&pl_[off];
        }
        __syncthreads();
        short8 Ah[2], Al[2], Bh[4], Bl[4];
        #pragma unroll
        for (int a = 0; a < 2; ++a) {
            Ah[a] = *(const short8*)&As[0][wr + a*16 + l15][quad*8];
            Al[a] = *(const short8*)&As[1][wr + a*16 + l15][quad*8];
        }
        #pragma unroll
        for (int c = 0; c < 4; ++c) {
            Bh[c] = *(const short8*)&Bs[0][wc + c*16 + l15][quad*8];
            Bl[c] = *(const short8*)&Bs[1][wc + c*16 + l15][quad*8];
        }
        #pragma unroll
        for (int a = 0; a < 2; ++a)
            #pragma unroll
            for (int c = 0; c < 4; ++c) {
                acc[a][c] = __builtin_amdgcn_mfma_f32_16x16x32_bf16(Ah[a], Bl[c], acc[a][c], 0, 0, 0);
                acc[a][c] = __builtin_amdgcn_mfma_f32_16x16x32_bf16(Al[a], Bh[c], acc[a][c], 0, 0, 0);
                acc[a][c] = __builtin_amdgcn_mfma_f32_16x16x32_bf16(Ah[a], Bh[c], acc[a][c], 0, 0, 0);
            }
        __syncthreads();
    }

    const float* bp = bias1;
    float* op = out1;
    int obase = o0, ozs = out_zs1;
    if (o0 >= osplit) { bp = bias2; op = out2; obase = o0 - osplit; ozs = out_zs2; }

    #pragma unroll
    for (int a = 0; a < 2; ++a) {
        int ob = obase + wr + a*16 + quad*4;
        #pragma unroll
        for (int c = 0; c < 4; ++c) {
            int n = n0 + wc + c*16 + l15;
            #pragma unroll
            for (int r = 0; r < 4; ++r) {
                int o = ob + r;
                size_t oi = (size_t)z*ozs + (size_t)o*nCols + n;
                float v = acc[a][c][r] + bp[o];
                if (acc_flag) v += op[oi];
                op[oi] = v;
            }
        }
    }
}

// ---------------------------------------------------------------------------
// repack with transpose: q/k fp32 [z][128][C] -> hi/lo [zh][C][32]
// ---------------------------------------------------------------------------
__global__ __launch_bounds__(256) void repack_t_kernel(
    const float* __restrict__ in, u16* __restrict__ ohi,
    u16* __restrict__ olo, int C, float scale)
{
    __shared__ float tile[32][68];
    int zh = blockIdx.y;
    int h = zh & 3, z = zh >> 2;
    int n0 = blockIdx.x * 64;
    int t = threadIdx.x;
    {
        int i = t >> 3, nc = (t & 7) * 8;
        const float* src = &in[((size_t)z*ND + i*NH + h)*C + n0 + nc];
        float4 a = *(const float4*)src;
        float4 b = *(const float4*)(src + 4);
        tile[i][nc+0]=a.x*scale; tile[i][nc+1]=a.y*scale;
        tile[i][nc+2]=a.z*scale; tile[i][nc+3]=a.w*scale;
        tile[i][nc+4]=b.x*scale; tile[i][nc+5]=b.y*scale;
        tile[i][nc+6]=b.z*scale; tile[i][nc+7]=b.w*scale;
    }
    __syncthreads();
    int n = t >> 2, i8 = (t & 3) * 8;
    short8 hi, lo;
    #pragma unroll
    for (int j = 0; j < 8; ++j) {
        float v = tile[i8 + j][n];
        u16 hb = f2bf(v);
        hi[j] = (short)hb;
        lo[j] = (short)f2bf(v - bf2f(hb));
    }
    size_t ob = ((size_t)zh * C + n0 + n) * 32 + i8;
    *(short8*)&ohi[ob] = hi;
    *(short8*)&olo[ob] = lo;
}

// ---------------------------------------------------------------------------
// repack V: [z][128][M] fp32 -> hi/lo [zh][32][M]
// ---------------------------------------------------------------------------
__global__ __launch_bounds__(256) void repack_v_kernel(
    const float* __restrict__ in, u16* __restrict__ ohi,
    u16* __restrict__ olo, int M)
{
    int tid = blockIdx.x * 256 + threadIdx.x;
    int per = M >> 3;
    int m8 = (tid % per) * 8;
    int zd = tid / per;
    int d = zd & (ND-1), z = zd >> 7;
    int i = d >> 2, h = d & 3;
    const float* src = &in[(size_t)zd * M + m8];
    float4 a = *(const float4*)src;
    float4 b = *(const float4*)(src + 4);
    float vals[8] = {a.x,a.y,a.z,a.w,b.x,b.y,b.z,b.w};
    short8 hi, lo;
    #pragma unroll
    for (int j = 0; j < 8; ++j) {
        u16 hb = f2bf(vals[j]);
        hi[j] = (short)hb;
        lo[j] = (short)f2bf(vals[j] - bf2f(hb));
    }
    size_t ob = (((size_t)(z*4 + h))*32 + i) * M + m8;
    *(short8*)&ohi[ob] = hi;
    *(short8*)&olo[ob] = lo;
}

// ---------------------------------------------------------------------------
// Attention v2. Block = 64 queries x (h, z); 4 waves: wave = qp + 2*mh.
// Scores C = K·Q^T (A=K from LDS, B=Q persistent regs): row stats per-lane.
// Pass 1: in-register online (m,l); pass 2: probs in regs -> p colsums via
// lane butterflies + LDS pcol; P packed bf16 hi/lo through wave-private LDS
// region (no barrier) into PV A-fragments. Chunk = 64 source cols.
// ---------------------------------------------------------------------------
__global__ __launch_bounds__(256) void attn_mfma2_kernel(
    const u16* __restrict__ qhi, const u16* __restrict__ qlo,
    const u16* __restrict__ khi, const u16* __restrict__ klo,
    const u16* __restrict__ vthi, const u16* __restrict__ vtlo,
    int M, float* __restrict__ msg, float* __restrict__ p)
{
    __shared__ u16 ks[2][64][32];            // [plane][m][i] unpadded (64B rows)
    __shared__ u16 vs[2][32][72];            // [plane][i][m] pad 72
    __shared__ unsigned int Pw[2][64][36];   // P hi/lo staging (wave-private use)
    __shared__ float pcol[2048];
    __shared__ float redm[2][64], redl[2][64];
    __shared__ float rowM[64], rowIV[64];

    const int t = threadIdx.x;
    const int lane = t & 63, wave = t >> 6;
    const int l15 = lane & 15, quad = lane >> 4;
    const int qp = wave & 1, mh = wave >> 1;
    const int h = blockIdx.y, z = blockIdx.z;
    const int zh = z*4 + h;
    const int n0 = blockIdx.x * 64;

    for (int i = t; i < M; i += 256) pcol[i] = 0.f;

    // persistent Q B-fragments (lane l15 = q col, quad*8.. = k)
    short8 qBh[2], qBl[2];
    #pragma unroll
    for (int qt = 0; qt < 2; ++qt) {
        size_t qb = ((size_t)zh*NN + n0 + qp*32 + qt*16 + l15)*32 + quad*8;
        qBh[qt] = *(const short8*)&qhi[qb];
        qBl[qt] = *(const short8*)&qlo[qb];
    }

    const int nch = M >> 6;
    const int smr = t >> 2, sc8 = (t & 3) * 8;
    const int svi = t >> 3, sm8 = (t & 7) * 8;

    float rm[2] = {-1e30f, -1e30f}, rl[2] = {0.f, 0.f};

    // ---------------- pass 1: online (m, l) in registers ----------------
    for (int ch = 0; ch < nch; ++ch) {
        const int m0 = ch << 6;
        {
            size_t gk = ((size_t)zh*M + m0 + smr)*32 + sc8;
            *(short8*)&ks[0][smr][sc8] = *(const short8*)&khi[gk];
            *(short8*)&ks[1][smr][sc8] = *(const short8*)&klo[gk];
        }
        __syncthreads();
        #pragma unroll
        for (int qt = 0; qt < 2; ++qt) {
            #pragma unroll
            for (int mt = 0; mt < 2; ++mt) {
                int mrow = mh*32 + mt*16;
                short8 kh = *(const short8*)&ks[0][mrow + l15][quad*8];
                short8 kl = *(const short8*)&ks[1][mrow + l15][quad*8];
                f32x4 a = {0.f,0.f,0.f,0.f};
                a = __builtin_amdgcn_mfma_f32_16x16x32_bf16(kh, qBl[qt], a, 0,0,0);
                a = __builtin_amdgcn_mfma_f32_16x16x32_bf16(kl, qBh[qt], a, 0,0,0);
                a = __builtin_amdgcn_mfma_f32_16x16x32_bf16(kh, qBh[qt], a, 0,0,0);
                float bm = fmaxf(fmaxf(a[0],a[1]), fmaxf(a[2],a[3]));
                float bs = __expf(a[0]-bm)+__expf(a[1]-bm)+__expf(a[2]-bm)+__expf(a[3]-bm);
                if (bm > rm[qt]) { rl[qt] = rl[qt]*__expf(rm[qt]-bm) + bs; rm[qt] = bm; }
                else rl[qt] += bs*__expf(bm - rm[qt]);
            }
        }
        __syncthreads();
    }

    // reduce over quads (same q col), then across the two mh waves
    #pragma unroll
    for (int qt = 0; qt < 2; ++qt) {
        #pragma unroll
        for (int off = 16; off <= 32; off <<= 1) {
            float om = __shfl_xor(rm[qt], off);
            float ol = __shfl_xor(rl[qt], off);
            float nm = fmaxf(rm[qt], om);
            rl[qt] = rl[qt]*__expf(rm[qt]-nm) + ol*__expf(om-nm);
            rm[qt] = nm;
        }
        if (quad == 0) {
            redm[mh][qp*32 + qt*16 + l15] = rm[qt];
            redl[mh][qp*32 + qt*16 + l15] = rl[qt];
        }
    }
    __syncthreads();
    if (t < 64) {
        float ma = redm[0][t], mb = redm[1][t];
        float m = fmaxf(ma, mb);
        float l = redl[0][t]*__expf(ma-m) + redl[1][t]*__expf(mb-m);
        rowM[t] = m;
        rowIV[t] = 1.f / l;
    }
    __syncthreads();
    float myRM[2], myRIV[2];
    #pragma unroll
    for (int qt = 0; qt < 2; ++qt) {
        myRM[qt]  = rowM[qp*32 + qt*16 + l15];
        myRIV[qt] = rowIV[qp*32 + qt*16 + l15];
    }

    // ---------------- pass 2: probs, pcol, PV ----------------
    f32x4 oa[2][2];
    #pragma unroll
    for (int qt = 0; qt < 2; ++qt)
        #pragma unroll
        for (int dt = 0; dt < 2; ++dt) oa[qt][dt] = (f32x4){0.f,0.f,0.f,0.f};

    for (int ch = 0; ch < nch; ++ch) {
        const int m0 = ch << 6;
        {
            size_t gk = ((size_t)zh*M + m0 + smr)*32 + sc8;
            *(short8*)&ks[0][smr][sc8] = *(const short8*)&khi[gk];
            *(short8*)&ks[1][smr][sc8] = *(const short8*)&klo[gk];
            size_t gv = ((size_t)zh*32 + svi)*M + m0 + sm8;
            *(short8*)&vs[0][svi][sm8] = *(const short8*)&vthi[gv];
            *(short8*)&vs[1][svi][sm8] = *(const short8*)&vtlo[gv];
        }
        __syncthreads();

        float pr[2][2][4];
        #pragma unroll
        for (int qt = 0; qt < 2; ++qt)
            #pragma unroll
            for (int mt = 0; mt < 2; ++mt) {
                int mrow = mh*32 + mt*16;
                short8 kh = *(const short8*)&ks[0][mrow + l15][quad*8];
                short8 kl = *(const short8*)&ks[1][mrow + l15][quad*8];
                f32x4 a = {0.f,0.f,0.f,0.f};
                a = __builtin_amdgcn_mfma_f32_16x16x32_bf16(kh, qBl[qt], a, 0,0,0);
                a = __builtin_amdgcn_mfma_f32_16x16x32_bf16(kl, qBh[qt], a, 0,0,0);
                a = __builtin_amdgcn_mfma_f32_16x16x32_bf16(kh, qBh[qt], a, 0,0,0);
                #pragma unroll
                for (int r = 0; r < 4; ++r)
                    pr[qt][mt][r] = __expf(a[r] - myRM[qt]) * myRIV[qt];
            }

        // p column sums: butterfly over the 16 q-lanes, both qt merged
        #pragma unroll
        for (int mt = 0; mt < 2; ++mt)
            #pragma unroll
            for (int r = 0; r < 4; ++r) {
                float ps = pr[0][mt][r] + pr[1][mt][r];
                ps += __shfl_xor(ps, 1);
                ps += __shfl_xor(ps, 2);
                ps += __shfl_xor(ps, 4);
                ps += __shfl_xor(ps, 8);
                if (l15 == 0)
                    atomicAdd(&pcol[m0 + mh*32 + mt*16 + quad*4 + r], ps);
            }

        // pack probs bf16 hi/lo and stage A-fragments (wave-private region)
        #pragma unroll
        for (int qt = 0; qt < 2; ++qt) {
            int qrow = qp*32 + qt*16 + l15;
            #pragma unroll
            for (int mt = 0; mt < 2; ++mt) {
                u16 h0 = f2bf(pr[qt][mt][0]), h1 = f2bf(pr[qt][mt][1]);
                u16 h2 = f2bf(pr[qt][mt][2]), h3 = f2bf(pr[qt][mt][3]);
                uint2 hv;
                hv.x = (unsigned)h0 | ((unsigned)h1 << 16);
                hv.y = (unsigned)h2 | ((unsigned)h3 << 16);
                u16 l0 = f2bf(pr[qt][mt][0] - bf2f(h0));
                u16 l1 = f2bf(pr[qt][mt][1] - bf2f(h1));
                u16 l2 = f2bf(pr[qt][mt][2] - bf2f(h2));
                u16 l3 = f2bf(pr[qt][mt][3] - bf2f(h3));
                uint2 lv;
                lv.x = (unsigned)l0 | ((unsigned)l1 << 16);
                lv.y = (unsigned)l2 | ((unsigned)l3 << 16);
                int ui = mh*16 + mt*8 + quad*2;
                *(uint2*)&Pw[0][qrow][ui] = hv;
                *(uint2*)&Pw[1][qrow][ui] = lv;
            }
        }

        // PV: C[q][dh] += P[q][m] · V^T[m][dh] over the wave's 32-m group
        #pragma unroll
        for (int qt = 0; qt < 2; ++qt) {
            int qrow = qp*32 + qt*16 + l15;
            short8 pAh = *(const short8*)&Pw[0][qrow][mh*16 + quad*4];
            short8 pAl = *(const short8*)&Pw[1][qrow][mh*16 + quad*4];
            #pragma unroll
            for (int dt = 0; dt < 2; ++dt) {
                short8 vh = *(const short8*)&vs[0][dt*16 + l15][mh*32 + quad*8];
                short8 vl = *(const short8*)&vs[1][dt*16 + l15][mh*32 + quad*8];
                oa[qt][dt] = __builtin_amdgcn_mfma_f32_16x16x32_bf16(pAh, vl, oa[qt][dt], 0,0,0);
                oa[qt][dt] = __builtin_amdgcn_mfma_f32_16x16x32_bf16(pAl, vh, oa[qt][dt], 0,0,0);
                oa[qt][dt] = __builtin_amdgcn_mfma_f32_16x16x32_bf16(pAh, vh, oa[qt][dt], 0,0,0);
            }
        }
        __syncthreads();
    }

    // combine the two mh partial PV sums, write msg, flush pcol
    float* obuf = (float*)&Pw[0][0][0];
    if (mh == 1) {
        #pragma unroll
        for (int qt = 0; qt < 2; ++qt)
            #pragma unroll
            for (int dt = 0; dt < 2; ++dt) {
                float4 v;
                v.x = oa[qt][dt][0]; v.y = oa[qt][dt][1];
                v.z = oa[qt][dt][2]; v.w = oa[qt][dt][3];
                *(float4*)&obuf[(((qp*2+qt)*2+dt)*64 + lane)*4] = v;
            }
    }
    __syncthreads();
    if (mh == 0) {
        #pragma unroll
        for (int qt = 0; qt < 2; ++qt)
            #pragma unroll
            for (int dt = 0; dt < 2; ++dt) {
                float4 v = *(const float4*)&obuf[(((qp*2+qt)*2+dt)*64 + lane)*4];
                float vv[4] = {v.x, v.y, v.z, v.w};
                #pragma unroll
                for (int r = 0; r < 4; ++r) {
                    int qg = n0 + qp*32 + qt*16 + quad*4 + r;
                    int i  = dt*16 + l15;
                    msg[((size_t)z*ND + i*NH + h)*NN + qg] = oa[qt][dt][r] + vv[r];
                }
            }
    }
    for (int i = t; i < M; i += 256)
        atomicAdd(&p[(size_t)z*NN + i], pcol[i]*0.25f);
}

// ---------------------------------------------------------------------------
__global__ __launch_bounds__(256) void stats_kernel(
    const float* __restrict__ zbuf, float* __restrict__ mean, float* __restrict__ inv)
{
    int bc = blockIdx.x;
    const float* row = zbuf + (size_t)bc * NN;
    __shared__ float red[256];
    __shared__ float m_s;
    int t = threadIdx.x;
    float s = 0.f;
    for (int i = t; i < NN; i += 256) s += row[i];
    red[t] = s; __syncthreads();
    for (int o = 128; o > 0; o >>= 1) {
        if (t < o) red[t] += red[t + o];
        __syncthreads();
    }
    if (t == 0) { m_s = red[0] * (1.f / NN); mean[bc] = m_s; }
    __syncthreads();
    float m = m_s;
    float ss = 0.f;
    for (int i = t; i < NN; i += 256) { float d = row[i] - m; ss = fmaf(d, d, ss); }
    red[t] = ss; __syncthreads();
    for (int o = 128; o > 0; o >>= 1) {
        if (t < o) red[t] += red[t + o];
        __syncthreads();
    }
    if (t == 0) inv[bc] = 1.f / sqrtf(red[0] * (1.f / NN) + IN_EPS);
}

// ---------------------------------------------------------------------------
__global__ __launch_bounds__(256) void rank_kernel(
    const float* __restrict__ p, int* __restrict__ rank, int M)
{
    int zz = blockIdx.y;
    __shared__ float pv[2048];
    for (int i = threadIdx.x; i < M; i += 256) pv[i] = p[(size_t)zz*NN + i];
    __syncthreads();
    int i = blockIdx.x * 256 + threadIdx.x;
    if (i < M) {
        float pi = pv[i];
        int r = 0;
        for (int j = 0; j < M; ++j) {
            float pj = pv[j];
            r += (pj > pi) ? 1 : ((pj == pi && j < i) ? 1 : 0);
        }
        rank[zz*NN + i] = r;
    }
}

__global__ __launch_bounds__(256) void select_kernel(
    const int* __restrict__ rank, int* __restrict__ idx0, int* __restrict__ idx1,
    int M, int k, int cross)
{
    int z = blockIdx.x;
    int st = z >> 1, b = z & 1;
    int ts = cross ? 1 - st : st;
    int* idx = (ts ? idx1 : idx0) + b * NN;
    const int* rk = rank + z * NN;
    __shared__ int sel[2048], idv[2048], sa[2048], sb[2048];
    int t = threadIdx.x;
    for (int i = t; i < M; i += 256) {
        int s = rk[i] < k ? 1 : 0;
        sel[i] = s;
        sa[i] = s;
        idv[i] = idx[i];
    }
    __syncthreads();
    int* src = sa; int* dst = sb;
    for (int off = 1; off < M; off <<= 1) {
        for (int i = t; i < M; i += 256)
            dst[i] = src[i] + (i >= off ? src[i - off] : 0);
        __syncthreads();
        int* tmp = src; src = dst; dst = tmp;
    }
    for (int i = t; i < M; i += 256)
        if (sel[i]) idx[src[i] - 1] = idv[i];
}

// ---------------------------------------------------------------------------
extern "C" void kernel_launch(void* const* d_in, const int* in_sizes, int n_in,
                              void* d_out, int out_size, void* d_ws, size_t ws_size,
                              hipStream_t stream)
{
    const float* x0in = (const float*)d_in[0];
    const float* x1in = (const float*)d_in[1];
    const float* Wq = (const float*)d_in[2];
    const float* bq = (const float*)d_in[3];
    const float* Wk = (const float*)d_in[4];
    const float* bk = (const float*)d_in[5];
    const float* Wv = (const float*)d_in[6];
    const float* bv = (const float*)d_in[7];
    const float* Wm = (const float*)d_in[8];
    const float* bm = (const float*)d_in[9];
    const float* W1 = (const float*)d_in[10];
    const float* b1 = (const float*)d_in[11];
    const float* W2 = (const float*)d_in[12];
    const float* b2 = (const float*)d_in[13];

    float* out = (float*)d_out;
    float* ws  = (float*)d_ws;

    const size_t MB1 = 1048576;
    u16* xphi = (u16*)ws;                 u16* xplo = xphi + MB1;
    float* S1 = ws + 1*MB1;
    float* S2 = ws + 2*MB1;
    float* S3 = ws + 3*MB1;
    float* S4 = ws + 4*MB1;
    float* S5 = ws + 5*MB1;
    float* S6 = ws + 6*MB1;
    float* S7 = ws + 7*MB1;
    u16* whi = (u16*)(ws + 8*MB1);        u16* wlo = whi + 655360;
    float* meanb = ws + 9*MB1;
    float* invb  = meanb + 1024;
    float* p     = invb + 1024;
    int* idx0 = (int*)(p + 4*NN);
    int* idx1 = idx0 + NB*NN;
    int* rankb = idx1 + NB*NN;

    u16* hphi = (u16*)S2;  u16* hplo = hphi + 2*MB1;
    u16* mphi = (u16*)S3;  u16* mplo = mphi + MB1;
    u16* m2phi = (u16*)S1; u16* m2plo = m2phi + MB1;
    float* zf = S5;

    init_kernel<<<BDN/4/256, 256, 0, stream>>>(x0in, x1in, out, idx0, idx1);
    wrepack_kernel<<<2560, 256, 0, stream>>>(Wq, Wk, Wv, Wm, W1, W2, whi, wlo);
    repack_xh_kernel<<<dim3(32, 16), 256, 0, stream>>>(out, xphi, xplo, 128, nullptr, nullptr);

    const int Ms[4] = {2048, 1024, 512, 256};
    const int Mb[4] = {11, 10, 9, 8};
    for (int l = 0; l < 4; ++l) {
        int M = Ms[l];
        int k_new = (M/2 < 128) ? 128 : M/2;
        int cross = l & 1;
        size_t lw = (size_t)l * 163840;
        const u16* Wqh = whi + lw;           const u16* Wql = wlo + lw;
        const u16* Wkh = Wqh + 16384;        const u16* Wkl = Wql + 16384;
        const u16* Wmh = Wqh + 49152;        const u16* Wml = Wql + 49152;
        const u16* W1h = Wqh + 65536;        const u16* W1l = Wql + 65536;
        const u16* W2h = Wqh + 131072;       const u16* W2l = Wql + 131072;

        u16* sphi = (u16*)S1;  u16* splo = sphi + (size_t)512*M;
        u16* qthi = (u16*)S5;  u16* qtlo = qthi + MB1;
        u16* kthi = (u16*)S6;  u16* ktlo = kthi + (size_t)512*M;
        u16* vthi = (u16*)S7;  u16* vtlo = vthi + (size_t)512*M;

        gather_rows_kernel<<<M/2, 256, 0, stream>>>(xphi, xplo, idx0, idx1,
                                                    sphi, splo, Mb[l], cross, p);

        // q = Wq x + bq -> S2 fp32
        gemm_mfma_kernel<<<dim3(16, 2, 4), 256, 0, stream>>>(
            Wqh, Wql, 128, bq + l*ND, bq + l*ND, 1024,
            xphi, xplo, 128, xphi, xplo, 128, 128,
            128, NN, S2, DN, S2, DN, 0);
        // [k ; v] stacked: rows 0-127 -> S3, 128-255 -> S4
        gemm_mfma_kernel<<<dim3(M/128, 4, 4), 256, 0, stream>>>(
            Wkh, Wkl, 128, bk + l*ND, bv + l*ND, 128,
            sphi, splo, 128, sphi, splo, 128, 128,
            128, M, S3, 128*M, S4, 128*M, 0);

        repack_t_kernel<<<dim3(NN/64, 16), 256, 0, stream>>>(S2, qthi, qtlo, NN, QK_SCALE);
        repack_t_kernel<<<dim3(M/64, 16), 256, 0, stream>>>(S3, kthi, ktlo, M, 1.0f);
        repack_v_kernel<<<dim3((4*ND*M)/(8*256)), 256, 0, stream>>>(S4, vthi, vtlo, M);

        attn_mfma2_kernel<<<dim3(NN/64, NH, 4), 256, 0, stream>>>(
            qthi, qtlo, kthi, ktlo, vthi, vtlo, M, S2, p);   // msg -> S2

        repack_xh_kernel<<<dim3(32, 16), 256, 0, stream>>>(S2, mphi, mplo, 128, nullptr, nullptr);
        gemm_mfma_kernel<<<dim3(16, 2, 4), 256, 0, stream>>>(
            Wmh, Wml, 128, bm + l*ND, bm + l*ND, 1024,
            mphi, mplo, 128, mphi, mplo, 128, 128,
            128, NN, S4, DN, S4, DN, 0);
        repack_xh_kernel<<<dim3(32, 16), 256, 0, stream>>>(S4, m2phi, m2plo, 128, nullptr, nullptr);

        gemm_mfma_kernel<<<dim3(16, 4, 4), 256, 0, stream>>>(
            W1h, W1l, 256, b1 + l*ND2, b1 + l*ND2, 1024,
            xphi, xplo, 128, m2phi, m2plo, 128, 128,
            256, NN, zf, 2*DN, zf, 2*DN, 0);

        stats_kernel<<<4*ND2, 256, 0, stream>>>(zf, meanb, invb);
        repack_xh_kernel<<<dim3(32, 32), 256, 0, stream>>>(zf, hphi, hplo, 256, meanb, invb);

        gemm_mfma_kernel<<<dim3(16, 2, 4), 256, 0, stream>>>(
            W2h, W2l, 256, b2 + l*ND, b2 + l*ND, 1024,
            hphi, hplo, 256, hphi, hplo, 256, 256,
            256, NN, out, DN, out, DN, 1);

        if (l < 3)
            repack_xh_kernel<<<dim3(32, 16), 256, 0, stream>>>(out, xphi, xplo, 128, nullptr, nullptr);

        rank_kernel<<<dim3((M+255)/256, 4), 256, 0, stream>>>(p, rankb, M);
        select_kernel<<<4, 256, 0, stream>>>(rankb, idx0, idx1, M, k_new, cross);
    }
}

// Round 6
// 613.358 us; speedup vs baseline: 4.0206x; 1.2830x over previous
//
#include <hip/hip_runtime.h>
#include <cstdint>
#include <cstddef>

// ---------------------------------------------------------------------------
// SDHGNN round 6: fused pipeline (8 dispatches/layer).
//  - qkv_kernel: q/k/v GEMMs fused, idx-indirect B (no gather), epilogues emit
//    attention-ready bf16 planes (Wq/Wk/Wv rows permuted to h*32+i).
//  - attn3: chunk=128, PV pure-bf16 (P hi, V hi), msg planes out (Wm cols
//    permuted to h*32+i so writes are coalesced).
//  - wm/w1/w2: plane-in/plane-out epilogues; W1 accumulates instnorm stats.
// x-path stays split-bf16 3-term (fp32-grade) so top-k never flips.
// ---------------------------------------------------------------------------

#define NB 2
#define ND 128
#define NH 4
#define NN 2048
#define ND2 256
#define DN (ND*NN)
#define BDN (NB*DN)
#define QK_SCALE 0.17677669529663687f
#define IN_EPS 1e-3f

typedef unsigned short u16;
typedef __attribute__((ext_vector_type(8))) short short8;
typedef __attribute__((ext_vector_type(4))) float f32x4;

__device__ __forceinline__ u16 f2bf(float f) {
    unsigned u = __float_as_uint(f);
    return (u16)((u + 0x7fffu + ((u >> 16) & 1u)) >> 16);
}
__device__ __forceinline__ float bf2f(u16 h) {
    return __uint_as_float(((unsigned)h) << 16);
}

// ---------------------------------------------------------------------------
__global__ __launch_bounds__(256) void init_kernel(
    const float* __restrict__ x0in, const float* __restrict__ x1in,
    float* __restrict__ out, int* __restrict__ idx0, int* __restrict__ idx1)
{
    int tid = blockIdx.x * 256 + threadIdx.x;
    const float4* a = (const float4*)x0in;
    const float4* b = (const float4*)x1in;
    float4* o = (float4*)out;
    o[tid] = a[tid];
    o[BDN/4 + tid] = b[tid];
    if (tid < NB*NN) {
        int v = tid & (NN-1);
        idx0[tid] = v;
        idx1[tid] = v;
    }
}

// ---------------------------------------------------------------------------
// weights -> bf16 hi/lo planes with permutations:
//   Wq/Wk/Wv: rows permuted o' = h*32+i (src row = (o'&31)*4 + (o'>>5))
//   Wm: cols permuted likewise; W1/W2 unchanged.
// layer flat: Wq'(16384) Wk' Wv' Wm' | W1(65536) | W2(32768) = 163840.
// tail: permuted fp32 biases bqp/bkp/bvp [4][128] each.
// ---------------------------------------------------------------------------
__global__ __launch_bounds__(256) void wrepack2_kernel(
    const float* __restrict__ Wq, const float* __restrict__ Wk,
    const float* __restrict__ Wv, const float* __restrict__ Wm,
    const float* __restrict__ W1, const float* __restrict__ W2,
    const float* __restrict__ bq, const float* __restrict__ bk,
    const float* __restrict__ bv,
    u16* __restrict__ whi, u16* __restrict__ wlo,
    float* __restrict__ bqp, float* __restrict__ bkp, float* __restrict__ bvp)
{
    int e = blockIdx.x * 256 + threadIdx.x;
    if (e < 655360) {
        int l = e / 163840, r = e - l*163840;
        float v;
        if (r < 49152) {
            int m = r >> 14;
            int rr = r & 16383;
            int o = rr >> 7, c = rr & 127;
            int so = (o & 31)*4 + (o >> 5);
            const float* W = (m == 0) ? Wq : ((m == 1) ? Wk : Wv);
            v = W[l*16384 + so*128 + c];
        } else if (r < 65536) {
            int rr = r - 49152;
            int o = rr >> 7, c = rr & 127;
            int sc = (c & 31)*4 + (c >> 5);
            v = Wm[l*16384 + o*128 + sc];
        } else if (r < 131072) v = W1[l*65536 + r - 65536];
        else                   v = W2[l*32768 + r - 131072];
        u16 hb = f2bf(v);
        whi[e] = hb;
        wlo[e] = f2bf(v - bf2f(hb));
    } else if (e < 656896) {
        int eb = e - 655360;
        int l = eb / 384, rr = eb % 384;
        int which = rr >> 7, o = rr & 127;
        int so = (o & 31)*4 + (o >> 5);
        float v = (which == 0 ? bq : (which == 1 ? bk : bv))[l*128 + so];
        (which == 0 ? bqp : (which == 1 ? bkp : bvp))[l*128 + o] = v;
    }
}

// ---------------------------------------------------------------------------
// fp32 [z][128][NN] -> bf16 hi/lo planes [z][n][128] (initial x planes only)
// ---------------------------------------------------------------------------
__global__ __launch_bounds__(256) void repack_xh_kernel(
    const float* __restrict__ in, u16* __restrict__ ohi, u16* __restrict__ olo)
{
    __shared__ float tile[32][68];
    int z = blockIdx.y >> 2, cg = blockIdx.y & 3;
    int n0 = blockIdx.x * 64;
    int t = threadIdx.x;
    {
        int i = t >> 3, nc = (t & 7) * 8;
        const float* src = &in[((size_t)z*128 + cg*32 + i)*NN + n0 + nc];
        float4 a = *(const float4*)src;
        float4 b = *(const float4*)(src + 4);
        tile[i][nc+0]=a.x; tile[i][nc+1]=a.y; tile[i][nc+2]=a.z; tile[i][nc+3]=a.w;
        tile[i][nc+4]=b.x; tile[i][nc+5]=b.y; tile[i][nc+6]=b.z; tile[i][nc+7]=b.w;
    }
    __syncthreads();
    int n = t >> 2, c8 = (t & 3) * 8;
    short8 hi, lo;
    #pragma unroll
    for (int j = 0; j < 8; ++j) {
        float v = tile[c8 + j][n];
        u16 h = f2bf(v);
        hi[j] = (short)h;
        lo[j] = (short)f2bf(v - bf2f(h));
    }
    size_t ob = ((size_t)z*NN + n0 + n)*128 + cg*32 + c8;
    *(short8*)&ohi[ob] = hi;
    *(short8*)&olo[ob] = lo;
}

// ---------------------------------------------------------------------------
// Fused QKV. Roles: bx<32: q (B = own x planes, cols NN); else k/v tiles
// (B = x planes of gathered stream via idx indirection, cols M).
// Epilogues: q/k -> qt/kt planes [zh][C][32] hi/lo (q scaled); v -> vt hi
// [zh][32][M]. q-role blocks also zero p.
// ---------------------------------------------------------------------------
__global__ __launch_bounds__(256) void qkv_kernel(
    const u16* __restrict__ Whi, const u16* __restrict__ Wlo,
    const float* __restrict__ bqp, const float* __restrict__ bkp,
    const float* __restrict__ bvp,
    const u16* __restrict__ xphi, const u16* __restrict__ xplo,
    const int* __restrict__ idx0, const int* __restrict__ idx1,
    int cross, int mtbits, int M,
    u16* __restrict__ qthi, u16* __restrict__ qtlo,
    u16* __restrict__ kthi, u16* __restrict__ ktlo,
    u16* __restrict__ vthi, float* __restrict__ p)
{
    __shared__ u16 As[2][64][40];
    __shared__ u16 Bs[2][128][40];

    const int z = blockIdx.z;
    const int bx = blockIdx.x;
    const int t = threadIdx.x;
    const int lane = t & 63, w = t >> 6;
    const int l15 = lane & 15, quad = lane >> 4;
    const int wr = (w & 1)*32, wc = (w >> 1)*64;

    int role, o0, n0, nCols;
    const u16 *Wbh, *Wbl;
    const float* bias;
    if (bx < 32) {
        role = 0; o0 = (bx >> 4)*64; n0 = (bx & 15)*128; nCols = NN;
        Wbh = Whi; Wbl = Wlo; bias = bqp;
        if (t < 64) p[(size_t)z*NN + bx*64 + t] = 0.f;
    } else {
        int e = bx - 32;
        int mt_ = (1 << mtbits) - 1;
        int ct = e & mt_, rt = e >> mtbits;
        n0 = ct*128; nCols = M;
        if (rt < 2) { role = 1; o0 = rt*64; Wbh = Whi+16384; Wbl = Wlo+16384; bias = bkp; }
        else        { role = 2; o0 = (rt-2)*64; Wbh = Whi+32768; Wbl = Wlo+32768; bias = bvp; }
    }
    const int st = z >> 1, b = z & 1;
    int srcz = z;
    const int* idxp = nullptr;
    if (role != 0) {
        int ss = cross ? 1 - st : st;
        srcz = ss*2 + b;
        idxp = (ss ? idx1 : idx0) + b*NN;
    }

    f32x4 acc[2][4];
    #pragma unroll
    for (int a = 0; a < 2; ++a)
        #pragma unroll
        for (int c = 0; c < 4; ++c) acc[a][c] = (f32x4){0.f,0.f,0.f,0.f};

    const int ao = t >> 2, ak = (t & 3)*8;
    for (int kc = 0; kc < 128; kc += 32) {
        {
            size_t wa = (size_t)(o0 + ao)*128 + kc + ak;
            *(short8*)&As[0][ao][ak] = *(const short8*)&Wbh[wa];
            *(short8*)&As[1][ao][ak] = *(const short8*)&Wbl[wa];
        }
        #pragma unroll
        for (int r = 0; r < 2; ++r) {
            int nl = (t >> 2) + r*64;
            int grow = n0 + nl;
            if (idxp) grow = idxp[grow];
            size_t off = ((size_t)srcz*NN + grow)*128 + kc + ak;
            *(short8*)&Bs[0][nl][ak] = *(const short8*)&xphi[off];
            *(short8*)&Bs[1][nl][ak] = *(const short8*)&xplo[off];
        }
        __syncthreads();
        short8 Ah[2], Al[2], Bh[4], Bl[4];
        #pragma unroll
        for (int a = 0; a < 2; ++a) {
            Ah[a] = *(const short8*)&As[0][wr + a*16 + l15][quad*8];
            Al[a] = *(const short8*)&As[1][wr + a*16 + l15][quad*8];
        }
        #pragma unroll
        for (int c = 0; c < 4; ++c) {
            Bh[c] = *(const short8*)&Bs[0][wc + c*16 + l15][quad*8];
            Bl[c] = *(const short8*)&Bs[1][wc + c*16 + l15][quad*8];
        }
        #pragma unroll
        for (int a = 0; a < 2; ++a)
            #pragma unroll
            for (int c = 0; c < 4; ++c) {
                acc[a][c] = __builtin_amdgcn_mfma_f32_16x16x32_bf16(Ah[a], Bl[c], acc[a][c], 0,0,0);
                acc[a][c] = __builtin_amdgcn_mfma_f32_16x16x32_bf16(Al[a], Bh[c], acc[a][c], 0,0,0);
                acc[a][c] = __builtin_amdgcn_mfma_f32_16x16x32_bf16(Ah[a], Bh[c], acc[a][c], 0,0,0);
            }
        __syncthreads();
    }

    if (role == 2) {
        #pragma unroll
        for (int a = 0; a < 2; ++a)
            #pragma unroll
            for (int c = 0; c < 4; ++c)
                #pragma unroll
                for (int r = 0; r < 4; ++r) {
                    int row = o0 + wr + a*16 + quad*4 + r;
                    int m = n0 + wc + c*16 + l15;
                    float v = acc[a][c][r] + bias[row];
                    vthi[((size_t)(z*4 + (row>>5))*32 + (row&31))*(size_t)M + m] = f2bf(v);
                }
    } else {
        float* tb = (float*)&Bs[0][0][0];   // [64][66]
        u16* ohi = role ? kthi : qthi;
        u16* olo = role ? ktlo : qtlo;
        float scale = role ? 1.f : QK_SCALE;
        #pragma unroll
        for (int rd = 0; rd < 2; ++rd) {
            __syncthreads();
            if ((w >> 1) == rd) {
                #pragma unroll
                for (int a = 0; a < 2; ++a)
                    #pragma unroll
                    for (int c = 0; c < 4; ++c)
                        #pragma unroll
                        for (int r = 0; r < 4; ++r) {
                            int rl = wr + a*16 + quad*4 + r;
                            tb[rl*66 + c*16 + l15] = acc[a][c][r] + bias[o0 + rl];
                        }
            }
            __syncthreads();
            int n = t >> 2;
            #pragma unroll
            for (int oc = 0; oc < 2; ++oc) {
                int r0 = ((t & 3) + oc*4)*8;
                short8 hi, lo;
                #pragma unroll
                for (int j = 0; j < 8; ++j) {
                    float v = tb[(r0 + j)*66 + n] * scale;
                    u16 hb = f2bf(v);
                    hi[j] = (short)hb;
                    lo[j] = (short)f2bf(v - bf2f(hb));
                }
                int rowg = o0 + r0;
                size_t ob = ((size_t)(z*4 + (rowg >> 5))*nCols + n0 + rd*64 + n)*32 + (rowg & 31);
                *(short8*)&ohi[ob] = hi;
                *(short8*)&olo[ob] = lo;
            }
        }
    }
}

// ---------------------------------------------------------------------------
// Attention v3. Block = 64 queries x (h, z); waves: qp = w&1, mh = w>>1.
// Chunk 128. Scores C=K*Q^T split-bf16 3-term (fp32-grade, feeds p);
// PV pure bf16 (P hi, V hi). msg -> bf16 hi/lo planes [z][n][h*32+i].
// ---------------------------------------------------------------------------
__global__ __launch_bounds__(256) void attn3_kernel(
    const u16* __restrict__ qthi, const u16* __restrict__ qtlo,
    const u16* __restrict__ kthi, const u16* __restrict__ ktlo,
    const u16* __restrict__ vthi,
    int M, u16* __restrict__ msghi, u16* __restrict__ msglo,
    float* __restrict__ p)
{
    __shared__ u16 ks[2][128][32];
    __shared__ u16 vs[32][136];
    __shared__ u16 Pw[64][136];
    __shared__ float pcol[2048];
    __shared__ float redm[2][64], redl[2][64];
    __shared__ float rowM[64], rowIV[64];

    const int t = threadIdx.x;
    const int lane = t & 63, wave = t >> 6;
    const int l15 = lane & 15, quad = lane >> 4;
    const int qp = wave & 1, mh = wave >> 1;
    const int h = blockIdx.y, z = blockIdx.z;
    const int zh = z*4 + h;
    const int n0 = blockIdx.x * 64;

    for (int i = t; i < 2048; i += 256) pcol[i] = 0.f;

    short8 qBh[2], qBl[2];
    #pragma unroll
    for (int qt = 0; qt < 2; ++qt) {
        size_t qb = ((size_t)zh*NN + n0 + qp*32 + qt*16 + l15)*32 + quad*8;
        qBh[qt] = *(const short8*)&qthi[qb];
        qBl[qt] = *(const short8*)&qtlo[qb];
    }

    const int nch = M >> 7;
    const int sr = t >> 1, sc = (t & 1)*16;
    const int vr = t >> 3, vc = (t & 7)*16;

    float rm[2] = {-1e30f, -1e30f}, rl[2] = {0.f, 0.f};

    // ---- pass 1: online (m,l), in-register per lane ----
    for (int ch = 0; ch < nch; ++ch) {
        const int m0 = ch << 7;
        {
            size_t gk = ((size_t)zh*M + m0 + sr)*32 + sc;
            *(short8*)&ks[0][sr][sc]   = *(const short8*)&kthi[gk];
            *(short8*)&ks[0][sr][sc+8] = *(const short8*)&kthi[gk+8];
            *(short8*)&ks[1][sr][sc]   = *(const short8*)&ktlo[gk];
            *(short8*)&ks[1][sr][sc+8] = *(const short8*)&ktlo[gk+8];
        }
        __syncthreads();
        #pragma unroll
        for (int qt = 0; qt < 2; ++qt)
            #pragma unroll
            for (int mt = 0; mt < 4; ++mt) {
                int mrow = mh*64 + mt*16 + l15;
                short8 kh = *(const short8*)&ks[0][mrow][quad*8];
                short8 kl = *(const short8*)&ks[1][mrow][quad*8];
                f32x4 a = {0.f,0.f,0.f,0.f};
                a = __builtin_amdgcn_mfma_f32_16x16x32_bf16(kh, qBl[qt], a, 0,0,0);
                a = __builtin_amdgcn_mfma_f32_16x16x32_bf16(kl, qBh[qt], a, 0,0,0);
                a = __builtin_amdgcn_mfma_f32_16x16x32_bf16(kh, qBh[qt], a, 0,0,0);
                float bm = fmaxf(fmaxf(a[0],a[1]), fmaxf(a[2],a[3]));
                float bs = __expf(a[0]-bm)+__expf(a[1]-bm)+__expf(a[2]-bm)+__expf(a[3]-bm);
                if (bm > rm[qt]) { rl[qt] = rl[qt]*__expf(rm[qt]-bm) + bs; rm[qt] = bm; }
                else rl[qt] += bs*__expf(bm - rm[qt]);
            }
        __syncthreads();
    }

    #pragma unroll
    for (int qt = 0; qt < 2; ++qt) {
        #pragma unroll
        for (int off = 16; off <= 32; off <<= 1) {
            float om = __shfl_xor(rm[qt], off);
            float ol = __shfl_xor(rl[qt], off);
            float nm = fmaxf(rm[qt], om);
            rl[qt] = rl[qt]*__expf(rm[qt]-nm) + ol*__expf(om-nm);
            rm[qt] = nm;
        }
        if (quad == 0) {
            redm[mh][qp*32 + qt*16 + l15] = rm[qt];
            redl[mh][qp*32 + qt*16 + l15] = rl[qt];
        }
    }
    __syncthreads();
    if (t < 64) {
        float ma = redm[0][t], mb = redm[1][t];
        float m = fmaxf(ma, mb);
        float l = redl[0][t]*__expf(ma-m) + redl[1][t]*__expf(mb-m);
        rowM[t] = m;
        rowIV[t] = 1.f / l;
    }
    __syncthreads();
    float myRM[2], myRIV[2];
    #pragma unroll
    for (int qt = 0; qt < 2; ++qt) {
        myRM[qt]  = rowM[qp*32 + qt*16 + l15];
        myRIV[qt] = rowIV[qp*32 + qt*16 + l15];
    }

    // ---- pass 2: probs, pcol, PV ----
    f32x4 oa[2][2];
    #pragma unroll
    for (int qt = 0; qt < 2; ++qt)
        #pragma unroll
        for (int dt = 0; dt < 2; ++dt) oa[qt][dt] = (f32x4){0.f,0.f,0.f,0.f};

    for (int ch = 0; ch < nch; ++ch) {
        const int m0 = ch << 7;
        {
            size_t gk = ((size_t)zh*M + m0 + sr)*32 + sc;
            *(short8*)&ks[0][sr][sc]   = *(const short8*)&kthi[gk];
            *(short8*)&ks[0][sr][sc+8] = *(const short8*)&kthi[gk+8];
            *(short8*)&ks[1][sr][sc]   = *(const short8*)&ktlo[gk];
            *(short8*)&ks[1][sr][sc+8] = *(const short8*)&ktlo[gk+8];
            size_t gv = ((size_t)zh*32 + vr)*M + m0 + vc;
            *(short8*)&vs[vr][vc]   = *(const short8*)&vthi[gv];
            *(short8*)&vs[vr][vc+8] = *(const short8*)&vthi[gv+8];
        }
        __syncthreads();

        float pr[2][4][4];
        #pragma unroll
        for (int qt = 0; qt < 2; ++qt)
            #pragma unroll
            for (int mt = 0; mt < 4; ++mt) {
                int mrow = mh*64 + mt*16 + l15;
                short8 kh = *(const short8*)&ks[0][mrow][quad*8];
                short8 kl = *(const short8*)&ks[1][mrow][quad*8];
                f32x4 a = {0.f,0.f,0.f,0.f};
                a = __builtin_amdgcn_mfma_f32_16x16x32_bf16(kh, qBl[qt], a, 0,0,0);
                a = __builtin_amdgcn_mfma_f32_16x16x32_bf16(kl, qBh[qt], a, 0,0,0);
                a = __builtin_amdgcn_mfma_f32_16x16x32_bf16(kh, qBh[qt], a, 0,0,0);
                #pragma unroll
                for (int r = 0; r < 4; ++r)
                    pr[qt][mt][r] = __expf(a[r] - myRM[qt]) * myRIV[qt];
            }

        #pragma unroll
        for (int mt = 0; mt < 4; ++mt)
            #pragma unroll
            for (int r = 0; r < 4; ++r) {
                float ps = pr[0][mt][r] + pr[1][mt][r];
                ps += __shfl_xor(ps, 1);
                ps += __shfl_xor(ps, 2);
                ps += __shfl_xor(ps, 4);
                ps += __shfl_xor(ps, 8);
                if (l15 == 0)
                    atomicAdd(&pcol[m0 + mh*64 + mt*16 + quad*4 + r], ps);
            }

        #pragma unroll
        for (int qt = 0; qt < 2; ++qt) {
            int qrow = qp*32 + qt*16 + l15;
            #pragma unroll
            for (int mt = 0; mt < 4; ++mt) {
                u16 h0 = f2bf(pr[qt][mt][0]), h1 = f2bf(pr[qt][mt][1]);
                u16 h2 = f2bf(pr[qt][mt][2]), h3 = f2bf(pr[qt][mt][3]);
                uint2 hv;
                hv.x = (unsigned)h0 | ((unsigned)h1 << 16);
                hv.y = (unsigned)h2 | ((unsigned)h3 << 16);
                *(uint2*)&Pw[qrow][mh*64 + mt*16 + quad*4] = hv;
            }
        }

        #pragma unroll
        for (int qt = 0; qt < 2; ++qt) {
            int qrow = qp*32 + qt*16 + l15;
            #pragma unroll
            for (int ks2 = 0; ks2 < 2; ++ks2) {
                short8 pAh = *(const short8*)&Pw[qrow][mh*64 + ks2*32 + quad*8];
                #pragma unroll
                for (int dt = 0; dt < 2; ++dt) {
                    short8 vh = *(const short8*)&vs[dt*16 + l15][mh*64 + ks2*32 + quad*8];
                    oa[qt][dt] = __builtin_amdgcn_mfma_f32_16x16x32_bf16(pAh, vh, oa[qt][dt], 0,0,0);
                }
            }
        }
        __syncthreads();
    }

    // merge mh halves via LDS, pack msg planes
    float* ob = (float*)&Pw[0][0];        // [64][33]
    float* fb = ob + 2112;                // [64][33]
    if (mh == 1) {
        #pragma unroll
        for (int qt = 0; qt < 2; ++qt)
            #pragma unroll
            for (int dt = 0; dt < 2; ++dt)
                #pragma unroll
                for (int r = 0; r < 4; ++r) {
                    int q = qp*32 + qt*16 + quad*4 + r;
                    ob[q*33 + dt*16 + l15] = oa[qt][dt][r];
                }
    }
    __syncthreads();
    if (mh == 0) {
        #pragma unroll
        for (int qt = 0; qt < 2; ++qt)
            #pragma unroll
            for (int dt = 0; dt < 2; ++dt)
                #pragma unroll
                for (int r = 0; r < 4; ++r) {
                    int q = qp*32 + qt*16 + quad*4 + r;
                    fb[q*33 + dt*16 + l15] = oa[qt][dt][r] + ob[q*33 + dt*16 + l15];
                }
    }
    __syncthreads();
    {
        int n = t >> 2, i8 = (t & 3)*8;
        short8 hi, lo;
        #pragma unroll
        for (int j = 0; j < 8; ++j) {
            float v = fb[n*33 + i8 + j];
            u16 hb = f2bf(v);
            hi[j] = (short)hb;
            lo[j] = (short)f2bf(v - bf2f(hb));
        }
        size_t mb = ((size_t)z*NN + n0 + n)*128 + h*32 + i8;
        *(short8*)&msghi[mb] = hi;
        *(short8*)&msglo[mb] = lo;
    }
    for (int i = t; i < M; i += 256)
        atomicAdd(&p[(size_t)z*NN + i], pcol[i]*0.25f);
}

// ---------------------------------------------------------------------------
// shared 3-term GEMM core (B from hi/lo planes, rows n with z*NN base)
// ---------------------------------------------------------------------------
__device__ __forceinline__ void gemm_core3(
    u16 (*As)[64][40], u16 (*Bs)[128][40],
    const u16* __restrict__ Whi, const u16* __restrict__ Wlo, int o0, int Cin,
    const u16* __restrict__ B1hi, const u16* __restrict__ B1lo, int s1,
    const u16* __restrict__ B2hi, const u16* __restrict__ B2lo, int s2, int split,
    size_t brow, int n0, int t, f32x4 acc[2][4])
{
    const int lane = t & 63, w = t >> 6;
    const int l15 = lane & 15, quad = lane >> 4;
    const int wr = (w & 1)*32, wc = (w >> 1)*64;
    const int ao = t >> 2, ak = (t & 3)*8;
    for (int kc = 0; kc < Cin; kc += 32) {
        {
            size_t wa = (size_t)(o0 + ao)*Cin + kc + ak;
            *(short8*)&As[0][ao][ak] = *(const short8*)&Whi[wa];
            *(short8*)&As[1][ao][ak] = *(const short8*)&Wlo[wa];
        }
        #pragma unroll
        for (int r = 0; r < 2; ++r) {
            int nl = (t >> 2) + r*64;
            int c = kc + ak;
            const u16 *ph, *pl;
            size_t off;
            if (c < split) { ph = B1hi; pl = B1lo; off = (brow + n0 + nl)*s1 + c; }
            else { ph = B2hi; pl = B2lo; off = (brow + n0 + nl)*s2 + (c - split); }
            *(short8*)&Bs[0][nl][ak] = *(const short8*)&ph[off];
            *(short8*)&Bs[1][nl][ak] = *(const short8*)&pl[off];
        }
        __syncthreads();
        short8 Ah[2], Al[2], Bh[4], Bl[4];
        #pragma unroll
        for (int a = 0; a < 2; ++a) {
            Ah[a] = *(const short8*)&As[0][wr + a*16 + l15][quad*8];
            Al[a] = *(const short8*)&As[1][wr + a*16 + l15][quad*8];
        }
        #pragma unroll
        for (int c = 0; c < 4; ++c) {
            Bh[c] = *(const short8*)&Bs[0][wc + c*16 + l15][quad*8];
            Bl[c] = *(const short8*)&Bs[1][wc + c*16 + l15][quad*8];
        }
        #pragma unroll
        for (int a = 0; a < 2; ++a)
            #pragma unroll
            for (int c = 0; c < 4; ++c) {
                acc[a][c] = __builtin_amdgcn_mfma_f32_16x16x32_bf16(Ah[a], Bl[c], acc[a][c], 0,0,0);
                acc[a][c] = __builtin_amdgcn_mfma_f32_16x16x32_bf16(Al[a], Bh[c], acc[a][c], 0,0,0);
                acc[a][c] = __builtin_amdgcn_mfma_f32_16x16x32_bf16(Ah[a], Bh[c], acc[a][c], 0,0,0);
            }
        __syncthreads();
    }
}

// ---------------------------------------------------------------------------
// Wm: m2 = Wm' * msg + bm -> m2 planes (epilogue transpose). Zeroes stats.
// ---------------------------------------------------------------------------
__global__ __launch_bounds__(256) void wm_kernel(
    const u16* __restrict__ Wmh, const u16* __restrict__ Wml,
    const float* __restrict__ bm,
    const u16* __restrict__ msghi, const u16* __restrict__ msglo,
    u16* __restrict__ m2hi, u16* __restrict__ m2lo,
    float* __restrict__ gsum, float* __restrict__ gsq)
{
    __shared__ u16 As[2][64][40];
    __shared__ u16 Bs[2][128][40];
    const int z = blockIdx.z, o0 = blockIdx.y*64, n0 = blockIdx.x*128;
    const int t = threadIdx.x;
    const int lane = t & 63, w = t >> 6;
    const int l15 = lane & 15, quad = lane >> 4;
    const int wr = (w & 1)*32;

    if (blockIdx.x == 0 && blockIdx.y == 0) {
        gsum[z*256 + t] = 0.f;
        gsq[z*256 + t] = 0.f;
    }

    f32x4 acc[2][4];
    #pragma unroll
    for (int a = 0; a < 2; ++a)
        #pragma unroll
        for (int c = 0; c < 4; ++c) acc[a][c] = (f32x4){0.f,0.f,0.f,0.f};
    gemm_core3(As, Bs, Wmh, Wml, o0, 128, msghi, msglo, 128,
               msghi, msglo, 128, 128, (size_t)z*NN, n0, t, acc);

    float* tb = (float*)&Bs[0][0][0];
    #pragma unroll
    for (int rd = 0; rd < 2; ++rd) {
        __syncthreads();
        if ((w >> 1) == rd) {
            #pragma unroll
            for (int a = 0; a < 2; ++a)
                #pragma unroll
                for (int c = 0; c < 4; ++c)
                    #pragma unroll
                    for (int r = 0; r < 4; ++r) {
                        int rl = wr + a*16 + quad*4 + r;
                        tb[rl*66 + c*16 + l15] = acc[a][c][r] + bm[o0 + rl];
                    }
        }
        __syncthreads();
        int n = t >> 2;
        #pragma unroll
        for (int oc = 0; oc < 2; ++oc) {
            int r0 = ((t & 3) + oc*4)*8;
            short8 hi, lo;
            #pragma unroll
            for (int j = 0; j < 8; ++j) {
                float v = tb[(r0 + j)*66 + n];
                u16 hb = f2bf(v);
                hi[j] = (short)hb;
                lo[j] = (short)f2bf(v - bf2f(hb));
            }
            size_t ob = ((size_t)z*NN + n0 + rd*64 + n)*128 + o0 + r0;
            *(short8*)&m2hi[ob] = hi;
            *(short8*)&m2lo[ob] = lo;
        }
    }
}

// ---------------------------------------------------------------------------
// W1: z = W1 [x ; m2] + b1 -> zf fp32 + instnorm stats atomics.
// ---------------------------------------------------------------------------
__global__ __launch_bounds__(256) void w1_kernel(
    const u16* __restrict__ W1h, const u16* __restrict__ W1l,
    const float* __restrict__ b1,
    const u16* __restrict__ xphi, const u16* __restrict__ xplo,
    const u16* __restrict__ m2hi, const u16* __restrict__ m2lo,
    float* __restrict__ zf, float* __restrict__ gsum, float* __restrict__ gsq)
{
    __shared__ u16 As[2][64][40];
    __shared__ u16 Bs[2][128][40];
    const int z = blockIdx.z, o0 = blockIdx.y*64, n0 = blockIdx.x*128;
    const int t = threadIdx.x;
    const int lane = t & 63, w = t >> 6;
    const int l15 = lane & 15, quad = lane >> 4;
    const int wr = (w & 1)*32, wc = (w >> 1)*64;

    f32x4 acc[2][4];
    #pragma unroll
    for (int a = 0; a < 2; ++a)
        #pragma unroll
        for (int c = 0; c < 4; ++c) acc[a][c] = (f32x4){0.f,0.f,0.f,0.f};
    gemm_core3(As, Bs, W1h, W1l, o0, 256, xphi, xplo, 128,
               m2hi, m2lo, 128, 128, (size_t)z*NN, n0, t, acc);

    float ssum[2][4], ssq[2][4];
    #pragma unroll
    for (int a = 0; a < 2; ++a)
        #pragma unroll
        for (int r = 0; r < 4; ++r) { ssum[a][r] = 0.f; ssq[a][r] = 0.f; }
    #pragma unroll
    for (int a = 0; a < 2; ++a)
        #pragma unroll
        for (int c = 0; c < 4; ++c)
            #pragma unroll
            for (int r = 0; r < 4; ++r) {
                int row = o0 + wr + a*16 + quad*4 + r;
                int n = n0 + wc + c*16 + l15;
                float v = acc[a][c][r] + b1[row];
                zf[((size_t)z*256 + row)*NN + n] = v;
                ssum[a][r] += v;
                ssq[a][r] = fmaf(v, v, ssq[a][r]);
            }
    #pragma unroll
    for (int a = 0; a < 2; ++a)
        #pragma unroll
        for (int r = 0; r < 4; ++r) {
            float s = ssum[a][r], q2 = ssq[a][r];
            #pragma unroll
            for (int o = 1; o < 16; o <<= 1) {
                s  += __shfl_xor(s, o);
                q2 += __shfl_xor(q2, o);
            }
            if (l15 == 0) {
                int row = o0 + wr + a*16 + quad*4 + r;
                atomicAdd(&gsum[z*256 + row], s);
                atomicAdd(&gsq[z*256 + row], q2);
            }
        }
}

// ---------------------------------------------------------------------------
// h = relu(instnorm(zf)) -> h planes [z][n][256] hi/lo
// ---------------------------------------------------------------------------
__global__ __launch_bounds__(256) void hrepack_kernel(
    const float* __restrict__ zf, const float* __restrict__ gsum,
    const float* __restrict__ gsq, u16* __restrict__ hhi, u16* __restrict__ hlo)
{
    __shared__ float tile[32][68];
    int z = blockIdx.y >> 3, cg = blockIdx.y & 7;
    int n0 = blockIdx.x * 64;
    int t = threadIdx.x;
    {
        int i = t >> 3, nc = (t & 7) * 8;
        int c = cg*32 + i;
        float mean = gsum[z*256 + c] * (1.f/NN);
        float var = gsq[z*256 + c] * (1.f/NN) - mean*mean;
        float iv = rsqrtf(var + IN_EPS);
        const float* src = &zf[((size_t)z*256 + c)*NN + n0 + nc];
        float4 a = *(const float4*)src;
        float4 b = *(const float4*)(src + 4);
        float vv[8] = {a.x,a.y,a.z,a.w,b.x,b.y,b.z,b.w};
        #pragma unroll
        for (int j = 0; j < 8; ++j) {
            float v = (vv[j] - mean) * iv;
            tile[i][nc + j] = v > 0.f ? v : 0.f;
        }
    }
    __syncthreads();
    int n = t >> 2, c8 = (t & 3) * 8;
    short8 hi, lo;
    #pragma unroll
    for (int j = 0; j < 8; ++j) {
        float v = tile[c8 + j][n];
        u16 hb = f2bf(v);
        hi[j] = (short)hb;
        lo[j] = (short)f2bf(v - bf2f(hb));
    }
    size_t ob = ((size_t)z*NN + n0 + n)*256 + cg*32 + c8;
    *(short8*)&hhi[ob] = hi;
    *(short8*)&hlo[ob] = lo;
}

// ---------------------------------------------------------------------------
// W2: x += W2 h + b2 (fp32) and refresh x planes (unless last layer).
// ---------------------------------------------------------------------------
__global__ __launch_bounds__(256) void w2_kernel(
    const u16* __restrict__ W2h, const u16* __restrict__ W2l,
    const float* __restrict__ b2,
    const u16* __restrict__ hhi, const u16* __restrict__ hlo,
    float* __restrict__ out, u16* __restrict__ xphi, u16* __restrict__ xplo,
    int writeplanes)
{
    __shared__ u16 As[2][64][40];
    __shared__ u16 Bs[2][128][40];
    const int z = blockIdx.z, o0 = blockIdx.y*64, n0 = blockIdx.x*128;
    const int t = threadIdx.x;
    const int lane = t & 63, w = t >> 6;
    const int l15 = lane & 15, quad = lane >> 4;
    const int wr = (w & 1)*32;

    f32x4 acc[2][4];
    #pragma unroll
    for (int a = 0; a < 2; ++a)
        #pragma unroll
        for (int c = 0; c < 4; ++c) acc[a][c] = (f32x4){0.f,0.f,0.f,0.f};
    gemm_core3(As, Bs, W2h, W2l, o0, 256, hhi, hlo, 256,
               hhi, hlo, 256, 256, (size_t)z*NN, n0, t, acc);

    float* tb = (float*)&Bs[0][0][0];
    #pragma unroll
    for (int rd = 0; rd < 2; ++rd) {
        __syncthreads();
        if ((w >> 1) == rd) {
            #pragma unroll
            for (int a = 0; a < 2; ++a)
                #pragma unroll
                for (int c = 0; c < 4; ++c)
                    #pragma unroll
                    for (int r = 0; r < 4; ++r) {
                        int rl = wr + a*16 + quad*4 + r;
                        int rowg = o0 + rl;
                        int n = n0 + rd*64 + c*16 + l15;
                        size_t oi = ((size_t)z*128 + rowg)*NN + n;
                        float v = acc[a][c][r] + b2[rowg] + out[oi];
                        out[oi] = v;
                        tb[rl*66 + c*16 + l15] = v;
                    }
        }
        __syncthreads();
        if (writeplanes) {
            int n = t >> 2;
            #pragma unroll
            for (int oc = 0; oc < 2; ++oc) {
                int r0 = ((t & 3) + oc*4)*8;
                short8 hi, lo;
                #pragma unroll
                for (int j = 0; j < 8; ++j) {
                    float v = tb[(r0 + j)*66 + n];
                    u16 hb = f2bf(v);
                    hi[j] = (short)hb;
                    lo[j] = (short)f2bf(v - bf2f(hb));
                }
                size_t ob = ((size_t)z*NN + n0 + rd*64 + n)*128 + o0 + r0;
                *(short8*)&xphi[ob] = hi;
                *(short8*)&xplo[ob] = lo;
            }
        }
    }
}

// ---------------------------------------------------------------------------
__global__ __launch_bounds__(256) void rank_kernel(
    const float* __restrict__ p, int* __restrict__ rank, int M)
{
    int zz = blockIdx.y;
    __shared__ float pv[2048];
    for (int i = threadIdx.x; i < M; i += 256) pv[i] = p[(size_t)zz*NN + i];
    __syncthreads();
    int i = blockIdx.x * 256 + threadIdx.x;
    if (i < M) {
        float pi = pv[i];
        int r = 0;
        for (int j = 0; j < M; ++j) {
            float pj = pv[j];
            r += (pj > pi) ? 1 : ((pj == pi && j < i) ? 1 : 0);
        }
        rank[zz*NN + i] = r;
    }
}

__global__ __launch_bounds__(256) void select_kernel(
    const int* __restrict__ rank, int* __restrict__ idx0, int* __restrict__ idx1,
    int M, int k, int cross)
{
    int z = blockIdx.x;
    int st = z >> 1, b = z & 1;
    int ts = cross ? 1 - st : st;
    int* idx = (ts ? idx1 : idx0) + b * NN;
    const int* rk = rank + z * NN;
    __shared__ int sel[2048], idv[2048], sa[2048], sb[2048];
    int t = threadIdx.x;
    for (int i = t; i < M; i += 256) {
        int s = rk[i] < k ? 1 : 0;
        sel[i] = s;
        sa[i] = s;
        idv[i] = idx[i];
    }
    __syncthreads();
    int* src = sa; int* dst = sb;
    for (int off = 1; off < M; off <<= 1) {
        for (int i = t; i < M; i += 256)
            dst[i] = src[i] + (i >= off ? src[i - off] : 0);
        __syncthreads();
        int* tmp = src; src = dst; dst = tmp;
    }
    for (int i = t; i < M; i += 256)
        if (sel[i]) idx[src[i] - 1] = idv[i];
}

// ---------------------------------------------------------------------------
extern "C" void kernel_launch(void* const* d_in, const int* in_sizes, int n_in,
                              void* d_out, int out_size, void* d_ws, size_t ws_size,
                              hipStream_t stream)
{
    const float* x0in = (const float*)d_in[0];
    const float* x1in = (const float*)d_in[1];
    const float* Wq = (const float*)d_in[2];
    const float* bq = (const float*)d_in[3];
    const float* Wk = (const float*)d_in[4];
    const float* bk = (const float*)d_in[5];
    const float* Wv = (const float*)d_in[6];
    const float* bv = (const float*)d_in[7];
    const float* Wm = (const float*)d_in[8];
    const float* bm = (const float*)d_in[9];
    const float* W1 = (const float*)d_in[10];
    const float* b1 = (const float*)d_in[11];
    const float* W2 = (const float*)d_in[12];
    const float* b2 = (const float*)d_in[13];

    float* out = (float*)d_out;
    float* ws  = (float*)d_ws;

    // u16 plane slots (U = 1Mi u16 = 2 MB each); zf aliases qt/kt (dead then).
    const size_t U = 1048576;
    u16* ub   = (u16*)ws;
    u16* xphi = ub;            u16* xplo = ub + U;
    u16* qthi = ub + 2*U;      u16* qtlo = ub + 3*U;
    u16* kthi = ub + 4*U;      u16* ktlo = ub + 5*U;
    u16* vthi = ub + 6*U;
    u16* msghi = ub + 7*U;     u16* msglo = ub + 8*U;
    u16* m2hi = ub + 9*U;      u16* m2lo = ub + 10*U;
    u16* hhi  = ub + 11*U;     u16* hlo = ub + 13*U;      // 2U each
    u16* whi  = ub + 15*U;     u16* wlo = whi + 655360;
    float* zf = (float*)(ub + 2*U);                        // aliases qt/kt (4U = 8MB)
    float* ft = (float*)(wlo + 655360);
    float* bqp = ft;           float* bkp = ft + 512;      float* bvp = ft + 1024;
    float* gsum = ft + 1536;   float* gsq = ft + 2560;
    float* p = ft + 3584;                                  // [4][NN]
    int* idx0 = (int*)(p + 4*NN);
    int* idx1 = idx0 + NB*NN;
    int* rankb = idx1 + NB*NN;

    init_kernel<<<BDN/4/256, 256, 0, stream>>>(x0in, x1in, out, idx0, idx1);
    wrepack2_kernel<<<2566, 256, 0, stream>>>(Wq, Wk, Wv, Wm, W1, W2, bq, bk, bv,
                                              whi, wlo, bqp, bkp, bvp);
    repack_xh_kernel<<<dim3(32, 16), 256, 0, stream>>>(out, xphi, xplo);

    const int Ms[4] = {2048, 1024, 512, 256};
    const int Mtb[4] = {4, 3, 2, 1};      // log2(M/128)
    for (int l = 0; l < 4; ++l) {
        int M = Ms[l];
        int k_new = (M/2 < 128) ? 128 : M/2;
        int cross = l & 1;
        size_t lw = (size_t)l * 163840;
        const u16* Wlh = whi + lw;  const u16* Wll = wlo + lw;

        int mtiles = M >> 7;
        qkv_kernel<<<dim3(32 + 4*mtiles, 1, 4), 256, 0, stream>>>(
            Wlh, Wll, bqp + l*128, bkp + l*128, bvp + l*128,
            xphi, xplo, idx0, idx1, cross, Mtb[l], M,
            qthi, qtlo, kthi, ktlo, vthi, p);

        attn3_kernel<<<dim3(32, NH, 4), 256, 0, stream>>>(
            qthi, qtlo, kthi, ktlo, vthi, M, msghi, msglo, p);

        wm_kernel<<<dim3(16, 2, 4), 256, 0, stream>>>(
            Wlh + 49152, Wll + 49152, bm + l*128,
            msghi, msglo, m2hi, m2lo, gsum, gsq);

        w1_kernel<<<dim3(16, 4, 4), 256, 0, stream>>>(
            Wlh + 65536, Wll + 65536, b1 + l*256,
            xphi, xplo, m2hi, m2lo, zf, gsum, gsq);

        hrepack_kernel<<<dim3(32, 32), 256, 0, stream>>>(zf, gsum, gsq, hhi, hlo);

        w2_kernel<<<dim3(16, 2, 4), 256, 0, stream>>>(
            Wlh + 131072, Wll + 131072, b2 + l*128,
            hhi, hlo, out, xphi, xplo, (l < 3) ? 1 : 0);

        rank_kernel<<<dim3((M+255)/256, 4), 256, 0, stream>>>(p, rankb, M);
        select_kernel<<<4, 256, 0, stream>>>(rankb, idx0, idx1, M, k_new, cross);
    }
}

// Round 8
// 555.192 us; speedup vs baseline: 4.4418x; 1.1048x over previous
//
#include <hip/hip_runtime.h>
#include <cstdint>
#include <cstddef>

// ---------------------------------------------------------------------------
// SDHGNN round 8: round 7 structure (512-thread attention, 64x64 GEMM tiles)
// with pass-1 reverted to 3-term split-bf16 scores. Round 7's hi-only pass-1
// ate the top-k rank margin (p err ~1e-3 vs gap ~5e-4) -> nondeterministic
// index flips across graph replays. Everything feeding p stays 3-term.
// ---------------------------------------------------------------------------

#define NB 2
#define ND 128
#define NH 4
#define NN 2048
#define ND2 256
#define DN (ND*NN)
#define BDN (NB*DN)
#define QK_SCALE 0.17677669529663687f
#define IN_EPS 1e-3f

typedef unsigned short u16;
typedef __attribute__((ext_vector_type(8))) short short8;
typedef __attribute__((ext_vector_type(4))) float f32x4;

__device__ __forceinline__ u16 f2bf(float f) {
    unsigned u = __float_as_uint(f);
    return (u16)((u + 0x7fffu + ((u >> 16) & 1u)) >> 16);
}
__device__ __forceinline__ float bf2f(u16 h) {
    return __uint_as_float(((unsigned)h) << 16);
}

// ---------------------------------------------------------------------------
__global__ __launch_bounds__(256) void init_kernel(
    const float* __restrict__ x0in, const float* __restrict__ x1in,
    float* __restrict__ out, int* __restrict__ idx0, int* __restrict__ idx1)
{
    int tid = blockIdx.x * 256 + threadIdx.x;
    const float4* a = (const float4*)x0in;
    const float4* b = (const float4*)x1in;
    float4* o = (float4*)out;
    o[tid] = a[tid];
    o[BDN/4 + tid] = b[tid];
    if (tid < NB*NN) {
        int v = tid & (NN-1);
        idx0[tid] = v;
        idx1[tid] = v;
    }
}

// ---------------------------------------------------------------------------
// weights -> bf16 hi/lo planes with permutations:
//   Wq/Wk/Wv rows permuted o' = h*32+i; Wm cols permuted; W1/W2 unchanged.
// ---------------------------------------------------------------------------
__global__ __launch_bounds__(256) void wrepack2_kernel(
    const float* __restrict__ Wq, const float* __restrict__ Wk,
    const float* __restrict__ Wv, const float* __restrict__ Wm,
    const float* __restrict__ W1, const float* __restrict__ W2,
    const float* __restrict__ bq, const float* __restrict__ bk,
    const float* __restrict__ bv,
    u16* __restrict__ whi, u16* __restrict__ wlo,
    float* __restrict__ bqp, float* __restrict__ bkp, float* __restrict__ bvp)
{
    int e = blockIdx.x * 256 + threadIdx.x;
    if (e < 655360) {
        int l = e / 163840, r = e - l*163840;
        float v;
        if (r < 49152) {
            int m = r >> 14;
            int rr = r & 16383;
            int o = rr >> 7, c = rr & 127;
            int so = (o & 31)*4 + (o >> 5);
            const float* W = (m == 0) ? Wq : ((m == 1) ? Wk : Wv);
            v = W[l*16384 + so*128 + c];
        } else if (r < 65536) {
            int rr = r - 49152;
            int o = rr >> 7, c = rr & 127;
            int sc = (c & 31)*4 + (c >> 5);
            v = Wm[l*16384 + o*128 + sc];
        } else if (r < 131072) v = W1[l*65536 + r - 65536];
        else                   v = W2[l*32768 + r - 131072];
        u16 hb = f2bf(v);
        whi[e] = hb;
        wlo[e] = f2bf(v - bf2f(hb));
    } else if (e < 656896) {
        int eb = e - 655360;
        int l = eb / 384, rr = eb % 384;
        int which = rr >> 7, o = rr & 127;
        int so = (o & 31)*4 + (o >> 5);
        float v = (which == 0 ? bq : (which == 1 ? bk : bv))[l*128 + so];
        (which == 0 ? bqp : (which == 1 ? bkp : bvp))[l*128 + o] = v;
    }
}

// ---------------------------------------------------------------------------
// fp32 [z][128][NN] -> bf16 hi/lo planes [z][n][128] (initial x planes)
// ---------------------------------------------------------------------------
__global__ __launch_bounds__(256) void repack_xh_kernel(
    const float* __restrict__ in, u16* __restrict__ ohi, u16* __restrict__ olo)
{
    __shared__ float tile[32][68];
    int z = blockIdx.y >> 2, cg = blockIdx.y & 3;
    int n0 = blockIdx.x * 64;
    int t = threadIdx.x;
    {
        int i = t >> 3, nc = (t & 7) * 8;
        const float* src = &in[((size_t)z*128 + cg*32 + i)*NN + n0 + nc];
        float4 a = *(const float4*)src;
        float4 b = *(const float4*)(src + 4);
        tile[i][nc+0]=a.x; tile[i][nc+1]=a.y; tile[i][nc+2]=a.z; tile[i][nc+3]=a.w;
        tile[i][nc+4]=b.x; tile[i][nc+5]=b.y; tile[i][nc+6]=b.z; tile[i][nc+7]=b.w;
    }
    __syncthreads();
    int n = t >> 2, c8 = (t & 3) * 8;
    short8 hi, lo;
    #pragma unroll
    for (int j = 0; j < 8; ++j) {
        float v = tile[c8 + j][n];
        u16 h = f2bf(v);
        hi[j] = (short)h;
        lo[j] = (short)f2bf(v - bf2f(h));
    }
    size_t ob = ((size_t)z*NN + n0 + n)*128 + cg*32 + c8;
    *(short8*)&ohi[ob] = hi;
    *(short8*)&olo[ob] = lo;
}

// ---------------------------------------------------------------------------
// shared 64x64 GEMM core, split-bf16 3-term, K-chunk 32, 4 waves 2x2 subtiles
// ---------------------------------------------------------------------------
__device__ __forceinline__ void gcore(
    u16* As0, u16* As1, u16* Bs0, u16* Bs1,
    const u16* __restrict__ Whi, const u16* __restrict__ Wlo, int o0, int Cin,
    const u16* __restrict__ B1hi, const u16* __restrict__ B1lo, int s1,
    const u16* __restrict__ B2hi, const u16* __restrict__ B2lo, int s2, int split,
    size_t brow, int n0, const int* __restrict__ idxp, int t, f32x4 acc[2][2])
{
    const int lane = t & 63, w = t >> 6;
    const int l15 = lane & 15, quad = lane >> 4;
    const int wr = (w & 1)*32, wc = (w >> 1)*32;
    const int ao = t >> 2, ak = (t & 3)*8;
    int grow = n0 + ao;
    if (idxp) grow = idxp[grow];
    for (int kc = 0; kc < Cin; kc += 32) {
        {
            size_t wa = (size_t)(o0 + ao)*Cin + kc + ak;
            *(short8*)&As0[ao*40 + ak] = *(const short8*)&Whi[wa];
            *(short8*)&As1[ao*40 + ak] = *(const short8*)&Wlo[wa];
        }
        {
            int c = kc + ak;
            const u16 *ph, *pl;
            size_t off;
            if (c < split) { ph = B1hi; pl = B1lo; off = (brow + grow)*s1 + c; }
            else { ph = B2hi; pl = B2lo; off = (brow + grow)*s2 + (c - split); }
            *(short8*)&Bs0[ao*40 + ak] = *(const short8*)&ph[off];
            *(short8*)&Bs1[ao*40 + ak] = *(const short8*)&pl[off];
        }
        __syncthreads();
        short8 Ah[2], Al[2], Bh[2], Bl[2];
        #pragma unroll
        for (int a = 0; a < 2; ++a) {
            Ah[a] = *(const short8*)&As0[(wr + a*16 + l15)*40 + quad*8];
            Al[a] = *(const short8*)&As1[(wr + a*16 + l15)*40 + quad*8];
        }
        #pragma unroll
        for (int c = 0; c < 2; ++c) {
            Bh[c] = *(const short8*)&Bs0[(wc + c*16 + l15)*40 + quad*8];
            Bl[c] = *(const short8*)&Bs1[(wc + c*16 + l15)*40 + quad*8];
        }
        #pragma unroll
        for (int a = 0; a < 2; ++a)
            #pragma unroll
            for (int c = 0; c < 2; ++c) {
                acc[a][c] = __builtin_amdgcn_mfma_f32_16x16x32_bf16(Ah[a], Bl[c], acc[a][c], 0,0,0);
                acc[a][c] = __builtin_amdgcn_mfma_f32_16x16x32_bf16(Al[a], Bh[c], acc[a][c], 0,0,0);
                acc[a][c] = __builtin_amdgcn_mfma_f32_16x16x32_bf16(Ah[a], Bh[c], acc[a][c], 0,0,0);
            }
        __syncthreads();
    }
}

// ---------------------------------------------------------------------------
// Fused QKV, 64x64 tiles. bx<64: q role (2 row-tiles x 32 n-tiles, own x).
// else: k/v roles over gathered stream (idx indirection), n-tiles of M/64.
// Epilogues: q/k -> qt/kt planes [zh][C][32]; v -> vt hi [zh][32][M].
// ---------------------------------------------------------------------------
__global__ __launch_bounds__(256) void qkv_kernel(
    const u16* __restrict__ Whi, const u16* __restrict__ Wlo,
    const float* __restrict__ bqp, const float* __restrict__ bkp,
    const float* __restrict__ bvp,
    const u16* __restrict__ xphi, const u16* __restrict__ xplo,
    const int* __restrict__ idx0, const int* __restrict__ idx1,
    int cross, int M,
    u16* __restrict__ qthi, u16* __restrict__ qtlo,
    u16* __restrict__ kthi, u16* __restrict__ ktlo,
    u16* __restrict__ vthi, float* __restrict__ p)
{
    __shared__ u16 gsm[10240];
    u16* As0 = gsm;  u16* As1 = gsm + 2560;
    u16* Bs0 = gsm + 5120; u16* Bs1 = gsm + 7680;
    float* tb = (float*)gsm;                 // [64][66]

    const int z = blockIdx.z;
    const int bx = blockIdx.x;
    const int t = threadIdx.x;
    const int lane = t & 63, w = t >> 6;
    const int l15 = lane & 15, quad = lane >> 4;
    const int wr = (w & 1)*32, wc = (w >> 1)*32;

    int role, o0, n0, nCols;
    const u16 *Wbh, *Wbl;
    const float* bias;
    if (bx < 64) {
        role = 0; o0 = (bx & 1)*64; n0 = (bx >> 1)*64; nCols = NN;
        Wbh = Whi; Wbl = Wlo; bias = bqp;
        if (t < 32) p[(size_t)z*NN + bx*32 + t] = 0.f;
    } else {
        int e = bx - 64;
        int kt = M >> 6;
        int ct = e % kt, rt = e / kt;
        n0 = ct*64; nCols = M;
        if (rt < 2) { role = 1; o0 = rt*64; Wbh = Whi+16384; Wbl = Wlo+16384; bias = bkp; }
        else        { role = 2; o0 = (rt-2)*64; Wbh = Whi+32768; Wbl = Wlo+32768; bias = bvp; }
    }
    size_t brow = (size_t)z * NN;
    const int* idxp = nullptr;
    if (role != 0) {
        int ss = cross ? 1 - (z >> 1) : (z >> 1);
        brow = (size_t)(ss*2 + (z & 1)) * NN;
        idxp = (ss ? idx1 : idx0) + (z & 1)*NN;
    }

    f32x4 acc[2][2];
    #pragma unroll
    for (int a = 0; a < 2; ++a)
        #pragma unroll
        for (int c = 0; c < 2; ++c) acc[a][c] = (f32x4){0.f,0.f,0.f,0.f};

    gcore(As0, As1, Bs0, Bs1, Wbh, Wbl, o0, 128,
          xphi, xplo, 128, xphi, xplo, 128, 128, brow, n0, idxp, t, acc);

    if (role == 2) {
        #pragma unroll
        for (int a = 0; a < 2; ++a)
            #pragma unroll
            for (int c = 0; c < 2; ++c)
                #pragma unroll
                for (int r = 0; r < 4; ++r) {
                    int row = o0 + wr + a*16 + quad*4 + r;
                    int m = n0 + wc + c*16 + l15;
                    float v = acc[a][c][r] + bias[row];
                    vthi[((size_t)(z*4 + (row>>5))*32 + (row&31))*(size_t)M + m] = f2bf(v);
                }
    } else {
        float scale = role ? 1.f : QK_SCALE;
        #pragma unroll
        for (int a = 0; a < 2; ++a)
            #pragma unroll
            for (int c = 0; c < 2; ++c)
                #pragma unroll
                for (int r = 0; r < 4; ++r) {
                    int rl = wr + a*16 + quad*4 + r;
                    tb[rl*66 + wc + c*16 + l15] = acc[a][c][r] + bias[o0 + rl];
                }
        __syncthreads();
        u16* ohi = role ? kthi : qthi;
        u16* olo = role ? ktlo : qtlo;
        int n = t >> 2, rb = (t & 3)*16;
        #pragma unroll
        for (int g = 0; g < 2; ++g) {
            short8 hi, lo;
            #pragma unroll
            for (int j = 0; j < 8; ++j) {
                float v = tb[(rb + g*8 + j)*66 + n] * scale;
                u16 hb = f2bf(v);
                hi[j] = (short)hb;
                lo[j] = (short)f2bf(v - bf2f(hb));
            }
            int rowg = o0 + rb + g*8;
            size_t ob = ((size_t)(z*4 + (rowg >> 5))*nCols + n0 + n)*32 + (rowg & 31);
            *(short8*)&ohi[ob] = hi;
            *(short8*)&olo[ob] = lo;
        }
    }
}

// ---------------------------------------------------------------------------
// Attention v4b: 512 threads, 8 waves (qp = w&1 q-half, mh = w>>1 m-quarter).
// Chunk 128. BOTH passes use 3-term split-bf16 scores (fp32-grade -> p safe).
// Pass 2: probs -> pcol (LDS), P hi wave-private -> PV bf16.
// msg -> planes [z][n][h*32+i].
// ---------------------------------------------------------------------------
__global__ __launch_bounds__(512) void attn4_kernel(
    const u16* __restrict__ qthi, const u16* __restrict__ qtlo,
    const u16* __restrict__ kthi, const u16* __restrict__ ktlo,
    const u16* __restrict__ vthi, int M,
    u16* __restrict__ msghi, u16* __restrict__ msglo, float* __restrict__ p)
{
    __shared__ u16 kv[14592];            // ks0[128][40] | ks1[128][40] | vs[32][136]
    __shared__ u16 Pw[64][146];
    __shared__ float pcol[2048];
    __shared__ float redm[4][64], redl[4][64];
    __shared__ float rowM[64], rowIV[64];

    u16* ks0 = kv;
    u16* ks1 = kv + 5120;
    u16* vs  = kv + 10240;               // stride 136
    float* obuf = (float*)kv;            // [3][64][32] after chunk loops

    const int t = threadIdx.x;
    const int lane = t & 63, wave = t >> 6;
    const int l15 = lane & 15, quad = lane >> 4;
    const int qp = wave & 1, mh = wave >> 1;     // mh 0..3
    const int h = blockIdx.y, z = blockIdx.z;
    const int zh = z*4 + h;
    const int n0 = blockIdx.x * 64;

    for (int i = t; i < M; i += 512) pcol[i] = 0.f;

    short8 qBh[2], qBl[2];
    #pragma unroll
    for (int qt = 0; qt < 2; ++qt) {
        size_t qb = ((size_t)zh*NN + n0 + qp*32 + qt*16 + l15)*32 + quad*8;
        qBh[qt] = *(const short8*)&qthi[qb];
        qBl[qt] = *(const short8*)&qtlo[qb];
    }

    const int nch = M >> 7;
    const int sr = t >> 2, sc8 = (t & 3)*8;
    const int vr = t >> 4, vc8 = (t & 15)*8;

    float rm[2] = {-1e30f, -1e30f}, rl[2] = {0.f, 0.f};

    // ---- pass 1: (m,l) from 3-term scores (fp32-grade) ----
    for (int ch = 0; ch < nch; ++ch) {
        const int m0 = ch << 7;
        {
            size_t gk = ((size_t)zh*M + m0 + sr)*32 + sc8;
            *(short8*)&ks0[sr*40 + sc8] = *(const short8*)&kthi[gk];
            *(short8*)&ks1[sr*40 + sc8] = *(const short8*)&ktlo[gk];
        }
        __syncthreads();
        #pragma unroll
        for (int qt = 0; qt < 2; ++qt)
            #pragma unroll
            for (int mt = 0; mt < 2; ++mt) {
                int mrow = mh*32 + mt*16 + l15;
                short8 kh = *(const short8*)&ks0[mrow*40 + quad*8];
                short8 kl = *(const short8*)&ks1[mrow*40 + quad*8];
                f32x4 a = {0.f,0.f,0.f,0.f};
                a = __builtin_amdgcn_mfma_f32_16x16x32_bf16(kh, qBl[qt], a, 0,0,0);
                a = __builtin_amdgcn_mfma_f32_16x16x32_bf16(kl, qBh[qt], a, 0,0,0);
                a = __builtin_amdgcn_mfma_f32_16x16x32_bf16(kh, qBh[qt], a, 0,0,0);
                float bm = fmaxf(fmaxf(a[0],a[1]), fmaxf(a[2],a[3]));
                float bs = __expf(a[0]-bm)+__expf(a[1]-bm)+__expf(a[2]-bm)+__expf(a[3]-bm);
                if (bm > rm[qt]) { rl[qt] = rl[qt]*__expf(rm[qt]-bm) + bs; rm[qt] = bm; }
                else rl[qt] += bs*__expf(bm - rm[qt]);
            }
        __syncthreads();
    }

    #pragma unroll
    for (int qt = 0; qt < 2; ++qt) {
        #pragma unroll
        for (int off = 16; off <= 32; off <<= 1) {
            float om = __shfl_xor(rm[qt], off);
            float ol = __shfl_xor(rl[qt], off);
            float nm = fmaxf(rm[qt], om);
            rl[qt] = rl[qt]*__expf(rm[qt]-nm) + ol*__expf(om-nm);
            rm[qt] = nm;
        }
        if (quad == 0) {
            redm[mh][qp*32 + qt*16 + l15] = rm[qt];
            redl[mh][qp*32 + qt*16 + l15] = rl[qt];
        }
    }
    __syncthreads();
    if (t < 64) {
        float m = redm[0][t], l = redl[0][t];
        #pragma unroll
        for (int w2 = 1; w2 < 4; ++w2) {
            float om = redm[w2][t];
            float nm = fmaxf(m, om);
            l = l*__expf(m - nm) + redl[w2][t]*__expf(om - nm);
            m = nm;
        }
        rowM[t] = m;
        rowIV[t] = 1.f / l;
    }
    __syncthreads();
    float myRM[2], myRIV[2];
    #pragma unroll
    for (int qt = 0; qt < 2; ++qt) {
        myRM[qt]  = rowM[qp*32 + qt*16 + l15];
        myRIV[qt] = rowIV[qp*32 + qt*16 + l15];
    }

    // ---- pass 2: probs (3-term), pcol, PV (bf16) ----
    f32x4 oa[2][2];
    #pragma unroll
    for (int qt = 0; qt < 2; ++qt)
        #pragma unroll
        for (int dt = 0; dt < 2; ++dt) oa[qt][dt] = (f32x4){0.f,0.f,0.f,0.f};

    for (int ch = 0; ch < nch; ++ch) {
        const int m0 = ch << 7;
        {
            size_t gk = ((size_t)zh*M + m0 + sr)*32 + sc8;
            *(short8*)&ks0[sr*40 + sc8] = *(const short8*)&kthi[gk];
            *(short8*)&ks1[sr*40 + sc8] = *(const short8*)&ktlo[gk];
            *(short8*)&vs[vr*136 + vc8] =
                *(const short8*)&vthi[((size_t)zh*32 + vr)*M + m0 + vc8];
        }
        __syncthreads();

        float pr[2][2][4];
        #pragma unroll
        for (int qt = 0; qt < 2; ++qt)
            #pragma unroll
            for (int mt = 0; mt < 2; ++mt) {
                int mrow = mh*32 + mt*16 + l15;
                short8 kh = *(const short8*)&ks0[mrow*40 + quad*8];
                short8 kl = *(const short8*)&ks1[mrow*40 + quad*8];
                f32x4 a = {0.f,0.f,0.f,0.f};
                a = __builtin_amdgcn_mfma_f32_16x16x32_bf16(kh, qBl[qt], a, 0,0,0);
                a = __builtin_amdgcn_mfma_f32_16x16x32_bf16(kl, qBh[qt], a, 0,0,0);
                a = __builtin_amdgcn_mfma_f32_16x16x32_bf16(kh, qBh[qt], a, 0,0,0);
                #pragma unroll
                for (int r = 0; r < 4; ++r)
                    pr[qt][mt][r] = __expf(a[r] - myRM[qt]) * myRIV[qt];
            }

        #pragma unroll
        for (int mt = 0; mt < 2; ++mt)
            #pragma unroll
            for (int r = 0; r < 4; ++r) {
                float ps = pr[0][mt][r] + pr[1][mt][r];
                ps += __shfl_xor(ps, 1);
                ps += __shfl_xor(ps, 2);
                ps += __shfl_xor(ps, 4);
                ps += __shfl_xor(ps, 8);
                if (l15 == 0)
                    atomicAdd(&pcol[m0 + mh*32 + mt*16 + quad*4 + r], ps);
            }

        #pragma unroll
        for (int qt = 0; qt < 2; ++qt) {
            int qrow = qp*32 + qt*16 + l15;
            #pragma unroll
            for (int mt = 0; mt < 2; ++mt) {
                u16 h0 = f2bf(pr[qt][mt][0]), h1 = f2bf(pr[qt][mt][1]);
                u16 h2 = f2bf(pr[qt][mt][2]), h3 = f2bf(pr[qt][mt][3]);
                uint2 hv;
                hv.x = (unsigned)h0 | ((unsigned)h1 << 16);
                hv.y = (unsigned)h2 | ((unsigned)h3 << 16);
                *(uint2*)&Pw[qrow][mh*36 + mt*16 + quad*4] = hv;
            }
        }

        #pragma unroll
        for (int qt = 0; qt < 2; ++qt) {
            int qrow = qp*32 + qt*16 + l15;
            short8 pAh = *(const short8*)&Pw[qrow][mh*36 + quad*8];
            #pragma unroll
            for (int dt = 0; dt < 2; ++dt) {
                short8 vh = *(const short8*)&vs[(dt*16 + l15)*136 + mh*32 + quad*8];
                oa[qt][dt] = __builtin_amdgcn_mfma_f32_16x16x32_bf16(pAh, vh, oa[qt][dt], 0,0,0);
            }
        }
        __syncthreads();
    }

    // merge mh partial PV sums via obuf (aliases kv), pack msg planes
    if (mh > 0) {
        #pragma unroll
        for (int qt = 0; qt < 2; ++qt)
            #pragma unroll
            for (int dt = 0; dt < 2; ++dt)
                #pragma unroll
                for (int r = 0; r < 4; ++r) {
                    int q = qp*32 + qt*16 + quad*4 + r;
                    obuf[((mh-1)*64 + q)*32 + dt*16 + l15] = oa[qt][dt][r];
                }
    }
    __syncthreads();
    if (mh == 0) {
        #pragma unroll
        for (int qt = 0; qt < 2; ++qt)
            #pragma unroll
            for (int dt = 0; dt < 2; ++dt)
                #pragma unroll
                for (int r = 0; r < 4; ++r) {
                    int q = qp*32 + qt*16 + quad*4 + r;
                    float v = oa[qt][dt][r];
                    #pragma unroll
                    for (int w2 = 0; w2 < 3; ++w2)
                        v += obuf[(w2*64 + q)*32 + dt*16 + l15];
                    obuf[q*32 + dt*16 + l15] = v;
                }
    }
    __syncthreads();
    {
        int tt = t & 255;
        int n = tt >> 2, i8 = (tt & 3)*8;
        short8 o8;
        if (t < 256) {
            #pragma unroll
            for (int j = 0; j < 8; ++j) o8[j] = (short)f2bf(obuf[n*32 + i8 + j]);
            *(short8*)&msghi[((size_t)z*NN + n0 + n)*128 + h*32 + i8] = o8;
        } else {
            #pragma unroll
            for (int j = 0; j < 8; ++j) {
                float v = obuf[n*32 + i8 + j];
                u16 hb = f2bf(v);
                o8[j] = (short)f2bf(v - bf2f(hb));
            }
            *(short8*)&msglo[((size_t)z*NN + n0 + n)*128 + h*32 + i8] = o8;
        }
    }
    for (int i = t; i < M; i += 512)
        atomicAdd(&p[(size_t)z*NN + i], pcol[i]*0.25f);
}

// ---------------------------------------------------------------------------
// Wm: m2 = Wm' * msg + bm -> m2 planes (epilogue transpose). Zeroes stats.
// ---------------------------------------------------------------------------
__global__ __launch_bounds__(256) void wm_kernel(
    const u16* __restrict__ Wmh, const u16* __restrict__ Wml,
    const float* __restrict__ bm,
    const u16* __restrict__ msghi, const u16* __restrict__ msglo,
    u16* __restrict__ m2hi, u16* __restrict__ m2lo,
    float* __restrict__ gsum, float* __restrict__ gsq)
{
    __shared__ u16 gsm[10240];
    u16* As0 = gsm;  u16* As1 = gsm + 2560;
    u16* Bs0 = gsm + 5120; u16* Bs1 = gsm + 7680;
    float* tb = (float*)gsm;

    const int z = blockIdx.z, o0 = blockIdx.y*64, n0 = blockIdx.x*64;
    const int t = threadIdx.x;
    const int lane = t & 63, w = t >> 6;
    const int l15 = lane & 15, quad = lane >> 4;
    const int wr = (w & 1)*32, wc = (w >> 1)*32;

    if (blockIdx.x == 0 && blockIdx.y == 0) {
        gsum[z*256 + t] = 0.f;
        gsq[z*256 + t] = 0.f;
    }

    f32x4 acc[2][2];
    #pragma unroll
    for (int a = 0; a < 2; ++a)
        #pragma unroll
        for (int c = 0; c < 2; ++c) acc[a][c] = (f32x4){0.f,0.f,0.f,0.f};
    gcore(As0, As1, Bs0, Bs1, Wmh, Wml, o0, 128,
          msghi, msglo, 128, msghi, msglo, 128, 128,
          (size_t)z*NN, n0, nullptr, t, acc);

    #pragma unroll
    for (int a = 0; a < 2; ++a)
        #pragma unroll
        for (int c = 0; c < 2; ++c)
            #pragma unroll
            for (int r = 0; r < 4; ++r) {
                int rl = wr + a*16 + quad*4 + r;
                tb[rl*66 + wc + c*16 + l15] = acc[a][c][r] + bm[o0 + rl];
            }
    __syncthreads();
    int n = t >> 2, rb = (t & 3)*16;
    #pragma unroll
    for (int g = 0; g < 2; ++g) {
        short8 hi, lo;
        #pragma unroll
        for (int j = 0; j < 8; ++j) {
            float v = tb[(rb + g*8 + j)*66 + n];
            u16 hb = f2bf(v);
            hi[j] = (short)hb;
            lo[j] = (short)f2bf(v - bf2f(hb));
        }
        size_t ob = ((size_t)z*NN + n0 + n)*128 + o0 + rb + g*8;
        *(short8*)&m2hi[ob] = hi;
        *(short8*)&m2lo[ob] = lo;
    }
}

// ---------------------------------------------------------------------------
// W1: z = W1 [x ; m2] + b1 -> zf fp32 + instnorm stats atomics.
// ---------------------------------------------------------------------------
__global__ __launch_bounds__(256) void w1_kernel(
    const u16* __restrict__ W1h, const u16* __restrict__ W1l,
    const float* __restrict__ b1,
    const u16* __restrict__ xphi, const u16* __restrict__ xplo,
    const u16* __restrict__ m2hi, const u16* __restrict__ m2lo,
    float* __restrict__ zf, float* __restrict__ gsum, float* __restrict__ gsq)
{
    __shared__ u16 gsm[10240];
    u16* As0 = gsm;  u16* As1 = gsm + 2560;
    u16* Bs0 = gsm + 5120; u16* Bs1 = gsm + 7680;

    const int z = blockIdx.z, o0 = blockIdx.y*64, n0 = blockIdx.x*64;
    const int t = threadIdx.x;
    const int lane = t & 63, w = t >> 6;
    const int l15 = lane & 15, quad = lane >> 4;
    const int wr = (w & 1)*32, wc = (w >> 1)*32;

    f32x4 acc[2][2];
    #pragma unroll
    for (int a = 0; a < 2; ++a)
        #pragma unroll
        for (int c = 0; c < 2; ++c) acc[a][c] = (f32x4){0.f,0.f,0.f,0.f};
    gcore(As0, As1, Bs0, Bs1, W1h, W1l, o0, 256,
          xphi, xplo, 128, m2hi, m2lo, 128, 128,
          (size_t)z*NN, n0, nullptr, t, acc);

    float ssum[2][4], ssq[2][4];
    #pragma unroll
    for (int a = 0; a < 2; ++a)
        #pragma unroll
        for (int r = 0; r < 4; ++r) { ssum[a][r] = 0.f; ssq[a][r] = 0.f; }
    #pragma unroll
    for (int a = 0; a < 2; ++a)
        #pragma unroll
        for (int c = 0; c < 2; ++c)
            #pragma unroll
            for (int r = 0; r < 4; ++r) {
                int row = o0 + wr + a*16 + quad*4 + r;
                int n = n0 + wc + c*16 + l15;
                float v = acc[a][c][r] + b1[row];
                zf[((size_t)z*256 + row)*NN + n] = v;
                ssum[a][r] += v;
                ssq[a][r] = fmaf(v, v, ssq[a][r]);
            }
    #pragma unroll
    for (int a = 0; a < 2; ++a)
        #pragma unroll
        for (int r = 0; r < 4; ++r) {
            float s = ssum[a][r], q2 = ssq[a][r];
            #pragma unroll
            for (int o = 1; o < 16; o <<= 1) {
                s  += __shfl_xor(s, o);
                q2 += __shfl_xor(q2, o);
            }
            if (l15 == 0) {
                int row = o0 + wr + a*16 + quad*4 + r;
                atomicAdd(&gsum[z*256 + row], s);
                atomicAdd(&gsq[z*256 + row], q2);
            }
        }
}

// ---------------------------------------------------------------------------
// h = relu(instnorm(zf)) -> h planes [z][n][256] hi/lo
// ---------------------------------------------------------------------------
__global__ __launch_bounds__(256) void hrepack_kernel(
    const float* __restrict__ zf, const float* __restrict__ gsum,
    const float* __restrict__ gsq, u16* __restrict__ hhi, u16* __restrict__ hlo)
{
    __shared__ float tile[32][68];
    int z = blockIdx.y >> 3, cg = blockIdx.y & 7;
    int n0 = blockIdx.x * 64;
    int t = threadIdx.x;
    {
        int i = t >> 3, nc = (t & 7) * 8;
        int c = cg*32 + i;
        float mean = gsum[z*256 + c] * (1.f/NN);
        float var = gsq[z*256 + c] * (1.f/NN) - mean*mean;
        float iv = rsqrtf(var + IN_EPS);
        const float* src = &zf[((size_t)z*256 + c)*NN + n0 + nc];
        float4 a = *(const float4*)src;
        float4 b = *(const float4*)(src + 4);
        float vv[8] = {a.x,a.y,a.z,a.w,b.x,b.y,b.z,b.w};
        #pragma unroll
        for (int j = 0; j < 8; ++j) {
            float v = (vv[j] - mean) * iv;
            tile[i][nc + j] = v > 0.f ? v : 0.f;
        }
    }
    __syncthreads();
    int n = t >> 2, c8 = (t & 3) * 8;
    short8 hi, lo;
    #pragma unroll
    for (int j = 0; j < 8; ++j) {
        float v = tile[c8 + j][n];
        u16 hb = f2bf(v);
        hi[j] = (short)hb;
        lo[j] = (short)f2bf(v - bf2f(hb));
    }
    size_t ob = ((size_t)z*NN + n0 + n)*256 + cg*32 + c8;
    *(short8*)&hhi[ob] = hi;
    *(short8*)&hlo[ob] = lo;
}

// ---------------------------------------------------------------------------
// W2: x += W2 h + b2 (fp32) and refresh x planes (unless last layer).
// ---------------------------------------------------------------------------
__global__ __launch_bounds__(256) void w2_kernel(
    const u16* __restrict__ W2h, const u16* __restrict__ W2l,
    const float* __restrict__ b2,
    const u16* __restrict__ hhi, const u16* __restrict__ hlo,
    float* __restrict__ out, u16* __restrict__ xphi, u16* __restrict__ xplo,
    int writeplanes)
{
    __shared__ u16 gsm[10240];
    u16* As0 = gsm;  u16* As1 = gsm + 2560;
    u16* Bs0 = gsm + 5120; u16* Bs1 = gsm + 7680;
    float* tb = (float*)gsm;

    const int z = blockIdx.z, o0 = blockIdx.y*64, n0 = blockIdx.x*64;
    const int t = threadIdx.x;
    const int lane = t & 63, w = t >> 6;
    const int l15 = lane & 15, quad = lane >> 4;
    const int wr = (w & 1)*32, wc = (w >> 1)*32;

    f32x4 acc[2][2];
    #pragma unroll
    for (int a = 0; a < 2; ++a)
        #pragma unroll
        for (int c = 0; c < 2; ++c) acc[a][c] = (f32x4){0.f,0.f,0.f,0.f};
    gcore(As0, As1, Bs0, Bs1, W2h, W2l, o0, 256,
          hhi, hlo, 256, hhi, hlo, 256, 256,
          (size_t)z*NN, n0, nullptr, t, acc);

    #pragma unroll
    for (int a = 0; a < 2; ++a)
        #pragma unroll
        for (int c = 0; c < 2; ++c)
            #pragma unroll
            for (int r = 0; r < 4; ++r) {
                int rl = wr + a*16 + quad*4 + r;
                int rowg = o0 + rl;
                int n = n0 + wc + c*16 + l15;
                size_t oi = ((size_t)z*128 + rowg)*NN + n;
                float v = acc[a][c][r] + b2[rowg] + out[oi];
                out[oi] = v;
                tb[rl*66 + wc + c*16 + l15] = v;
            }
    __syncthreads();
    if (writeplanes) {
        int n = t >> 2, rb = (t & 3)*16;
        #pragma unroll
        for (int g = 0; g < 2; ++g) {
            short8 hi, lo;
            #pragma unroll
            for (int j = 0; j < 8; ++j) {
                float v = tb[(rb + g*8 + j)*66 + n];
                u16 hb = f2bf(v);
                hi[j] = (short)hb;
                lo[j] = (short)f2bf(v - bf2f(hb));
            }
            size_t ob = ((size_t)z*NN + n0 + n)*128 + o0 + rb + g*8;
            *(short8*)&xphi[ob] = hi;
            *(short8*)&xplo[ob] = lo;
        }
    }
}

// ---------------------------------------------------------------------------
__global__ __launch_bounds__(256) void rank_kernel(
    const float* __restrict__ p, int* __restrict__ rank, int M)
{
    int zz = blockIdx.y;
    __shared__ float pv[2048];
    for (int i = threadIdx.x; i < M; i += 256) pv[i] = p[(size_t)zz*NN + i];
    __syncthreads();
    int i = blockIdx.x * 256 + threadIdx.x;
    if (i < M) {
        float pi = pv[i];
        int r = 0;
        for (int j = 0; j < M; ++j) {
            float pj = pv[j];
            r += (pj > pi) ? 1 : ((pj == pi && j < i) ? 1 : 0);
        }
        rank[zz*NN + i] = r;
    }
}

__global__ __launch_bounds__(256) void select_kernel(
    const int* __restrict__ rank, int* __restrict__ idx0, int* __restrict__ idx1,
    int M, int k, int cross)
{
    int z = blockIdx.x;
    int st = z >> 1, b = z & 1;
    int ts = cross ? 1 - st : st;
    int* idx = (ts ? idx1 : idx0) + b * NN;
    const int* rk = rank + z * NN;
    __shared__ int sel[2048], idv[2048], sa[2048], sb[2048];
    int t = threadIdx.x;
    for (int i = t; i < M; i += 256) {
        int s = rk[i] < k ? 1 : 0;
        sel[i] = s;
        sa[i] = s;
        idv[i] = idx[i];
    }
    __syncthreads();
    int* src = sa; int* dst = sb;
    for (int off = 1; off < M; off <<= 1) {
        for (int i = t; i < M; i += 256)
            dst[i] = src[i] + (i >= off ? src[i - off] : 0);
        __syncthreads();
        int* tmp = src; src = dst; dst = tmp;
    }
    for (int i = t; i < M; i += 256)
        if (sel[i]) idx[src[i] - 1] = idv[i];
}

// ---------------------------------------------------------------------------
extern "C" void kernel_launch(void* const* d_in, const int* in_sizes, int n_in,
                              void* d_out, int out_size, void* d_ws, size_t ws_size,
                              hipStream_t stream)
{
    const float* x0in = (const float*)d_in[0];
    const float* x1in = (const float*)d_in[1];
    const float* Wq = (const float*)d_in[2];
    const float* bq = (const float*)d_in[3];
    const float* Wk = (const float*)d_in[4];
    const float* bk = (const float*)d_in[5];
    const float* Wv = (const float*)d_in[6];
    const float* bv = (const float*)d_in[7];
    const float* Wm = (const float*)d_in[8];
    const float* bm = (const float*)d_in[9];
    const float* W1 = (const float*)d_in[10];
    const float* b1 = (const float*)d_in[11];
    const float* W2 = (const float*)d_in[12];
    const float* b2 = (const float*)d_in[13];

    float* out = (float*)d_out;
    float* ws  = (float*)d_ws;

    const size_t U = 1048576;
    u16* ub   = (u16*)ws;
    u16* xphi = ub;            u16* xplo = ub + U;
    u16* qthi = ub + 2*U;      u16* qtlo = ub + 3*U;
    u16* kthi = ub + 4*U;      u16* ktlo = ub + 5*U;
    u16* vthi = ub + 6*U;
    u16* msghi = ub + 7*U;     u16* msglo = ub + 8*U;
    u16* m2hi = ub + 9*U;      u16* m2lo = ub + 10*U;
    u16* hhi  = ub + 11*U;     u16* hlo = ub + 13*U;      // 2U each
    u16* whi  = ub + 15*U;     u16* wlo = whi + 655360;
    float* zf = (float*)(ub + 2*U);                        // aliases qt/kt (8 MB)
    float* ft = (float*)(wlo + 655360);
    float* bqp = ft;           float* bkp = ft + 512;      float* bvp = ft + 1024;
    float* gsum = ft + 1536;   float* gsq = ft + 2560;
    float* p = ft + 3584;                                  // [4][NN]
    int* idx0 = (int*)(p + 4*NN);
    int* idx1 = idx0 + NB*NN;
    int* rankb = idx1 + NB*NN;

    init_kernel<<<BDN/4/256, 256, 0, stream>>>(x0in, x1in, out, idx0, idx1);
    wrepack2_kernel<<<2566, 256, 0, stream>>>(Wq, Wk, Wv, Wm, W1, W2, bq, bk, bv,
                                              whi, wlo, bqp, bkp, bvp);
    repack_xh_kernel<<<dim3(32, 16), 256, 0, stream>>>(out, xphi, xplo);

    const int Ms[4] = {2048, 1024, 512, 256};
    for (int l = 0; l < 4; ++l) {
        int M = Ms[l];
        int k_new = (M/2 < 128) ? 128 : M/2;
        int cross = l & 1;
        size_t lw = (size_t)l * 163840;
        const u16* Wlh = whi + lw;  const u16* Wll = wlo + lw;

        qkv_kernel<<<dim3(64 + 4*(M/64), 1, 4), 256, 0, stream>>>(
            Wlh, Wll, bqp + l*128, bkp + l*128, bvp + l*128,
            xphi, xplo, idx0, idx1, cross, M,
            qthi, qtlo, kthi, ktlo, vthi, p);

        attn4_kernel<<<dim3(32, NH, 4), 512, 0, stream>>>(
            qthi, qtlo, kthi, ktlo, vthi, M, msghi, msglo, p);

        wm_kernel<<<dim3(32, 2, 4), 256, 0, stream>>>(
            Wlh + 49152, Wll + 49152, bm + l*128,
            msghi, msglo, m2hi, m2lo, gsum, gsq);

        w1_kernel<<<dim3(32, 4, 4), 256, 0, stream>>>(
            Wlh + 65536, Wll + 65536, b1 + l*256,
            xphi, xplo, m2hi, m2lo, zf, gsum, gsq);

        hrepack_kernel<<<dim3(32, 32), 256, 0, stream>>>(zf, gsum, gsq, hhi, hlo);

        w2_kernel<<<dim3(32, 2, 4), 256, 0, stream>>>(
            Wlh + 131072, Wll + 131072, b2 + l*128,
            hhi, hlo, out, xphi, xplo, (l < 3) ? 1 : 0);

        rank_kernel<<<dim3((M+255)/256, 4), 256, 0, stream>>>(p, rankb, M);
        select_kernel<<<4, 256, 0, stream>>>(rankb, idx0, idx1, M, k_new, cross);
    }
}